// Round 6
// baseline (243.661 us; speedup 1.0000x reference)
//
#include <hip/hip_runtime.h>
#include <math.h>

#define N_NODES 65536
#define B_GRAPHS 64
#define NPG 1024
#define EPG 16384
#define E_TOTAL (B_GRAPHS * EPG)
#define NEG 0.2f

typedef float f32x4 __attribute__((ext_vector_type(4)));
typedef __bf16 bf16x8 __attribute__((ext_vector_type(8)));
typedef int i32x4 __attribute__((ext_vector_type(4)));
typedef unsigned int uint32;
typedef unsigned short u16;

union FragU { i32x4 i; bf16x8 v; uint32 u[4]; };

// split f32 pair -> packed bf16 hi dword + lo dword (elem0 in low 16 bits)
__device__ __forceinline__ void cvt_pair(float a, float b, uint32& hi, uint32& lo) {
    uint32 ia = __float_as_uint(a), ib = __float_as_uint(b);
    uint32 ha = ia & 0xFFFF0000u, hb = ib & 0xFFFF0000u;
    hi = (ia >> 16) | hb;
    float ra = a - __uint_as_float(ha);
    float rb = b - __uint_as_float(hb);
    lo = (__float_as_uint(ra) >> 16) | (__float_as_uint(rb) & 0xFFFF0000u);
}

// raw v_exp_f32 (2^x) — logits bounded by construction
__device__ __forceinline__ float fast_exp2(float x) {
    float r;
    asm("v_exp_f32 %0, %1" : "=v"(r) : "v"(x));
    return r;
}

// ---------------- DPP 16-lane reduce (head groups = DPP rows) ----------------
template <int CTRL>
__device__ __forceinline__ float dpp_add(float v) {
    int x = __builtin_amdgcn_update_dpp(0, __float_as_int(v), CTRL, 0xf, 0xf, true);
    return v + __int_as_float(x);
}
__device__ __forceinline__ float hsum16(float v) {
    v = dpp_add<0xB1>(v);   // quad_perm xor 1
    v = dpp_add<0x4E>(v);   // quad_perm xor 2
    v = dpp_add<0x124>(v);  // row_ror:4
    v = dpp_add<0x128>(v);  // row_ror:8
    return v;
}

// ---------------- CSR build: one block per graph, LDS count-sort ----------------
__global__ __launch_bounds__(1024) void k_csr(const int* __restrict__ src, const int* __restrict__ dst,
                                              int* __restrict__ rowptr, int* __restrict__ col) {
    __shared__ int cnt[NPG];
    __shared__ int tmp[NPG];
    __shared__ int scol[EPG];   // 64KB
    int g = blockIdx.x, tid = threadIdx.x;
    int ebase = g * EPG;
    cnt[tid] = 0;
    __syncthreads();
    for (int e = tid; e < EPG; e += 1024)
        atomicAdd(&cnt[dst[ebase + e] & (NPG - 1)], 1);
    __syncthreads();
    int* a = cnt; int* b = tmp;
#pragma unroll
    for (int off = 1; off < 1024; off <<= 1) {
        int u = a[tid] + ((tid >= off) ? a[tid - off] : 0);
        __syncthreads();
        b[tid] = u;
        __syncthreads();
        int* t = a; a = b; b = t;
    }
    int excl = tid ? a[tid - 1] : 0;
    rowptr[g * NPG + tid] = ebase + excl;
    if (g == B_GRAPHS - 1 && tid == 0) rowptr[N_NODES] = E_TOTAL;
    b[tid] = excl;
    __syncthreads();
    for (int e = tid; e < EPG; e += 1024) {
        int d = dst[ebase + e] & (NPG - 1);
        int p = atomicAdd(&b[d], 1);
        scol[p] = src[ebase + e];
    }
    __syncthreads();
    int4* cg = (int4*)(col + ebase);
    const int4* cs = (const int4*)scol;
    for (int i = tid; i < EPG / 4; i += 1024) cg[i] = cs[i];
}

// ---------------- W transpose + bf16 hi/lo split ----------------
__global__ __launch_bounds__(256) void k_wconv(const float* __restrict__ Ws1, const float* __restrict__ Wd1,
                                               const float* __restrict__ Ws2, const float* __restrict__ Wd2,
                                               u16* __restrict__ Wt1, u16* __restrict__ Wt2) {
    int id = blockIdx.x * 256 + threadIdx.x;   // 40960 total
    if (id < 32768) {
        int mat = id >> 14, rem = id & 16383, n = rem >> 7, k = rem & 127;
        float v = (mat ? Wd1 : Ws1)[k * 128 + n];
        uint32 iv = __float_as_uint(v), h = iv & 0xFFFF0000u;
        float r = v - __uint_as_float(h);
        Wt1[((mat * 2 + 0) * 128 + n) * 128 + k] = (u16)(iv >> 16);
        Wt1[((mat * 2 + 1) * 128 + n) * 128 + k] = (u16)(__float_as_uint(r) >> 16);
    } else if (id < 40960) {
        int id2 = id - 32768;
        int mat = id2 >> 12, rem = id2 & 4095, n = rem >> 5, k = rem & 31;
        float v = (mat ? Wd2 : Ws2)[k * 128 + n];
        uint32 iv = __float_as_uint(v), h = iv & 0xFFFF0000u;
        float r = v - __uint_as_float(h);
        Wt2[((mat * 2 + 0) * 128 + n) * 32 + k] = (u16)(iv >> 16);
        Wt2[((mat * 2 + 1) * 128 + n) * 32 + k] = (u16)(__float_as_uint(r) >> 16);
    }
}

// ---------------- MFMA dual GEMM, operand-swapped ----------------
// block = 16 nodes x 256 outcols (fs 128 | fd 128); 16 waves, wave = one 16-col tile.
// A-operand = W^T tile (in registers, from L2-hot Wt); B-operand = X rows (8KB LDS).
// D[m=outcol][n=node]: lane stores node row (lane&15), 4 consecutive cols -> dwordx4.
template <int K>
__global__ __launch_bounds__(1024) void k_gemm_mfma(const float* __restrict__ X,
                                                    const u16* __restrict__ Wt,
                                                    const float* __restrict__ bs, const float* __restrict__ bd,
                                                    float* __restrict__ outs, float* __restrict__ outd) {
    constexpr int NC = K / 32;
    constexpr int LDK = K + 4;
    __shared__ float xs[16 * LDK];
    int tid = threadIdx.x;
    int lane = tid & 63, wv = tid >> 6;       // wv = col-tile 0..15
    int l15 = lane & 15, kg = lane >> 4;
    int nb = blockIdx.x * 16;

    // stage X: 16 rows x K floats (coalesced)
    if (K == 128) {
        int r = tid >> 6, c = (tid & 63) * 2;
        *(float2*)(xs + r * LDK + c) = *(const float2*)(X + (size_t)(nb + r) * K + c);
    } else {
        if (tid < 16 * K) {
            int r = tid / K, c = tid % K;
            xs[r * LDK + c] = X[(size_t)(nb + r) * K + c];
        }
    }

    // W frags in registers: hi row = (wv>=8 ? 256 : 0) + (wv&7)*16 + l15; lo = +128
    FragU wh[NC], wl[NC];
    {
        int Rh = ((wv >> 3) * 2) * 128 + (wv & 7) * 16 + l15;
        const u16* wb = Wt + (size_t)Rh * K + kg * 8;
#pragma unroll
        for (int c = 0; c < NC; ++c) {
            wh[c].i = *(const i32x4*)(wb + c * 32);
            wl[c].i = *(const i32x4*)(wb + (size_t)128 * K + c * 32);
        }
    }
    __syncthreads();

    f32x4 acc = (f32x4){0.f, 0.f, 0.f, 0.f};
#pragma unroll
    for (int c = 0; c < NC; ++c) {
        const float* xr = xs + l15 * LDK + c * 32 + kg * 8;
        float4 v0 = *(const float4*)xr;
        float4 v1 = *(const float4*)(xr + 4);
        FragU xh, xl;
        cvt_pair(v0.x, v0.y, xh.u[0], xl.u[0]);
        cvt_pair(v0.z, v0.w, xh.u[1], xl.u[1]);
        cvt_pair(v1.x, v1.y, xh.u[2], xl.u[2]);
        cvt_pair(v1.z, v1.w, xh.u[3], xl.u[3]);
        acc = __builtin_amdgcn_mfma_f32_16x16x32_bf16(wh[c].v, xh.v, acc, 0, 0, 0);
        acc = __builtin_amdgcn_mfma_f32_16x16x32_bf16(wl[c].v, xh.v, acc, 0, 0, 0);
        acc = __builtin_amdgcn_mfma_f32_16x16x32_bf16(wh[c].v, xl.v, acc, 0, 0, 0);
    }

    // epilogue: node = nb + (lane&15); cols = (wv&7)*16 + kg*4 .. +4 (contiguous)
    int colbase = (wv & 7) * 16 + kg * 4;
    const float* bp = (wv < 8) ? bs : bd;
    float* ob = (wv < 8) ? outs : outd;
    float4 bv = *(const float4*)(bp + colbase);
    float4 r4;
    r4.x = acc[0] + bv.x; r4.y = acc[1] + bv.y; r4.z = acc[2] + bv.z; r4.w = acc[3] + bv.w;
    *(float4*)(ob + (size_t)(nb + l15) * 128 + colbase) = r4;
}

// ---------------- GATv2 edge aggregation + head maxpool ----------------
__global__ __launch_bounds__(256) void k_edge(const float* __restrict__ fs, const float* __restrict__ fd,
                                              const int* __restrict__ rowptr, const int* __restrict__ col,
                                              const float* __restrict__ attn, float* __restrict__ hout) {
    int w = threadIdx.x >> 6, lane = threadIdx.x & 63;
    int bid = blockIdx.x;
    int nb = (bid & 7) * 2048 + (bid >> 3);   // XCD-aware swizzle (bijective: 16384 = 8*2048)
    int n = nb * 4 + w;
    float2 av = ((const float2*)attn)[lane];
    av.x *= 1.44269504089f;
    av.y *= 1.44269504089f;
    float2 fdv = *(const float2*)(fd + ((size_t)n << 7) + (lane << 1));
    int start = __builtin_amdgcn_readfirstlane(rowptr[n]);
    int end   = __builtin_amdgcn_readfirstlane(rowptr[n + 1]);
    int l7 = lane & 7;
    float z = 0.f, a0 = 0.f, a1 = 0.f;
    float z2 = 0.f, b0 = 0.f, b1 = 0.f;

    int nfull = (end - start) >> 3;
    int j = start;
    for (int c = 0; c < nfull; ++c, j += 8) {
        int myc = col[j + l7];
        float2 fv[8];
#pragma unroll
        for (int u = 0; u < 8; ++u) {
            int sg = __builtin_amdgcn_readlane(myc, u);
            fv[u] = *(const float2*)(fs + ((size_t)(uint32)sg << 7) + (lane << 1));
        }
#pragma unroll
        for (int u = 0; u < 8; ++u) {
            float e0 = fv[u].x + fdv.x; e0 = fmaxf(e0, NEG * e0);
            float e1 = fv[u].y + fdv.y; e1 = fmaxf(e1, NEG * e1);
            float sp = fmaf(e1, av.y, e0 * av.x);
            sp = hsum16(sp);
            float pe = fast_exp2(sp);
            if (u & 1) { z2 += pe; b0 = fmaf(pe, fv[u].x, b0); b1 = fmaf(pe, fv[u].y, b1); }
            else       { z  += pe; a0 = fmaf(pe, fv[u].x, a0); a1 = fmaf(pe, fv[u].y, a1); }
        }
    }
    int rem = end - j;
    if (rem > 0) {
        int jj = j + l7; jj = (jj < end) ? jj : end - 1;
        int myc = col[jj];
        float2 fv[8];
#pragma unroll
        for (int u = 0; u < 8; ++u) {
            int sg = __builtin_amdgcn_readlane(myc, u);
            fv[u] = *(const float2*)(fs + ((size_t)(uint32)sg << 7) + (lane << 1));
        }
#pragma unroll
        for (int u = 0; u < 8; ++u) {
            float e0 = fv[u].x + fdv.x; e0 = fmaxf(e0, NEG * e0);
            float e1 = fv[u].y + fdv.y; e1 = fmaxf(e1, NEG * e1);
            float sp = fmaf(e1, av.y, e0 * av.x);
            sp = hsum16(sp);
            float pe = fast_exp2(sp);
            pe = (u < rem) ? pe : 0.f;
            if (u & 1) { z2 += pe; b0 = fmaf(pe, fv[u].x, b0); b1 = fmaf(pe, fv[u].y, b1); }
            else       { z  += pe; a0 = fmaf(pe, fv[u].x, a0); a1 = fmaf(pe, fv[u].y, a1); }
        }
    }
    z += z2; a0 += b0; a1 += b1;
    float r = (z > 0.f) ? 1.f / z : 0.f;   // deg==0 -> output 0
    a0 *= r; a1 *= r;
    a0 = fmaxf(a0, __shfl_xor(a0, 16)); a0 = fmaxf(a0, __shfl_xor(a0, 32));
    a1 = fmaxf(a1, __shfl_xor(a1, 16)); a1 = fmaxf(a1, __shfl_xor(a1, 32));
    if (lane < 16)
        *(float2*)(hout + ((size_t)n << 5) + (lane << 1)) = make_float2(a0, a1);
}

// ---------------- global attention pooling ----------------
__global__ __launch_bounds__(256) void k_pool(const float* __restrict__ h2, const float* __restrict__ gW,
                                              const float* __restrict__ gb, float* __restrict__ out) {
    int b = blockIdx.x, tid = threadIdx.x;
    __shared__ float ga[NPG];
    __shared__ float red[256];
    __shared__ float gws[32];
    const float* hb = h2 + (size_t)b * NPG * 32;
    if (tid < 32) gws[tid] = gW[tid];
    __syncthreads();
    float gbv = gb[0];
    float lmax = -INFINITY;
    float gloc[4];
#pragma unroll
    for (int j = 0; j < 4; ++j) {
        int nl = tid + j * 256;
        const float* row = hb + nl * 32;
        float dot = 0.f;
#pragma unroll
        for (int c = 0; c < 32; c += 4) {
            float4 v = *(const float4*)(row + c);
            dot += v.x * gws[c] + v.y * gws[c + 1] + v.z * gws[c + 2] + v.w * gws[c + 3];
        }
        gloc[j] = dot + gbv;
        lmax = fmaxf(lmax, gloc[j]);
    }
    red[tid] = lmax; __syncthreads();
    for (int s2 = 128; s2 > 0; s2 >>= 1) { if (tid < s2) red[tid] = fmaxf(red[tid], red[tid + s2]); __syncthreads(); }
    float m = red[0];
    __syncthreads();
    float lsum = 0.f;
#pragma unroll
    for (int j = 0; j < 4; ++j) {
        int nl = tid + j * 256;
        float a = __expf(gloc[j] - m);
        ga[nl] = a;
        lsum += a;
    }
    red[tid] = lsum; __syncthreads();
    for (int s2 = 128; s2 > 0; s2 >>= 1) { if (tid < s2) red[tid] += red[tid + s2]; __syncthreads(); }
    float z = red[0];
    __syncthreads();
    int d = tid & 31, ng = tid >> 5;
    float acc = 0.f;
    for (int nl = ng; nl < NPG; nl += 8) acc += ga[nl] * hb[nl * 32 + d];
    red[tid] = acc; __syncthreads();
    if (tid < 32) {
        float s = red[tid];
#pragma unroll
        for (int g2 = 1; g2 < 8; ++g2) s += red[g2 * 32 + tid];
        out[b * 32 + tid] = s / z;
    }
}

extern "C" void kernel_launch(void* const* d_in, const int* in_sizes, int n_in,
                              void* d_out, int out_size, void* d_ws, size_t ws_size,
                              hipStream_t stream) {
    const float* x     = (const float*)d_in[0];
    const int*   src   = (const int*)d_in[1];
    const int*   dst   = (const int*)d_in[2];
    const float* Ws1   = (const float*)d_in[4];
    const float* bs1   = (const float*)d_in[5];
    const float* Wd1   = (const float*)d_in[6];
    const float* bd1   = (const float*)d_in[7];
    const float* attn1 = (const float*)d_in[8];
    const float* Ws2   = (const float*)d_in[9];
    const float* bs2   = (const float*)d_in[10];
    const float* Wd2   = (const float*)d_in[11];
    const float* bd2   = (const float*)d_in[12];
    const float* attn2 = (const float*)d_in[13];
    const float* gW    = (const float*)d_in[14];
    const float* gb    = (const float*)d_in[15];
    float* out = (float*)d_out;

    // workspace layout (~89 MB)
    float* fs = (float*)d_ws;                        // N*128
    float* fd = fs + (size_t)N_NODES * 128;          // N*128
    float* h1 = fd + (size_t)N_NODES * 128;          // N*32
    float* h2 = h1 + (size_t)N_NODES * 32;           // N*32
    int* rowptr = (int*)(h2 + (size_t)N_NODES * 32); // N+1
    int* col    = rowptr + (N_NODES + 4);            // E
    // Wt planes live INSIDE the h2 region (160KB << 8.4MB); consumed by gemm1/gemm2,
    // clobbered only later by k_edge layer-2 writing h2 (strictly after gemm2).
    u16* Wt1 = (u16*)h2;                             // 4*128*128 u16 = 128KB
    u16* Wt2 = Wt1 + 4 * 128 * 128;                  // 4*128*32  u16 =  32KB

    k_wconv<<<160, 256, 0, stream>>>(Ws1, Wd1, Ws2, Wd2, Wt1, Wt2);
    k_csr<<<B_GRAPHS, 1024, 0, stream>>>(src, dst, rowptr, col);

    // layer 1
    k_gemm_mfma<128><<<N_NODES / 16, 1024, 0, stream>>>(x, Wt1, bs1, bd1, fs, fd);
    k_edge<<<N_NODES / 4, 256, 0, stream>>>(fs, fd, rowptr, col, attn1, h1);

    // layer 2
    k_gemm_mfma<32><<<N_NODES / 16, 1024, 0, stream>>>(h1, Wt2, bs2, bd2, fs, fd);
    k_edge<<<N_NODES / 4, 256, 0, stream>>>(fs, fd, rowptr, col, attn2, h2);

    // global attention pooling
    k_pool<<<B_GRAPHS, 256, 0, stream>>>(h2, gW, gb, out);
}

// Round 7
// 242.798 us; speedup vs baseline: 1.0036x; 1.0036x over previous
//
#include <hip/hip_runtime.h>
#include <hip/hip_fp16.h>
#include <math.h>

#define N_NODES 65536
#define B_GRAPHS 64
#define NPG 1024
#define EPG 16384
#define E_TOTAL (B_GRAPHS * EPG)
#define NEG 0.2f

typedef float f32x4 __attribute__((ext_vector_type(4)));
typedef __bf16 bf16x8 __attribute__((ext_vector_type(8)));
typedef int i32x4 __attribute__((ext_vector_type(4)));
typedef unsigned int uint32;
typedef unsigned short u16;

union FragU { i32x4 i; bf16x8 v; uint32 u[4]; };

// split f32 pair -> packed bf16 hi dword + lo dword (elem0 in low 16 bits)
__device__ __forceinline__ void cvt_pair(float a, float b, uint32& hi, uint32& lo) {
    uint32 ia = __float_as_uint(a), ib = __float_as_uint(b);
    uint32 ha = ia & 0xFFFF0000u, hb = ib & 0xFFFF0000u;
    hi = (ia >> 16) | hb;
    float ra = a - __uint_as_float(ha);
    float rb = b - __uint_as_float(hb);
    lo = (__float_as_uint(ra) >> 16) | (__float_as_uint(rb) & 0xFFFF0000u);
}

// raw v_exp_f32 (2^x) — logits bounded by construction
__device__ __forceinline__ float fast_exp2(float x) {
    float r;
    asm("v_exp_f32 %0, %1" : "=v"(r) : "v"(x));
    return r;
}

__device__ __forceinline__ float2 h2f(uint32 u) {
    __half2 h = *(__half2*)&u;
    return __half22float2(h);
}

// ---------------- DPP 16-lane reduce (head groups = DPP rows) ----------------
template <int CTRL>
__device__ __forceinline__ float dpp_add(float v) {
    int x = __builtin_amdgcn_update_dpp(0, __float_as_int(v), CTRL, 0xf, 0xf, true);
    return v + __int_as_float(x);
}
__device__ __forceinline__ float hsum16(float v) {
    v = dpp_add<0xB1>(v);   // quad_perm xor 1
    v = dpp_add<0x4E>(v);   // quad_perm xor 2
    v = dpp_add<0x124>(v);  // row_ror:4
    v = dpp_add<0x128>(v);  // row_ror:8
    return v;
}

// ---------------- CSR build: one block per graph, LDS count-sort ----------------
__global__ __launch_bounds__(1024) void k_csr(const int* __restrict__ src, const int* __restrict__ dst,
                                              int* __restrict__ rowptr, int* __restrict__ col) {
    __shared__ int cnt[NPG];
    __shared__ int tmp[NPG];
    __shared__ int scol[EPG];   // 64KB
    int g = blockIdx.x, tid = threadIdx.x;
    int ebase = g * EPG;
    cnt[tid] = 0;
    __syncthreads();
    for (int e = tid; e < EPG; e += 1024)
        atomicAdd(&cnt[dst[ebase + e] & (NPG - 1)], 1);
    __syncthreads();
    int* a = cnt; int* b = tmp;
#pragma unroll
    for (int off = 1; off < 1024; off <<= 1) {
        int u = a[tid] + ((tid >= off) ? a[tid - off] : 0);
        __syncthreads();
        b[tid] = u;
        __syncthreads();
        int* t = a; a = b; b = t;
    }
    int excl = tid ? a[tid - 1] : 0;
    rowptr[g * NPG + tid] = ebase + excl;
    if (g == B_GRAPHS - 1 && tid == 0) rowptr[N_NODES] = E_TOTAL;
    b[tid] = excl;
    __syncthreads();
    for (int e = tid; e < EPG; e += 1024) {
        int d = dst[ebase + e] & (NPG - 1);
        int p = atomicAdd(&b[d], 1);
        scol[p] = src[ebase + e];
    }
    __syncthreads();
    int4* cg = (int4*)(col + ebase);
    const int4* cs = (const int4*)scol;
    for (int i = tid; i < EPG / 4; i += 1024) cg[i] = cs[i];
}

// ---------------- W transpose + bf16 hi/lo split ----------------
__global__ __launch_bounds__(256) void k_wconv(const float* __restrict__ Ws1, const float* __restrict__ Wd1,
                                               const float* __restrict__ Ws2, const float* __restrict__ Wd2,
                                               u16* __restrict__ Wt1, u16* __restrict__ Wt2) {
    int id = blockIdx.x * 256 + threadIdx.x;   // 40960 total
    if (id < 32768) {
        int mat = id >> 14, rem = id & 16383, n = rem >> 7, k = rem & 127;
        float v = (mat ? Wd1 : Ws1)[k * 128 + n];
        uint32 iv = __float_as_uint(v), h = iv & 0xFFFF0000u;
        float r = v - __uint_as_float(h);
        Wt1[((mat * 2 + 0) * 128 + n) * 128 + k] = (u16)(iv >> 16);
        Wt1[((mat * 2 + 1) * 128 + n) * 128 + k] = (u16)(__float_as_uint(r) >> 16);
    } else if (id < 40960) {
        int id2 = id - 32768;
        int mat = id2 >> 12, rem = id2 & 4095, n = rem >> 5, k = rem & 31;
        float v = (mat ? Wd2 : Ws2)[k * 128 + n];
        uint32 iv = __float_as_uint(v), h = iv & 0xFFFF0000u;
        float r = v - __uint_as_float(h);
        Wt2[((mat * 2 + 0) * 128 + n) * 32 + k] = (u16)(iv >> 16);
        Wt2[((mat * 2 + 1) * 128 + n) * 32 + k] = (u16)(__float_as_uint(r) >> 16);
    }
}

// ---------------- MFMA dual GEMM -> interleaved f16 output ----------------
// block = 256 thr = 4 waves, 16 nodes x 256 outcols; wave wv owns col-tiles wv*4..+3.
// A = W^T tile (per-chunk from L1-hot Wt), B = X rows (LDS). Epilogue transposes
// through LDS so the block writes ONE contiguous 8KB f16 segment.
// fsd row (256 halfs): [fs 0..127 | fd 0..127].
template <int K>
__global__ __launch_bounds__(256) void k_gemm_mfma(const float* __restrict__ X,
                                                   const u16* __restrict__ Wt,
                                                   const float* __restrict__ bs, const float* __restrict__ bd,
                                                   u16* __restrict__ fsd) {
    constexpr int NC = K / 32;
    constexpr int LDK = K + 4;
    __shared__ float xsbuf[2112];          // 8448B: stage (16 x LDK f32) / epilogue (16 x 264 halfs)
    float* xs = xsbuf;
    u16* eb = (u16*)xsbuf;
    int tid = threadIdx.x;
    int lane = tid & 63, wv = tid >> 6;
    int l15 = lane & 15, kg = lane >> 4;
    int nb = blockIdx.x * 16;

    // stage X (coalesced)
    if (K == 128) {
#pragma unroll
        for (int j = 0; j < 2; ++j) {
            int f = tid + j * 256;         // 0..511
            int r = f >> 5, c4 = f & 31;
            *(float4*)(xs + r * LDK + c4 * 4) = *(const float4*)(X + (size_t)(nb + r) * K + c4 * 4);
        }
    } else {
        if (tid < 128) {
            int r = tid >> 3, c4 = tid & 7;
            *(float4*)(xs + r * LDK + c4 * 4) = *(const float4*)(X + (size_t)(nb + r) * K + c4 * 4);
        }
    }
    __syncthreads();

    f32x4 acc[4];
#pragma unroll
    for (int i = 0; i < 4; ++i) acc[i] = (f32x4){0.f, 0.f, 0.f, 0.f};

#pragma unroll
    for (int c = 0; c < NC; ++c) {
        const float* xr = xs + l15 * LDK + c * 32 + kg * 8;
        float4 v0 = *(const float4*)xr;
        float4 v1 = *(const float4*)(xr + 4);
        FragU xh, xl;
        cvt_pair(v0.x, v0.y, xh.u[0], xl.u[0]);
        cvt_pair(v0.z, v0.w, xh.u[1], xl.u[1]);
        cvt_pair(v1.x, v1.y, xh.u[2], xl.u[2]);
        cvt_pair(v1.z, v1.w, xh.u[3], xl.u[3]);
#pragma unroll
        for (int i = 0; i < 4; ++i) {
            int T = wv * 4 + i;
            int Rh = ((T >> 3) * 2) * 128 + (T & 7) * 16 + l15;
            const u16* wb = Wt + (size_t)Rh * K + c * 32 + kg * 8;
            FragU wh, wl;
            wh.i = *(const i32x4*)wb;
            wl.i = *(const i32x4*)(wb + (size_t)128 * K);
            acc[i] = __builtin_amdgcn_mfma_f32_16x16x32_bf16(wh.v, xh.v, acc[i], 0, 0, 0);
            acc[i] = __builtin_amdgcn_mfma_f32_16x16x32_bf16(wl.v, xh.v, acc[i], 0, 0, 0);
            acc[i] = __builtin_amdgcn_mfma_f32_16x16x32_bf16(wh.v, xl.v, acc[i], 0, 0, 0);
        }
    }
    __syncthreads();   // xs reads complete before epilogue overwrites

    // epilogue: lane holds node l15, tile T, cols kg*4..+3 -> f16 into LDS
#pragma unroll
    for (int i = 0; i < 4; ++i) {
        int T = wv * 4 + i;
        const float* bp = (T < 8) ? bs : bd;
        float4 bv = *(const float4*)(bp + (T & 7) * 16 + kg * 4);
        __half2 h0 = __float22half2_rn(make_float2(acc[i][0] + bv.x, acc[i][1] + bv.y));
        __half2 h1 = __float22half2_rn(make_float2(acc[i][2] + bv.z, acc[i][3] + bv.w));
        int colh = (T & 7) * 16 + (T >> 3) * 128 + kg * 4;   // half index in 256-wide row
        uint2 pk;
        pk.x = *(uint32*)&h0;
        pk.y = *(uint32*)&h1;
        *(uint2*)(eb + l15 * 264 + colh) = pk;
    }
    __syncthreads();

    // linear writeback: 16 rows x 512B = 8KB fully contiguous per block
#pragma unroll
    for (int j = 0; j < 2; ++j) {
        int f = tid + j * 256;             // 0..511 16B-chunks
        int r = f >> 5, c = f & 31;
        i32x4 v = *(const i32x4*)(eb + r * 264 + c * 8);
        *(i32x4*)(fsd + (size_t)(nb + r) * 256 + c * 8) = v;
    }
}

// ---------------- GATv2 edge aggregation + head maxpool (f16 fsd) ----------------
__global__ __launch_bounds__(256) void k_edge(const u16* __restrict__ fsd,
                                              const int* __restrict__ rowptr, const int* __restrict__ col,
                                              const float* __restrict__ attn, float* __restrict__ hout) {
    int w = threadIdx.x >> 6, lane = threadIdx.x & 63;
    int bid = blockIdx.x;
    int nb = (bid & 7) * 2048 + (bid >> 3);   // XCD-aware swizzle (bijective: 16384 = 8*2048)
    int n = nb * 4 + w;
    float2 av = ((const float2*)attn)[lane];
    av.x *= 1.44269504089f;
    av.y *= 1.44269504089f;
    float2 fdv = h2f(*(const uint32*)(fsd + ((size_t)n << 8) + 128 + (lane << 1)));
    int start = __builtin_amdgcn_readfirstlane(rowptr[n]);
    int end   = __builtin_amdgcn_readfirstlane(rowptr[n + 1]);
    int l7 = lane & 7;
    float z = 0.f, a0 = 0.f, a1 = 0.f;
    float z2 = 0.f, b0 = 0.f, b1 = 0.f;

    int nfull = (end - start) >> 3;
    int j = start;
    for (int c = 0; c < nfull; ++c, j += 8) {
        int myc = col[j + l7];
        float2 fv[8];
#pragma unroll
        for (int u = 0; u < 8; ++u) {
            int sg = __builtin_amdgcn_readlane(myc, u);
            fv[u] = h2f(*(const uint32*)(fsd + ((size_t)(uint32)sg << 8) + (lane << 1)));
        }
#pragma unroll
        for (int u = 0; u < 8; ++u) {
            float e0 = fv[u].x + fdv.x; e0 = fmaxf(e0, NEG * e0);
            float e1 = fv[u].y + fdv.y; e1 = fmaxf(e1, NEG * e1);
            float sp = fmaf(e1, av.y, e0 * av.x);
            sp = hsum16(sp);
            float pe = fast_exp2(sp);
            if (u & 1) { z2 += pe; b0 = fmaf(pe, fv[u].x, b0); b1 = fmaf(pe, fv[u].y, b1); }
            else       { z  += pe; a0 = fmaf(pe, fv[u].x, a0); a1 = fmaf(pe, fv[u].y, a1); }
        }
    }
    int rem = end - j;
    if (rem > 0) {
        int jj = j + l7; jj = (jj < end) ? jj : end - 1;
        int myc = col[jj];
        float2 fv[8];
#pragma unroll
        for (int u = 0; u < 8; ++u) {
            int sg = __builtin_amdgcn_readlane(myc, u);
            fv[u] = h2f(*(const uint32*)(fsd + ((size_t)(uint32)sg << 8) + (lane << 1)));
        }
#pragma unroll
        for (int u = 0; u < 8; ++u) {
            float e0 = fv[u].x + fdv.x; e0 = fmaxf(e0, NEG * e0);
            float e1 = fv[u].y + fdv.y; e1 = fmaxf(e1, NEG * e1);
            float sp = fmaf(e1, av.y, e0 * av.x);
            sp = hsum16(sp);
            float pe = fast_exp2(sp);
            pe = (u < rem) ? pe : 0.f;
            if (u & 1) { z2 += pe; b0 = fmaf(pe, fv[u].x, b0); b1 = fmaf(pe, fv[u].y, b1); }
            else       { z  += pe; a0 = fmaf(pe, fv[u].x, a0); a1 = fmaf(pe, fv[u].y, a1); }
        }
    }
    z += z2; a0 += b0; a1 += b1;
    float r = (z > 0.f) ? 1.f / z : 0.f;   // deg==0 -> output 0
    a0 *= r; a1 *= r;
    a0 = fmaxf(a0, __shfl_xor(a0, 16)); a0 = fmaxf(a0, __shfl_xor(a0, 32));
    a1 = fmaxf(a1, __shfl_xor(a1, 16)); a1 = fmaxf(a1, __shfl_xor(a1, 32));
    if (lane < 16)
        *(float2*)(hout + ((size_t)n << 5) + (lane << 1)) = make_float2(a0, a1);
}

// ---------------- global attention pooling ----------------
__global__ __launch_bounds__(256) void k_pool(const float* __restrict__ h2, const float* __restrict__ gW,
                                              const float* __restrict__ gb, float* __restrict__ out) {
    int b = blockIdx.x, tid = threadIdx.x;
    __shared__ float ga[NPG];
    __shared__ float red[256];
    __shared__ float gws[32];
    const float* hb = h2 + (size_t)b * NPG * 32;
    if (tid < 32) gws[tid] = gW[tid];
    __syncthreads();
    float gbv = gb[0];
    float lmax = -INFINITY;
    float gloc[4];
#pragma unroll
    for (int j = 0; j < 4; ++j) {
        int nl = tid + j * 256;
        const float* row = hb + nl * 32;
        float dot = 0.f;
#pragma unroll
        for (int c = 0; c < 32; c += 4) {
            float4 v = *(const float4*)(row + c);
            dot += v.x * gws[c] + v.y * gws[c + 1] + v.z * gws[c + 2] + v.w * gws[c + 3];
        }
        gloc[j] = dot + gbv;
        lmax = fmaxf(lmax, gloc[j]);
    }
    red[tid] = lmax; __syncthreads();
    for (int s2 = 128; s2 > 0; s2 >>= 1) { if (tid < s2) red[tid] = fmaxf(red[tid], red[tid + s2]); __syncthreads(); }
    float m = red[0];
    __syncthreads();
    float lsum = 0.f;
#pragma unroll
    for (int j = 0; j < 4; ++j) {
        int nl = tid + j * 256;
        float a = __expf(gloc[j] - m);
        ga[nl] = a;
        lsum += a;
    }
    red[tid] = lsum; __syncthreads();
    for (int s2 = 128; s2 > 0; s2 >>= 1) { if (tid < s2) red[tid] += red[tid + s2]; __syncthreads(); }
    float z = red[0];
    __syncthreads();
    int d = tid & 31, ng = tid >> 5;
    float acc = 0.f;
    for (int nl = ng; nl < NPG; nl += 8) acc += ga[nl] * hb[nl * 32 + d];
    red[tid] = acc; __syncthreads();
    if (tid < 32) {
        float s = red[tid];
#pragma unroll
        for (int g2 = 1; g2 < 8; ++g2) s += red[g2 * 32 + tid];
        out[b * 32 + tid] = s / z;
    }
}

extern "C" void kernel_launch(void* const* d_in, const int* in_sizes, int n_in,
                              void* d_out, int out_size, void* d_ws, size_t ws_size,
                              hipStream_t stream) {
    const float* x     = (const float*)d_in[0];
    const int*   src   = (const int*)d_in[1];
    const int*   dst   = (const int*)d_in[2];
    const float* Ws1   = (const float*)d_in[4];
    const float* bs1   = (const float*)d_in[5];
    const float* Wd1   = (const float*)d_in[6];
    const float* bd1   = (const float*)d_in[7];
    const float* attn1 = (const float*)d_in[8];
    const float* Ws2   = (const float*)d_in[9];
    const float* bs2   = (const float*)d_in[10];
    const float* Wd2   = (const float*)d_in[11];
    const float* bd2   = (const float*)d_in[12];
    const float* attn2 = (const float*)d_in[13];
    const float* gW    = (const float*)d_in[14];
    const float* gb    = (const float*)d_in[15];
    float* out = (float*)d_out;

    // workspace layout (~55 MB)
    u16* fsd   = (u16*)d_ws;                               // N*256 halfs (fs|fd interleaved)
    float* h1  = (float*)(fsd + (size_t)N_NODES * 256);    // N*32 f32
    float* h2  = h1 + (size_t)N_NODES * 32;                // N*32 f32
    int* rowptr = (int*)(h2 + (size_t)N_NODES * 32);       // N+1
    int* col    = rowptr + (N_NODES + 4);                  // E
    u16* Wt1    = (u16*)(col + E_TOTAL);                   // 4*128*128 u16 = 128KB
    u16* Wt2    = Wt1 + 4 * 128 * 128;                     // 4*128*32  u16 =  32KB

    k_wconv<<<160, 256, 0, stream>>>(Ws1, Wd1, Ws2, Wd2, Wt1, Wt2);
    k_csr<<<B_GRAPHS, 1024, 0, stream>>>(src, dst, rowptr, col);

    // layer 1
    k_gemm_mfma<128><<<N_NODES / 16, 256, 0, stream>>>(x, Wt1, bs1, bd1, fsd);
    k_edge<<<N_NODES / 4, 256, 0, stream>>>(fsd, rowptr, col, attn1, h1);

    // layer 2 (overwrites fsd)
    k_gemm_mfma<32><<<N_NODES / 16, 256, 0, stream>>>(h1, Wt2, bs2, bd2, fsd);
    k_edge<<<N_NODES / 4, 256, 0, stream>>>(fsd, rowptr, col, attn2, h2);

    // global attention pooling
    k_pool<<<B_GRAPHS, 256, 0, stream>>>(h2, gW, gb, out);
}

// Round 8
// 192.103 us; speedup vs baseline: 1.2684x; 1.2639x over previous
//
#include <hip/hip_runtime.h>
#include <hip/hip_fp16.h>
#include <math.h>

#define N_NODES 65536
#define B_GRAPHS 64
#define NPG 1024
#define EPG 16384
#define E_TOTAL (B_GRAPHS * EPG)
#define NEG 0.2f

typedef float f32x4 __attribute__((ext_vector_type(4)));
typedef _Float16 f16x8 __attribute__((ext_vector_type(8)));
typedef int i32x4 __attribute__((ext_vector_type(4)));
typedef unsigned int uint32;
typedef unsigned short u16;

union FragH { i32x4 i; f16x8 h; uint32 u[4]; };

// raw v_exp_f32 (2^x) — logits bounded by construction
__device__ __forceinline__ float fast_exp2(float x) {
    float r;
    asm("v_exp_f32 %0, %1" : "=v"(r) : "v"(x));
    return r;
}

__device__ __forceinline__ float2 h2f(uint32 u) {
    __half2 h = *(__half2*)&u;
    return __half22float2(h);
}
__device__ __forceinline__ uint32 f2h2(float a, float b) {
    __half2 h = __float22half2_rn(make_float2(a, b));
    return *(uint32*)&h;
}

// ---------------- DPP 16-lane reduce (head groups = DPP rows) ----------------
template <int CTRL>
__device__ __forceinline__ float dpp_add(float v) {
    int x = __builtin_amdgcn_update_dpp(0, __float_as_int(v), CTRL, 0xf, 0xf, true);
    return v + __int_as_float(x);
}
__device__ __forceinline__ float hsum16(float v) {
    v = dpp_add<0xB1>(v);   // quad_perm xor 1
    v = dpp_add<0x4E>(v);   // quad_perm xor 2
    v = dpp_add<0x124>(v);  // row_ror:4
    v = dpp_add<0x128>(v);  // row_ror:8
    return v;
}

// ---------------- CSR build: one block per graph, LDS count-sort ----------------
__global__ __launch_bounds__(1024) void k_csr(const int* __restrict__ src, const int* __restrict__ dst,
                                              int* __restrict__ rowptr, int* __restrict__ col) {
    __shared__ int cnt[NPG];
    __shared__ int tmp[NPG];
    __shared__ int scol[EPG];   // 64KB
    int g = blockIdx.x, tid = threadIdx.x;
    int ebase = g * EPG;
    cnt[tid] = 0;
    __syncthreads();
    for (int e = tid; e < EPG; e += 1024)
        atomicAdd(&cnt[dst[ebase + e] & (NPG - 1)], 1);
    __syncthreads();
    int* a = cnt; int* b = tmp;
#pragma unroll
    for (int off = 1; off < 1024; off <<= 1) {
        int u = a[tid] + ((tid >= off) ? a[tid - off] : 0);
        __syncthreads();
        b[tid] = u;
        __syncthreads();
        int* t = a; a = b; b = t;
    }
    int excl = tid ? a[tid - 1] : 0;
    rowptr[g * NPG + tid] = ebase + excl;
    if (g == B_GRAPHS - 1 && tid == 0) rowptr[N_NODES] = E_TOTAL;
    b[tid] = excl;
    __syncthreads();
    for (int e = tid; e < EPG; e += 1024) {
        int d = dst[ebase + e] & (NPG - 1);
        int p = atomicAdd(&b[d], 1);
        scol[p] = src[ebase + e];
    }
    __syncthreads();
    int4* cg = (int4*)(col + ebase);
    const int4* cs = (const int4*)scol;
    for (int i = tid; i < EPG / 4; i += 1024) cg[i] = cs[i];
}

// ---------------- W -> fragment-linear f16 ----------------
// Wf1[((T*4 + c)*64 + lane)*8 + j] = W1[k][n], k = c*32 + (lane>>4)*8 + j, n = (T&7)*16 + (lane&15)
//   T<8 -> Ws1 (fs), T>=8 -> Wd1 (fd).   Wf2 same with NC=1 (k = (lane>>4)*8 + j).
__global__ __launch_bounds__(256) void k_wfrag(const float* __restrict__ Ws1, const float* __restrict__ Wd1,
                                               const float* __restrict__ Ws2, const float* __restrict__ Wd2,
                                               __half* __restrict__ Wf1, __half* __restrict__ Wf2) {
    int id = blockIdx.x * 256 + threadIdx.x;   // 40960 total
    if (id < 32768) {
        int j = id & 7, l = (id >> 3) & 63, c = (id >> 9) & 3, T = id >> 11;
        int k = c * 32 + (l >> 4) * 8 + j;
        int n = (T & 7) * 16 + (l & 15);
        const float* W = (T < 8) ? Ws1 : Wd1;
        Wf1[id] = __float2half_rn(W[k * 128 + n]);
    } else if (id < 40960) {
        int rem = id - 32768;
        int j = rem & 7, l = (rem >> 3) & 63, T = rem >> 9;
        int k = (l >> 4) * 8 + j;
        int n = (T & 7) * 16 + (l & 15);
        const float* W = (T < 8) ? Ws2 : Wd2;
        Wf2[rem] = __float2half_rn(W[k * 128 + n]);
    }
}

// ---------------- MFMA dual GEMM, f16 single, fragment-linear W ----------------
// block = 512 thr = 8 waves, 32 nodes x 256 outcols. wave wv: node-group ng=wv&1 (16 nodes),
// col-tiles Tb=(wv>>1)*4 .. +3. W-frag loads are contiguous 1KB/wave (L2-hot).
// Epilogue transposes through LDS -> one contiguous 16KB f16 write per block.
template <int K>
__global__ __launch_bounds__(512) void k_gemm_mfma(const float* __restrict__ X,
                                                   const __half* __restrict__ Wf,
                                                   const float* __restrict__ bs, const float* __restrict__ bd,
                                                   u16* __restrict__ fsd) {
    constexpr int NC = K / 32;
    constexpr int LDK = K + 8;
    __shared__ float xsbuf[4352];          // 17408B: stage 32 x LDK f32 / epilogue 32 x 264 halfs
    float* xs = xsbuf;
    u16* eb = (u16*)xsbuf;
    int tid = threadIdx.x;
    int lane = tid & 63, wv = tid >> 6;
    int l15 = lane & 15, kg = lane >> 4;
    int ng = wv & 1, Tb = (wv >> 1) * 4;
    int nb = blockIdx.x * 32;

    // stage X (coalesced float4)
    if (K == 128) {
#pragma unroll
        for (int j = 0; j < 2; ++j) {
            int f = tid + j * 512;         // 0..1023
            int r = f >> 5, c4 = f & 31;
            *(float4*)(xs + r * LDK + c4 * 4) = *(const float4*)(X + (size_t)(nb + r) * K + c4 * 4);
        }
    } else {
        if (tid < 256) {
            int r = tid >> 3, c4 = tid & 7;
            *(float4*)(xs + r * LDK + c4 * 4) = *(const float4*)(X + (size_t)(nb + r) * K + c4 * 4);
        }
    }
    __syncthreads();

    // X fragments for this wave's node-group, all chunks, f16 RN
    int ridx = ng * 16 + l15;
    FragH xf[NC];
#pragma unroll
    for (int c = 0; c < NC; ++c) {
        const float* xr = xs + ridx * LDK + c * 32 + kg * 8;
        float4 v0 = *(const float4*)xr;
        float4 v1 = *(const float4*)(xr + 4);
        xf[c].u[0] = f2h2(v0.x, v0.y);
        xf[c].u[1] = f2h2(v0.z, v0.w);
        xf[c].u[2] = f2h2(v1.x, v1.y);
        xf[c].u[3] = f2h2(v1.z, v1.w);
    }

    f32x4 acc[4];
#pragma unroll
    for (int i = 0; i < 4; ++i) acc[i] = (f32x4){0.f, 0.f, 0.f, 0.f};

#pragma unroll
    for (int i = 0; i < 4; ++i) {
        int T = Tb + i;
        const __half* wp = Wf + ((size_t)(T * NC) * 64 + lane) * 8;
#pragma unroll
        for (int c = 0; c < NC; ++c) {
            FragH wfr;
            wfr.i = *(const i32x4*)(wp + (size_t)c * 512);
            acc[i] = __builtin_amdgcn_mfma_f32_16x16x32_f16(wfr.h, xf[c].h, acc[i], 0, 0, 0);
        }
    }
    __syncthreads();   // xs reads complete before epilogue overwrites

    // epilogue: node = nb + ng*16 + l15 (lane&15 = n); cols kg*4+r in tile T
#pragma unroll
    for (int i = 0; i < 4; ++i) {
        int T = Tb + i;
        const float* bp = (T < 8) ? bs : bd;
        float4 bv = *(const float4*)(bp + (T & 7) * 16 + kg * 4);
        uint2 pk;
        pk.x = f2h2(acc[i][0] + bv.x, acc[i][1] + bv.y);
        pk.y = f2h2(acc[i][2] + bv.z, acc[i][3] + bv.w);
        int colh = (T & 7) * 16 + (T >> 3) * 128 + kg * 4;   // half index in 256-wide row
        *(uint2*)(eb + (ng * 16 + l15) * 264 + colh) = pk;
    }
    __syncthreads();

    // linear writeback: 32 rows x 512B = 16KB fully contiguous per block
#pragma unroll
    for (int j = 0; j < 2; ++j) {
        int f = tid + j * 512;             // 0..1023 16B-chunks
        int r = f >> 5, c = f & 31;
        i32x4 v = *(const i32x4*)(eb + r * 264 + c * 8);
        *(i32x4*)(fsd + (size_t)(nb + r) * 256 + c * 8) = v;
    }
}

// ---------------- GATv2 edge aggregation + head maxpool (f16 fsd) ----------------
__global__ __launch_bounds__(256) void k_edge(const u16* __restrict__ fsd,
                                              const int* __restrict__ rowptr, const int* __restrict__ col,
                                              const float* __restrict__ attn, float* __restrict__ hout) {
    int w = threadIdx.x >> 6, lane = threadIdx.x & 63;
    int bid = blockIdx.x;
    int nb = (bid & 7) * 2048 + (bid >> 3);   // XCD-aware swizzle (bijective: 16384 = 8*2048)
    int n = nb * 4 + w;
    float2 av = ((const float2*)attn)[lane];
    av.x *= 1.44269504089f;
    av.y *= 1.44269504089f;
    float2 fdv = h2f(*(const uint32*)(fsd + ((size_t)n << 8) + 128 + (lane << 1)));
    int start = __builtin_amdgcn_readfirstlane(rowptr[n]);
    int end   = __builtin_amdgcn_readfirstlane(rowptr[n + 1]);
    int l7 = lane & 7;
    float z = 0.f, a0 = 0.f, a1 = 0.f;
    float z2 = 0.f, b0 = 0.f, b1 = 0.f;

    int nfull = (end - start) >> 3;
    int j = start;
    for (int c = 0; c < nfull; ++c, j += 8) {
        int myc = col[j + l7];
        float2 fv[8];
#pragma unroll
        for (int u = 0; u < 8; ++u) {
            int sg = __builtin_amdgcn_readlane(myc, u);
            fv[u] = h2f(*(const uint32*)(fsd + ((size_t)(uint32)sg << 8) + (lane << 1)));
        }
#pragma unroll
        for (int u = 0; u < 8; ++u) {
            float e0 = fv[u].x + fdv.x; e0 = fmaxf(e0, NEG * e0);
            float e1 = fv[u].y + fdv.y; e1 = fmaxf(e1, NEG * e1);
            float sp = fmaf(e1, av.y, e0 * av.x);
            sp = hsum16(sp);
            float pe = fast_exp2(sp);
            if (u & 1) { z2 += pe; b0 = fmaf(pe, fv[u].x, b0); b1 = fmaf(pe, fv[u].y, b1); }
            else       { z  += pe; a0 = fmaf(pe, fv[u].x, a0); a1 = fmaf(pe, fv[u].y, a1); }
        }
    }
    int rem = end - j;
    if (rem > 0) {
        int jj = j + l7; jj = (jj < end) ? jj : end - 1;
        int myc = col[jj];
        float2 fv[8];
#pragma unroll
        for (int u = 0; u < 8; ++u) {
            int sg = __builtin_amdgcn_readlane(myc, u);
            fv[u] = h2f(*(const uint32*)(fsd + ((size_t)(uint32)sg << 8) + (lane << 1)));
        }
#pragma unroll
        for (int u = 0; u < 8; ++u) {
            float e0 = fv[u].x + fdv.x; e0 = fmaxf(e0, NEG * e0);
            float e1 = fv[u].y + fdv.y; e1 = fmaxf(e1, NEG * e1);
            float sp = fmaf(e1, av.y, e0 * av.x);
            sp = hsum16(sp);
            float pe = fast_exp2(sp);
            pe = (u < rem) ? pe : 0.f;
            if (u & 1) { z2 += pe; b0 = fmaf(pe, fv[u].x, b0); b1 = fmaf(pe, fv[u].y, b1); }
            else       { z  += pe; a0 = fmaf(pe, fv[u].x, a0); a1 = fmaf(pe, fv[u].y, a1); }
        }
    }
    z += z2; a0 += b0; a1 += b1;
    float r = (z > 0.f) ? 1.f / z : 0.f;   // deg==0 -> output 0
    a0 *= r; a1 *= r;
    a0 = fmaxf(a0, __shfl_xor(a0, 16)); a0 = fmaxf(a0, __shfl_xor(a0, 32));
    a1 = fmaxf(a1, __shfl_xor(a1, 16)); a1 = fmaxf(a1, __shfl_xor(a1, 32));
    if (lane < 16)
        *(float2*)(hout + ((size_t)n << 5) + (lane << 1)) = make_float2(a0, a1);
}

// ---------------- global attention pooling ----------------
__global__ __launch_bounds__(256) void k_pool(const float* __restrict__ h2, const float* __restrict__ gW,
                                              const float* __restrict__ gb, float* __restrict__ out) {
    int b = blockIdx.x, tid = threadIdx.x;
    __shared__ float ga[NPG];
    __shared__ float red[256];
    __shared__ float gws[32];
    const float* hb = h2 + (size_t)b * NPG * 32;
    if (tid < 32) gws[tid] = gW[tid];
    __syncthreads();
    float gbv = gb[0];
    float lmax = -INFINITY;
    float gloc[4];
#pragma unroll
    for (int j = 0; j < 4; ++j) {
        int nl = tid + j * 256;
        const float* row = hb + nl * 32;
        float dot = 0.f;
#pragma unroll
        for (int c = 0; c < 32; c += 4) {
            float4 v = *(const float4*)(row + c);
            dot += v.x * gws[c] + v.y * gws[c + 1] + v.z * gws[c + 2] + v.w * gws[c + 3];
        }
        gloc[j] = dot + gbv;
        lmax = fmaxf(lmax, gloc[j]);
    }
    red[tid] = lmax; __syncthreads();
    for (int s2 = 128; s2 > 0; s2 >>= 1) { if (tid < s2) red[tid] = fmaxf(red[tid], red[tid + s2]); __syncthreads(); }
    float m = red[0];
    __syncthreads();
    float lsum = 0.f;
#pragma unroll
    for (int j = 0; j < 4; ++j) {
        int nl = tid + j * 256;
        float a = __expf(gloc[j] - m);
        ga[nl] = a;
        lsum += a;
    }
    red[tid] = lsum; __syncthreads();
    for (int s2 = 128; s2 > 0; s2 >>= 1) { if (tid < s2) red[tid] += red[tid + s2]; __syncthreads(); }
    float z = red[0];
    __syncthreads();
    int d = tid & 31, ng = tid >> 5;
    float acc = 0.f;
    for (int nl = ng; nl < NPG; nl += 8) acc += ga[nl] * hb[nl * 32 + d];
    red[tid] = acc; __syncthreads();
    if (tid < 32) {
        float s = red[tid];
#pragma unroll
        for (int g2 = 1; g2 < 8; ++g2) s += red[g2 * 32 + tid];
        out[b * 32 + tid] = s / z;
    }
}

extern "C" void kernel_launch(void* const* d_in, const int* in_sizes, int n_in,
                              void* d_out, int out_size, void* d_ws, size_t ws_size,
                              hipStream_t stream) {
    const float* x     = (const float*)d_in[0];
    const int*   src   = (const int*)d_in[1];
    const int*   dst   = (const int*)d_in[2];
    const float* Ws1   = (const float*)d_in[4];
    const float* bs1   = (const float*)d_in[5];
    const float* Wd1   = (const float*)d_in[6];
    const float* bd1   = (const float*)d_in[7];
    const float* attn1 = (const float*)d_in[8];
    const float* Ws2   = (const float*)d_in[9];
    const float* bs2   = (const float*)d_in[10];
    const float* Wd2   = (const float*)d_in[11];
    const float* bd2   = (const float*)d_in[12];
    const float* attn2 = (const float*)d_in[13];
    const float* gW    = (const float*)d_in[14];
    const float* gb    = (const float*)d_in[15];
    float* out = (float*)d_out;

    // workspace layout (~55 MB)
    u16* fsd   = (u16*)d_ws;                               // N*256 halfs (fs|fd interleaved)
    float* h1  = (float*)(fsd + (size_t)N_NODES * 256);    // N*32 f32
    float* h2  = h1 + (size_t)N_NODES * 32;                // N*32 f32
    int* rowptr = (int*)(h2 + (size_t)N_NODES * 32);       // N+1 (padded to 16B)
    int* col    = rowptr + (N_NODES + 4);                  // E
    __half* Wf1 = (__half*)(col + E_TOTAL);                // 32768 halfs = 64KB
    __half* Wf2 = Wf1 + 32768;                             // 8192 halfs = 16KB

    k_wfrag<<<160, 256, 0, stream>>>(Ws1, Wd1, Ws2, Wd2, Wf1, Wf2);
    k_csr<<<B_GRAPHS, 1024, 0, stream>>>(src, dst, rowptr, col);

    // layer 1
    k_gemm_mfma<128><<<N_NODES / 32, 512, 0, stream>>>(x, Wf1, bs1, bd1, fsd);
    k_edge<<<N_NODES / 4, 256, 0, stream>>>(fsd, rowptr, col, attn1, h1);

    // layer 2 (overwrites fsd)
    k_gemm_mfma<32><<<N_NODES / 32, 512, 0, stream>>>(h1, Wf2, bs2, bd2, fsd);
    k_edge<<<N_NODES / 4, 256, 0, stream>>>(fsd, rowptr, col, attn2, h2);

    // global attention pooling
    k_pool<<<B_GRAPHS, 256, 0, stream>>>(h2, gW, gb, out);
}

// Round 9
// 171.886 us; speedup vs baseline: 1.4176x; 1.1176x over previous
//
#include <hip/hip_runtime.h>
#include <hip/hip_fp16.h>
#include <math.h>

#define N_NODES 65536
#define B_GRAPHS 64
#define NPG 1024
#define EPG 16384
#define E_TOTAL (B_GRAPHS * EPG)
#define NEG 0.2f

typedef float f32x4 __attribute__((ext_vector_type(4)));
typedef _Float16 f16x8 __attribute__((ext_vector_type(8)));
typedef _Float16 h2v __attribute__((ext_vector_type(2)));
typedef int i32x4 __attribute__((ext_vector_type(4)));
typedef unsigned int uint32;
typedef unsigned short u16;

union FragH { i32x4 i; f16x8 h; uint32 u[4]; };
union H2U { uint32 u; h2v h; };

// raw v_exp_f32 (2^x) — logits bounded by construction
__device__ __forceinline__ float fast_exp2(float x) {
    float r;
    asm("v_exp_f32 %0, %1" : "=v"(r) : "v"(x));
    return r;
}

__device__ __forceinline__ float2 h2f(uint32 u) {
    __half2 h = *(__half2*)&u;
    return __half22float2(h);
}
__device__ __forceinline__ uint32 f2h2(float a, float b) {
    __half2 h = __float22half2_rn(make_float2(a, b));
    return *(uint32*)&h;
}

// 16-lane sum via explicit DPP-fused adds (head groups = DPP rows)
__device__ __forceinline__ float hsum16_f(float v) {
    float a, b, c, d;
    asm("v_add_f32_dpp %0, %1, %1 quad_perm:[1,0,3,2] row_mask:0xf bank_mask:0xf" : "=&v"(a) : "v"(v));
    asm("v_add_f32_dpp %0, %1, %1 quad_perm:[2,3,0,1] row_mask:0xf bank_mask:0xf" : "=&v"(b) : "v"(a));
    asm("v_add_f32_dpp %0, %1, %1 row_ror:4 row_mask:0xf bank_mask:0xf" : "=&v"(c) : "v"(b));
    asm("v_add_f32_dpp %0, %1, %1 row_ror:8 row_mask:0xf bank_mask:0xf" : "=&v"(d) : "v"(c));
    return d;
}

// acc += p * f16(lo/hi of fv), f32 accumulate (v_fma_mix_f32)
__device__ __forceinline__ void fma_mix_lo(float& acc, float p, uint32 fv) {
    asm("v_fma_mix_f32 %0, %1, %2, %0 op_sel_hi:[0,1,0]" : "+v"(acc) : "v"(p), "v"(fv));
}
__device__ __forceinline__ void fma_mix_hi(float& acc, float p, uint32 fv) {
    asm("v_fma_mix_f32 %0, %1, %2, %0 op_sel:[0,1,0] op_sel_hi:[0,1,0]" : "+v"(acc) : "v"(p), "v"(fv));
}

// e = max(e, neg*e) ; sp = dot2(e, av) in f32
__device__ __forceinline__ float edge_term(uint32 fvu, h2v fdv2, h2v neg2, h2v av2) {
    H2U fv; fv.u = fvu;
    h2v e = fv.h + fdv2;                 // v_pk_add_f16
    h2v en = e * neg2;                   // v_pk_mul_f16
    h2v em;
    asm("v_pk_max_f16 %0, %1, %2" : "=v"(em) : "v"(e), "v"(en));
    float sp;
    asm("v_dot2_f32_f16 %0, %1, %2, %3" : "=v"(sp) : "v"(em), "v"(av2), "v"(0.f));
    return sp;
}

// ---------------- CSR build: one block per graph, LDS count-sort ----------------
__global__ __launch_bounds__(1024) void k_csr(const int* __restrict__ src, const int* __restrict__ dst,
                                              int* __restrict__ rowptr, int* __restrict__ col) {
    __shared__ int cnt[NPG];
    __shared__ int tmp[NPG];
    __shared__ int scol[EPG];   // 64KB
    int g = blockIdx.x, tid = threadIdx.x;
    int ebase = g * EPG;
    cnt[tid] = 0;
    __syncthreads();
    for (int e = tid; e < EPG; e += 1024)
        atomicAdd(&cnt[dst[ebase + e] & (NPG - 1)], 1);
    __syncthreads();
    int* a = cnt; int* b = tmp;
#pragma unroll
    for (int off = 1; off < 1024; off <<= 1) {
        int u = a[tid] + ((tid >= off) ? a[tid - off] : 0);
        __syncthreads();
        b[tid] = u;
        __syncthreads();
        int* t = a; a = b; b = t;
    }
    int excl = tid ? a[tid - 1] : 0;
    rowptr[g * NPG + tid] = ebase + excl;
    if (g == B_GRAPHS - 1 && tid == 0) rowptr[N_NODES] = E_TOTAL;
    b[tid] = excl;
    __syncthreads();
    for (int e = tid; e < EPG; e += 1024) {
        int d = dst[ebase + e] & (NPG - 1);
        int p = atomicAdd(&b[d], 1);
        scol[p] = src[ebase + e];
    }
    __syncthreads();
    int4* cg = (int4*)(col + ebase);
    const int4* cs = (const int4*)scol;
    for (int i = tid; i < EPG / 4; i += 1024) cg[i] = cs[i];
}

// ---------------- W -> fragment-linear f16 ----------------
__global__ __launch_bounds__(256) void k_wfrag(const float* __restrict__ Ws1, const float* __restrict__ Wd1,
                                               const float* __restrict__ Ws2, const float* __restrict__ Wd2,
                                               __half* __restrict__ Wf1, __half* __restrict__ Wf2) {
    int id = blockIdx.x * 256 + threadIdx.x;   // 40960 total
    if (id < 32768) {
        int j = id & 7, l = (id >> 3) & 63, c = (id >> 9) & 3, T = id >> 11;
        int k = c * 32 + (l >> 4) * 8 + j;
        int n = (T & 7) * 16 + (l & 15);
        const float* W = (T < 8) ? Ws1 : Wd1;
        Wf1[id] = __float2half_rn(W[k * 128 + n]);
    } else if (id < 40960) {
        int rem = id - 32768;
        int j = rem & 7, l = (rem >> 3) & 63, T = rem >> 9;
        int k = (l >> 4) * 8 + j;
        int n = (T & 7) * 16 + (l & 15);
        const float* W = (T < 8) ? Ws2 : Wd2;
        Wf2[rem] = __float2half_rn(W[k * 128 + n]);
    }
}

// ---------------- MFMA dual GEMM, f16 single, fragment-linear W ----------------
template <int K>
__global__ __launch_bounds__(512) void k_gemm_mfma(const float* __restrict__ X,
                                                   const __half* __restrict__ Wf,
                                                   const float* __restrict__ bs, const float* __restrict__ bd,
                                                   u16* __restrict__ fsd) {
    constexpr int NC = K / 32;
    constexpr int LDK = K + 8;
    __shared__ float xsbuf[4352];          // stage 32 x LDK f32 / epilogue 32 x 264 halfs
    float* xs = xsbuf;
    u16* eb = (u16*)xsbuf;
    int tid = threadIdx.x;
    int lane = tid & 63, wv = tid >> 6;
    int l15 = lane & 15, kg = lane >> 4;
    int ng = wv & 1, Tb = (wv >> 1) * 4;
    int nb = blockIdx.x * 32;

    if (K == 128) {
#pragma unroll
        for (int j = 0; j < 2; ++j) {
            int f = tid + j * 512;
            int r = f >> 5, c4 = f & 31;
            *(float4*)(xs + r * LDK + c4 * 4) = *(const float4*)(X + (size_t)(nb + r) * K + c4 * 4);
        }
    } else {
        if (tid < 256) {
            int r = tid >> 3, c4 = tid & 7;
            *(float4*)(xs + r * LDK + c4 * 4) = *(const float4*)(X + (size_t)(nb + r) * K + c4 * 4);
        }
    }
    __syncthreads();

    int ridx = ng * 16 + l15;
    FragH xf[NC];
#pragma unroll
    for (int c = 0; c < NC; ++c) {
        const float* xr = xs + ridx * LDK + c * 32 + kg * 8;
        float4 v0 = *(const float4*)xr;
        float4 v1 = *(const float4*)(xr + 4);
        xf[c].u[0] = f2h2(v0.x, v0.y);
        xf[c].u[1] = f2h2(v0.z, v0.w);
        xf[c].u[2] = f2h2(v1.x, v1.y);
        xf[c].u[3] = f2h2(v1.z, v1.w);
    }

    f32x4 acc[4];
#pragma unroll
    for (int i = 0; i < 4; ++i) acc[i] = (f32x4){0.f, 0.f, 0.f, 0.f};

#pragma unroll
    for (int i = 0; i < 4; ++i) {
        int T = Tb + i;
        const __half* wp = Wf + ((size_t)(T * NC) * 64 + lane) * 8;
#pragma unroll
        for (int c = 0; c < NC; ++c) {
            FragH wfr;
            wfr.i = *(const i32x4*)(wp + (size_t)c * 512);
            acc[i] = __builtin_amdgcn_mfma_f32_16x16x32_f16(wfr.h, xf[c].h, acc[i], 0, 0, 0);
        }
    }
    __syncthreads();

#pragma unroll
    for (int i = 0; i < 4; ++i) {
        int T = Tb + i;
        const float* bp = (T < 8) ? bs : bd;
        float4 bv = *(const float4*)(bp + (T & 7) * 16 + kg * 4);
        uint2 pk;
        pk.x = f2h2(acc[i][0] + bv.x, acc[i][1] + bv.y);
        pk.y = f2h2(acc[i][2] + bv.z, acc[i][3] + bv.w);
        int colh = (T & 7) * 16 + (T >> 3) * 128 + kg * 4;
        *(uint2*)(eb + (ng * 16 + l15) * 264 + colh) = pk;
    }
    __syncthreads();

#pragma unroll
    for (int j = 0; j < 2; ++j) {
        int f = tid + j * 512;
        int r = f >> 5, c = f & 31;
        i32x4 v = *(const i32x4*)(eb + r * 264 + c * 8);
        *(i32x4*)(fsd + (size_t)(nb + r) * 256 + c * 8) = v;
    }
}

// ---------------- GATv2 edge aggregation + head maxpool (packed f16 VALU) ----------------
__global__ __launch_bounds__(256) void k_edge(const u16* __restrict__ fsd,
                                              const int* __restrict__ rowptr, const int* __restrict__ col,
                                              const float* __restrict__ attn, float* __restrict__ hout) {
    int w = threadIdx.x >> 6, lane = threadIdx.x & 63;
    int bid = blockIdx.x;
    int nb = (bid & 7) * 2048 + (bid >> 3);   // XCD-aware swizzle (bijective: 16384 = 8*2048)
    int n = nb * 4 + w;
    float2 av = ((const float2*)attn)[lane];
    h2v av2;
    av2[0] = (_Float16)(av.x * 1.44269504089f);   // fold log2(e)
    av2[1] = (_Float16)(av.y * 1.44269504089f);
    h2v neg2;
    neg2[0] = (_Float16)NEG; neg2[1] = (_Float16)NEG;
    H2U fdv; fdv.u = *(const uint32*)(fsd + ((size_t)n << 8) + 128 + (lane << 1));
    int start = __builtin_amdgcn_readfirstlane(rowptr[n]);
    int end   = __builtin_amdgcn_readfirstlane(rowptr[n + 1]);
    int l7 = lane & 7;
    float z = 0.f, a0 = 0.f, a1 = 0.f;
    float z2 = 0.f, b0 = 0.f, b1 = 0.f;

    int nfull = (end - start) >> 3;
    int j = start;
    for (int c = 0; c < nfull; ++c, j += 8) {
        int myc = col[j + l7];
        uint32 fv[8];
#pragma unroll
        for (int u = 0; u < 8; ++u) {
            int sg = __builtin_amdgcn_readlane(myc, u);
            fv[u] = *(const uint32*)(fsd + ((size_t)(uint32)sg << 8) + (lane << 1));
        }
#pragma unroll
        for (int u = 0; u < 8; ++u) {
            float sp = edge_term(fv[u], fdv.h, neg2, av2);
            sp = hsum16_f(sp);
            float pe = fast_exp2(sp);
            if (u & 1) { z2 += pe; fma_mix_lo(b0, pe, fv[u]); fma_mix_hi(b1, pe, fv[u]); }
            else       { z  += pe; fma_mix_lo(a0, pe, fv[u]); fma_mix_hi(a1, pe, fv[u]); }
        }
    }
    int rem = end - j;
    if (rem > 0) {
        int jj = j + l7; jj = (jj < end) ? jj : end - 1;
        int myc = col[jj];
        uint32 fv[8];
#pragma unroll
        for (int u = 0; u < 8; ++u) {
            int sg = __builtin_amdgcn_readlane(myc, u);
            fv[u] = *(const uint32*)(fsd + ((size_t)(uint32)sg << 8) + (lane << 1));
        }
#pragma unroll
        for (int u = 0; u < 8; ++u) {
            float sp = edge_term(fv[u], fdv.h, neg2, av2);
            sp = hsum16_f(sp);
            float pe = fast_exp2(sp);
            pe = (u < rem) ? pe : 0.f;
            if (u & 1) { z2 += pe; fma_mix_lo(b0, pe, fv[u]); fma_mix_hi(b1, pe, fv[u]); }
            else       { z  += pe; fma_mix_lo(a0, pe, fv[u]); fma_mix_hi(a1, pe, fv[u]); }
        }
    }
    z += z2; a0 += b0; a1 += b1;
    float r = (z > 0.f) ? 1.f / z : 0.f;   // deg==0 -> output 0
    a0 *= r; a1 *= r;
    a0 = fmaxf(a0, __shfl_xor(a0, 16)); a0 = fmaxf(a0, __shfl_xor(a0, 32));
    a1 = fmaxf(a1, __shfl_xor(a1, 16)); a1 = fmaxf(a1, __shfl_xor(a1, 32));
    if (lane < 16)
        *(float2*)(hout + ((size_t)n << 5) + (lane << 1)) = make_float2(a0, a1);
}

// ---------------- global attention pooling ----------------
__global__ __launch_bounds__(256) void k_pool(const float* __restrict__ h2, const float* __restrict__ gW,
                                              const float* __restrict__ gb, float* __restrict__ out) {
    int b = blockIdx.x, tid = threadIdx.x;
    __shared__ float ga[NPG];
    __shared__ float red[256];
    __shared__ float gws[32];
    const float* hb = h2 + (size_t)b * NPG * 32;
    if (tid < 32) gws[tid] = gW[tid];
    __syncthreads();
    float gbv = gb[0];
    float lmax = -INFINITY;
    float gloc[4];
#pragma unroll
    for (int j = 0; j < 4; ++j) {
        int nl = tid + j * 256;
        const float* row = hb + nl * 32;
        float dot = 0.f;
#pragma unroll
        for (int c = 0; c < 32; c += 4) {
            float4 v = *(const float4*)(row + c);
            dot += v.x * gws[c] + v.y * gws[c + 1] + v.z * gws[c + 2] + v.w * gws[c + 3];
        }
        gloc[j] = dot + gbv;
        lmax = fmaxf(lmax, gloc[j]);
    }
    red[tid] = lmax; __syncthreads();
    for (int s2 = 128; s2 > 0; s2 >>= 1) { if (tid < s2) red[tid] = fmaxf(red[tid], red[tid + s2]); __syncthreads(); }
    float m = red[0];
    __syncthreads();
    float lsum = 0.f;
#pragma unroll
    for (int j = 0; j < 4; ++j) {
        int nl = tid + j * 256;
        float a = __expf(gloc[j] - m);
        ga[nl] = a;
        lsum += a;
    }
    red[tid] = lsum; __syncthreads();
    for (int s2 = 128; s2 > 0; s2 >>= 1) { if (tid < s2) red[tid] += red[tid + s2]; __syncthreads(); }
    float z = red[0];
    __syncthreads();
    int d = tid & 31, ng = tid >> 5;
    float acc = 0.f;
    for (int nl = ng; nl < NPG; nl += 8) acc += ga[nl] * hb[nl * 32 + d];
    red[tid] = acc; __syncthreads();
    if (tid < 32) {
        float s = red[tid];
#pragma unroll
        for (int g2 = 1; g2 < 8; ++g2) s += red[g2 * 32 + tid];
        out[b * 32 + tid] = s / z;
    }
}

extern "C" void kernel_launch(void* const* d_in, const int* in_sizes, int n_in,
                              void* d_out, int out_size, void* d_ws, size_t ws_size,
                              hipStream_t stream) {
    const float* x     = (const float*)d_in[0];
    const int*   src   = (const int*)d_in[1];
    const int*   dst   = (const int*)d_in[2];
    const float* Ws1   = (const float*)d_in[4];
    const float* bs1   = (const float*)d_in[5];
    const float* Wd1   = (const float*)d_in[6];
    const float* bd1   = (const float*)d_in[7];
    const float* attn1 = (const float*)d_in[8];
    const float* Ws2   = (const float*)d_in[9];
    const float* bs2   = (const float*)d_in[10];
    const float* Wd2   = (const float*)d_in[11];
    const float* bd2   = (const float*)d_in[12];
    const float* attn2 = (const float*)d_in[13];
    const float* gW    = (const float*)d_in[14];
    const float* gb    = (const float*)d_in[15];
    float* out = (float*)d_out;

    // workspace layout (~55 MB)
    u16* fsd   = (u16*)d_ws;                               // N*256 halfs (fs|fd interleaved)
    float* h1  = (float*)(fsd + (size_t)N_NODES * 256);    // N*32 f32
    float* h2  = h1 + (size_t)N_NODES * 32;                // N*32 f32
    int* rowptr = (int*)(h2 + (size_t)N_NODES * 32);       // N+1 (padded)
    int* col    = rowptr + (N_NODES + 4);                  // E
    __half* Wf1 = (__half*)(col + E_TOTAL);                // 32768 halfs
    __half* Wf2 = Wf1 + 32768;                             // 8192 halfs

    k_wfrag<<<160, 256, 0, stream>>>(Ws1, Wd1, Ws2, Wd2, Wf1, Wf2);
    k_csr<<<B_GRAPHS, 1024, 0, stream>>>(src, dst, rowptr, col);

    // layer 1
    k_gemm_mfma<128><<<N_NODES / 32, 512, 0, stream>>>(x, Wf1, bs1, bd1, fsd);
    k_edge<<<N_NODES / 4, 256, 0, stream>>>(fsd, rowptr, col, attn1, h1);

    // layer 2 (overwrites fsd)
    k_gemm_mfma<32><<<N_NODES / 32, 512, 0, stream>>>(h1, Wf2, bs2, bd2, fsd);
    k_edge<<<N_NODES / 4, 256, 0, stream>>>(fsd, rowptr, col, attn2, h2);

    // global attention pooling
    k_pool<<<B_GRAPHS, 256, 0, stream>>>(h2, gW, gb, out);
}

// Round 12
// 162.124 us; speedup vs baseline: 1.5029x; 1.0602x over previous
//
#include <hip/hip_runtime.h>
#include <hip/hip_fp16.h>
#include <math.h>

#define N_NODES 65536
#define B_GRAPHS 64
#define NPG 1024
#define EPG 16384
#define E_TOTAL (B_GRAPHS * EPG)
#define NEG 0.2f

typedef float f32x4 __attribute__((ext_vector_type(4)));
typedef _Float16 f16x8 __attribute__((ext_vector_type(8)));
typedef _Float16 h2v __attribute__((ext_vector_type(2)));
typedef int i32x4 __attribute__((ext_vector_type(4)));
typedef unsigned int uint32;
typedef unsigned short u16;

union FragH { i32x4 i; f16x8 h; uint32 u[4]; };
union H2U { uint32 u; h2v h; };

// raw v_exp_f32 (2^x) — logits bounded by construction [validated R8/R9]
__device__ __forceinline__ float fast_exp2(float x) {
    float r;
    asm("v_exp_f32 %0, %1" : "=v"(r) : "v"(x));
    return r;
}

__device__ __forceinline__ uint32 f2h2(float a, float b) {
    __half2 h = __float22half2_rn(make_float2(a, b));
    return *(uint32*)&h;
}

// acc += p * f16(lo/hi of fv), f32 accumulate (v_fma_mix_f32) [validated R8/R9]
__device__ __forceinline__ void fma_mix_lo(float& acc, float p, uint32 fv) {
    asm("v_fma_mix_f32 %0, %1, %2, %0 op_sel_hi:[0,1,0]" : "+v"(acc) : "v"(p), "v"(fv));
}
__device__ __forceinline__ void fma_mix_hi(float& acc, float p, uint32 fv) {
    asm("v_fma_mix_f32 %0, %1, %2, %0 op_sel:[0,1,0] op_sel_hi:[0,1,0]" : "+v"(acc) : "v"(p), "v"(fv));
}

// e = fv + fd; e = max(e, NEG*e); sp += dot2(e, av)   (f32 accumulate) [validated R8/R9]
__device__ __forceinline__ float dot_term(uint32 fvu, h2v fdv, h2v neg2, h2v av, float accum) {
    H2U fv; fv.u = fvu;
    h2v e = fv.h + fdv;                  // v_pk_add_f16
    h2v en = e * neg2;                   // v_pk_mul_f16
    h2v em;
    asm("v_pk_max_f16 %0, %1, %2" : "=v"(em) : "v"(e), "v"(en));
    float sp;
    asm("v_dot2_f32_f16 %0, %1, %2, %3" : "=v"(sp) : "v"(em), "v"(av), "v"(accum));
    return sp;
}

// ---------------- CSR build: one block per graph, LDS count-sort ----------------
__global__ __launch_bounds__(1024) void k_csr(const int* __restrict__ src, const int* __restrict__ dst,
                                              int* __restrict__ rowptr, int* __restrict__ col) {
    __shared__ int cnt[NPG];
    __shared__ int tmp[NPG];
    __shared__ int scol[EPG];   // 64KB
    int g = blockIdx.x, tid = threadIdx.x;
    int ebase = g * EPG;
    cnt[tid] = 0;
    __syncthreads();
    for (int e = tid; e < EPG; e += 1024)
        atomicAdd(&cnt[dst[ebase + e] & (NPG - 1)], 1);
    __syncthreads();
    int* a = cnt; int* b = tmp;
#pragma unroll
    for (int off = 1; off < 1024; off <<= 1) {
        int u = a[tid] + ((tid >= off) ? a[tid - off] : 0);
        __syncthreads();
        b[tid] = u;
        __syncthreads();
        int* t = a; a = b; b = t;
    }
    int excl = tid ? a[tid - 1] : 0;
    rowptr[g * NPG + tid] = ebase + excl;
    if (g == B_GRAPHS - 1 && tid == 0) rowptr[N_NODES] = E_TOTAL;
    b[tid] = excl;
    __syncthreads();
    for (int e = tid; e < EPG; e += 1024) {
        int d = dst[ebase + e] & (NPG - 1);
        int p = atomicAdd(&b[d], 1);
        scol[p] = src[ebase + e];
    }
    __syncthreads();
    int4* cg = (int4*)(col + ebase);
    const int4* cs = (const int4*)scol;
    for (int i = tid; i < EPG / 4; i += 1024) cg[i] = cs[i];
}

// ---------------- W -> fragment-linear f16 ----------------
__global__ __launch_bounds__(256) void k_wfrag(const float* __restrict__ Ws1, const float* __restrict__ Wd1,
                                               const float* __restrict__ Ws2, const float* __restrict__ Wd2,
                                               __half* __restrict__ Wf1, __half* __restrict__ Wf2) {
    int id = blockIdx.x * 256 + threadIdx.x;   // 40960 total
    if (id < 32768) {
        int j = id & 7, l = (id >> 3) & 63, c = (id >> 9) & 3, T = id >> 11;
        int k = c * 32 + (l >> 4) * 8 + j;
        int n = (T & 7) * 16 + (l & 15);
        const float* W = (T < 8) ? Ws1 : Wd1;
        Wf1[id] = __float2half_rn(W[k * 128 + n]);
    } else if (id < 40960) {
        int rem = id - 32768;
        int j = rem & 7, l = (rem >> 3) & 63, T = rem >> 9;
        int k = (l >> 4) * 8 + j;
        int n = (T & 7) * 16 + (l & 15);
        const float* W = (T < 8) ? Ws2 : Wd2;
        Wf2[rem] = __float2half_rn(W[k * 128 + n]);
    }
}

// ---------------- MFMA dual GEMM, f16 single, fragment-linear W ----------------
template <int K>
__global__ __launch_bounds__(512) void k_gemm_mfma(const float* __restrict__ X,
                                                   const __half* __restrict__ Wf,
                                                   const float* __restrict__ bs, const float* __restrict__ bd,
                                                   u16* __restrict__ fsd) {
    constexpr int NC = K / 32;
    constexpr int LDK = K + 8;
    __shared__ float xsbuf[4352];          // stage 32 x LDK f32 / epilogue 32 x 264 halfs
    float* xs = xsbuf;
    u16* eb = (u16*)xsbuf;
    int tid = threadIdx.x;
    int lane = tid & 63, wv = tid >> 6;
    int l15 = lane & 15, kg = lane >> 4;
    int ng = wv & 1, Tb = (wv >> 1) * 4;
    int nb = blockIdx.x * 32;

    if (K == 128) {
#pragma unroll
        for (int j = 0; j < 2; ++j) {
            int f = tid + j * 512;
            int r = f >> 5, c4 = f & 31;
            *(float4*)(xs + r * LDK + c4 * 4) = *(const float4*)(X + (size_t)(nb + r) * K + c4 * 4);
        }
    } else {
        if (tid < 256) {
            int r = tid >> 3, c4 = tid & 7;
            *(float4*)(xs + r * LDK + c4 * 4) = *(const float4*)(X + (size_t)(nb + r) * K + c4 * 4);
        }
    }
    __syncthreads();

    int ridx = ng * 16 + l15;
    FragH xf[NC];
#pragma unroll
    for (int c = 0; c < NC; ++c) {
        const float* xr = xs + ridx * LDK + c * 32 + kg * 8;
        float4 v0 = *(const float4*)xr;
        float4 v1 = *(const float4*)(xr + 4);
        xf[c].u[0] = f2h2(v0.x, v0.y);
        xf[c].u[1] = f2h2(v0.z, v0.w);
        xf[c].u[2] = f2h2(v1.x, v1.y);
        xf[c].u[3] = f2h2(v1.z, v1.w);
    }

    f32x4 acc[4];
#pragma unroll
    for (int i = 0; i < 4; ++i) acc[i] = (f32x4){0.f, 0.f, 0.f, 0.f};

#pragma unroll
    for (int i = 0; i < 4; ++i) {
        int T = Tb + i;
        const __half* wp = Wf + ((size_t)(T * NC) * 64 + lane) * 8;
#pragma unroll
        for (int c = 0; c < NC; ++c) {
            FragH wfr;
            wfr.i = *(const i32x4*)(wp + (size_t)c * 512);
            acc[i] = __builtin_amdgcn_mfma_f32_16x16x32_f16(wfr.h, xf[c].h, acc[i], 0, 0, 0);
        }
    }
    __syncthreads();

#pragma unroll
    for (int i = 0; i < 4; ++i) {
        int T = Tb + i;
        const float* bp = (T < 8) ? bs : bd;
        float4 bv = *(const float4*)(bp + (T & 7) * 16 + kg * 4);
        uint2 pk;
        pk.x = f2h2(acc[i][0] + bv.x, acc[i][1] + bv.y);
        pk.y = f2h2(acc[i][2] + bv.z, acc[i][3] + bv.w);
        int colh = (T & 7) * 16 + (T >> 3) * 128 + kg * 4;
        *(uint2*)(eb + (ng * 16 + l15) * 264 + colh) = pk;
    }
    __syncthreads();

#pragma unroll
    for (int j = 0; j < 2; ++j) {
        int f = tid + j * 512;
        int r = f >> 5, c = f & 31;
        i32x4 v = *(const i32x4*)(eb + r * 264 + c * 8);
        *(i32x4*)(fsd + (size_t)(nb + r) * 256 + c * 8) = v;
    }
}

// ---------------- GATv2 edge aggregation + head maxpool ----------------
// one wave per dst node, 4 edges per iteration: lane = (q = lane>>4 -> edge slot,
// s = lane&15 -> dims s*8..s*8+7 via one dwordx4). head = s>>2.
// ALL cross-lane via __shfl_xor (validated masks 1/2/4/8/16/32) — no DPP.
__global__ __launch_bounds__(256) void k_edge(const u16* __restrict__ fsd,
                                              const int* __restrict__ rowptr, const int* __restrict__ col,
                                              const float* __restrict__ attn, float* __restrict__ hout) {
    int w = threadIdx.x >> 6, lane = threadIdx.x & 63;
    int bid = blockIdx.x;
    int nb = (bid & 7) * 2048 + (bid >> 3);   // XCD-aware swizzle (bijective: 16384 = 8*2048)
    int n = nb * 4 + w;
    int q = lane >> 4, s = lane & 15;
    const char* fsdb = (const char*)fsd;

    // attn weights for this lane's 8 dims: head = s>>2, within-head off = (s&3)*8
    const float* ap = attn + (s >> 2) * 32 + (s & 3) * 8;
    float4 a0 = *(const float4*)ap;
    float4 a1 = *(const float4*)(ap + 4);
    const float L2E = 1.44269504089f;
    h2v av0, av1, av2, av3;
    { H2U t; t.u = f2h2(a0.x * L2E, a0.y * L2E); av0 = t.h;
      t.u = f2h2(a0.z * L2E, a0.w * L2E); av1 = t.h;
      t.u = f2h2(a1.x * L2E, a1.y * L2E); av2 = t.h;
      t.u = f2h2(a1.z * L2E, a1.w * L2E); av3 = t.h; }
    h2v neg2; neg2[0] = (_Float16)NEG; neg2[1] = (_Float16)NEG;

    // fd dims for this lane: row n, halfs 128 + s*8 -> bytes 256 + s*16
    i32x4 fdq = *(const i32x4*)(fsdb + ((size_t)n << 9) + 256 + (s << 4));
    H2U fd0, fd1, fd2, fd3;
    fd0.u = (uint32)fdq[0]; fd1.u = (uint32)fdq[1]; fd2.u = (uint32)fdq[2]; fd3.u = (uint32)fdq[3];

    int start = __builtin_amdgcn_readfirstlane(rowptr[n]);
    int end   = __builtin_amdgcn_readfirstlane(rowptr[n + 1]);
    uint32 soff = (uint32)(s << 4);

    float z = 0.f;
    float c0 = 0.f, c1 = 0.f, c2 = 0.f, c3 = 0.f, c4 = 0.f, c5 = 0.f, c6 = 0.f, c7 = 0.f;

    auto proc4 = [&](int jj, bool tail) {
        int idx = jj + q;
        if (tail) idx = (idx < end) ? idx : (end - 1);
        uint32 cc = (uint32)col[idx];                       // per-lane (4 distinct)
        i32x4 fv = *(const i32x4*)(fsdb + (((size_t)cc << 9) | soff));
        uint32 w0 = (uint32)fv[0], w1 = (uint32)fv[1], w2 = (uint32)fv[2], w3 = (uint32)fv[3];
        float sp = dot_term(w0, fd0.h, neg2, av0, 0.f);
        sp = dot_term(w1, fd1.h, neg2, av1, sp);
        sp = dot_term(w2, fd2.h, neg2, av2, sp);
        sp = dot_term(w3, fd3.h, neg2, av3, sp);
        // quad reduce (lanes 4h..4h+3 of this quarter): XOR butterfly, bits 0-1
        sp += __shfl_xor(sp, 1);
        sp += __shfl_xor(sp, 2);
        float pe = fast_exp2(sp);
        if (tail) pe = (jj + q < end) ? pe : 0.f;
        z += pe;
        fma_mix_lo(c0, pe, w0); fma_mix_hi(c1, pe, w0);
        fma_mix_lo(c2, pe, w1); fma_mix_hi(c3, pe, w1);
        fma_mix_lo(c4, pe, w2); fma_mix_hi(c5, pe, w2);
        fma_mix_lo(c6, pe, w3); fma_mix_hi(c7, pe, w3);
    };

    int j = start;
    for (; j + 8 <= end; j += 8) { proc4(j, false); proc4(j + 4, false); }
    for (; j < end; j += 4) proc4(j, true);

    // combine edge-slot quarters (lanes xor 16, 32)
    z  += __shfl_xor(z, 16);  z  += __shfl_xor(z, 32);
    c0 += __shfl_xor(c0, 16); c0 += __shfl_xor(c0, 32);
    c1 += __shfl_xor(c1, 16); c1 += __shfl_xor(c1, 32);
    c2 += __shfl_xor(c2, 16); c2 += __shfl_xor(c2, 32);
    c3 += __shfl_xor(c3, 16); c3 += __shfl_xor(c3, 32);
    c4 += __shfl_xor(c4, 16); c4 += __shfl_xor(c4, 32);
    c5 += __shfl_xor(c5, 16); c5 += __shfl_xor(c5, 32);
    c6 += __shfl_xor(c6, 16); c6 += __shfl_xor(c6, 32);
    c7 += __shfl_xor(c7, 16); c7 += __shfl_xor(c7, 32);

    float r = (z > 0.f) ? 1.f / z : 0.f;   // deg==0 -> output 0
    c0 *= r; c1 *= r; c2 *= r; c3 *= r; c4 *= r; c5 *= r; c6 *= r; c7 *= r;

    // maxpool over heads: coset {s, s^4, s^8, s^12} -> XOR butterfly, bits 2-3
    c0 = fmaxf(c0, __shfl_xor(c0, 4)); c0 = fmaxf(c0, __shfl_xor(c0, 8));
    c1 = fmaxf(c1, __shfl_xor(c1, 4)); c1 = fmaxf(c1, __shfl_xor(c1, 8));
    c2 = fmaxf(c2, __shfl_xor(c2, 4)); c2 = fmaxf(c2, __shfl_xor(c2, 8));
    c3 = fmaxf(c3, __shfl_xor(c3, 4)); c3 = fmaxf(c3, __shfl_xor(c3, 8));
    c4 = fmaxf(c4, __shfl_xor(c4, 4)); c4 = fmaxf(c4, __shfl_xor(c4, 8));
    c5 = fmaxf(c5, __shfl_xor(c5, 4)); c5 = fmaxf(c5, __shfl_xor(c5, 8));
    c6 = fmaxf(c6, __shfl_xor(c6, 4)); c6 = fmaxf(c6, __shfl_xor(c6, 8));
    c7 = fmaxf(c7, __shfl_xor(c7, 4)); c7 = fmaxf(c7, __shfl_xor(c7, 8));

    if (lane < 4) {   // lane = s = within-head block 0..3 -> dims s*8..s*8+7
        float* op = hout + ((size_t)n << 5) + (lane << 3);
        *(float4*)op = make_float4(c0, c1, c2, c3);
        *(float4*)(op + 4) = make_float4(c4, c5, c6, c7);
    }
}

// ---------------- global attention pooling ----------------
__global__ __launch_bounds__(256) void k_pool(const float* __restrict__ h2, const float* __restrict__ gW,
                                              const float* __restrict__ gb, float* __restrict__ out) {
    int b = blockIdx.x, tid = threadIdx.x;
    __shared__ float ga[NPG];
    __shared__ float red[256];
    __shared__ float gws[32];
    const float* hb = h2 + (size_t)b * NPG * 32;
    if (tid < 32) gws[tid] = gW[tid];
    __syncthreads();
    float gbv = gb[0];
    float lmax = -INFINITY;
    float gloc[4];
#pragma unroll
    for (int j = 0; j < 4; ++j) {
        int nl = tid + j * 256;
        const float* row = hb + nl * 32;
        float dot = 0.f;
#pragma unroll
        for (int c = 0; c < 32; c += 4) {
            float4 v = *(const float4*)(row + c);
            dot += v.x * gws[c] + v.y * gws[c + 1] + v.z * gws[c + 2] + v.w * gws[c + 3];
        }
        gloc[j] = dot + gbv;
        lmax = fmaxf(lmax, gloc[j]);
    }
    red[tid] = lmax; __syncthreads();
    for (int s2 = 128; s2 > 0; s2 >>= 1) { if (tid < s2) red[tid] = fmaxf(red[tid], red[tid + s2]); __syncthreads(); }
    float m = red[0];
    __syncthreads();
    float lsum = 0.f;
#pragma unroll
    for (int j = 0; j < 4; ++j) {
        int nl = tid + j * 256;
        float a = __expf(gloc[j] - m);
        ga[nl] = a;
        lsum += a;
    }
    red[tid] = lsum; __syncthreads();
    for (int s2 = 128; s2 > 0; s2 >>= 1) { if (tid < s2) red[tid] += red[tid + s2]; __syncthreads(); }
    float z = red[0];
    __syncthreads();
    int d = tid & 31, ng = tid >> 5;
    float acc = 0.f;
    for (int nl = ng; nl < NPG; nl += 8) acc += ga[nl] * hb[nl * 32 + d];
    red[tid] = acc; __syncthreads();
    if (tid < 32) {
        float s = red[tid];
#pragma unroll
        for (int g2 = 1; g2 < 8; ++g2) s += red[g2 * 32 + tid];
        out[b * 32 + tid] = s / z;
    }
}

extern "C" void kernel_launch(void* const* d_in, const int* in_sizes, int n_in,
                              void* d_out, int out_size, void* d_ws, size_t ws_size,
                              hipStream_t stream) {
    const float* x     = (const float*)d_in[0];
    const int*   src   = (const int*)d_in[1];
    const int*   dst   = (const int*)d_in[2];
    const float* Ws1   = (const float*)d_in[4];
    const float* bs1   = (const float*)d_in[5];
    const float* Wd1   = (const float*)d_in[6];
    const float* bd1   = (const float*)d_in[7];
    const float* attn1 = (const float*)d_in[8];
    const float* Ws2   = (const float*)d_in[9];
    const float* bs2   = (const float*)d_in[10];
    const float* Wd2   = (const float*)d_in[11];
    const float* bd2   = (const float*)d_in[12];
    const float* attn2 = (const float*)d_in[13];
    const float* gW    = (const float*)d_in[14];
    const float* gb    = (const float*)d_in[15];
    float* out = (float*)d_out;

    // workspace layout (~55 MB)
    u16* fsd   = (u16*)d_ws;                               // N*256 halfs (fs|fd interleaved)
    float* h1  = (float*)(fsd + (size_t)N_NODES * 256);    // N*32 f32
    float* h2  = h1 + (size_t)N_NODES * 32;                // N*32 f32
    int* rowptr = (int*)(h2 + (size_t)N_NODES * 32);       // N+1 (padded)
    int* col    = rowptr + (N_NODES + 4);                  // E
    __half* Wf1 = (__half*)(col + E_TOTAL);                // 32768 halfs
    __half* Wf2 = Wf1 + 32768;                             // 8192 halfs

    k_wfrag<<<160, 256, 0, stream>>>(Ws1, Wd1, Ws2, Wd2, Wf1, Wf2);
    k_csr<<<B_GRAPHS, 1024, 0, stream>>>(src, dst, rowptr, col);

    // layer 1
    k_gemm_mfma<128><<<N_NODES / 32, 512, 0, stream>>>(x, Wf1, bs1, bd1, fsd);
    k_edge<<<N_NODES / 4, 256, 0, stream>>>(fsd, rowptr, col, attn1, h1);

    // layer 2 (overwrites fsd)
    k_gemm_mfma<32><<<N_NODES / 32, 512, 0, stream>>>(h1, Wf2, bs2, bd2, fsd);
    k_edge<<<N_NODES / 4, 256, 0, stream>>>(fsd, rowptr, col, attn2, h2);

    // global attention pooling
    k_pool<<<B_GRAPHS, 256, 0, stream>>>(h2, gW, gb, out);
}

// Round 13
// 158.599 us; speedup vs baseline: 1.5363x; 1.0222x over previous
//
#include <hip/hip_runtime.h>
#include <hip/hip_fp16.h>
#include <math.h>

#define N_NODES 65536
#define B_GRAPHS 64
#define NPG 1024
#define EPG 16384
#define E_TOTAL (B_GRAPHS * EPG)
#define NEG 0.2f

typedef float f32x4 __attribute__((ext_vector_type(4)));
typedef _Float16 f16x8 __attribute__((ext_vector_type(8)));
typedef _Float16 h2v __attribute__((ext_vector_type(2)));
typedef int i32x4 __attribute__((ext_vector_type(4)));
typedef unsigned int uint32;
typedef unsigned short u16;

union FragH { i32x4 i; f16x8 h; uint32 u[4]; };
union H2U { uint32 u; h2v h; };

// raw v_exp_f32 (2^x) — logits bounded by construction [validated R8/R9/R12]
__device__ __forceinline__ float fast_exp2(float x) {
    float r;
    asm("v_exp_f32 %0, %1" : "=v"(r) : "v"(x));
    return r;
}

__device__ __forceinline__ uint32 f2h2(float a, float b) {
    __half2 h = __float22half2_rn(make_float2(a, b));
    return *(uint32*)&h;
}

// acc += p * f16(lo/hi of fv), f32 accumulate (v_fma_mix_f32) [validated R8/R9/R12]
__device__ __forceinline__ void fma_mix_lo(float& acc, float p, uint32 fv) {
    asm("v_fma_mix_f32 %0, %1, %2, %0 op_sel_hi:[0,1,0]" : "+v"(acc) : "v"(p), "v"(fv));
}
__device__ __forceinline__ void fma_mix_hi(float& acc, float p, uint32 fv) {
    asm("v_fma_mix_f32 %0, %1, %2, %0 op_sel:[0,1,0] op_sel_hi:[0,1,0]" : "+v"(acc) : "v"(p), "v"(fv));
}

// e = fv + fd; e = max(e, NEG*e); sp += dot2(e, av)   (f32 accumulate) [validated R8/R9/R12]
__device__ __forceinline__ float dot_term(uint32 fvu, h2v fdv, h2v neg2, h2v av, float accum) {
    H2U fv; fv.u = fvu;
    h2v e = fv.h + fdv;                  // v_pk_add_f16
    h2v en = e * neg2;                   // v_pk_mul_f16
    h2v em;
    asm("v_pk_max_f16 %0, %1, %2" : "=v"(em) : "v"(e), "v"(en));
    float sp;
    asm("v_dot2_f32_f16 %0, %1, %2, %3" : "=v"(sp) : "v"(em), "v"(av), "v"(accum));
    return sp;
}

// ---------------- CSR build: one block per graph, LDS count-sort ----------------
__global__ __launch_bounds__(1024) void k_csr(const int* __restrict__ src, const int* __restrict__ dst,
                                              int* __restrict__ rowptr, int* __restrict__ col) {
    __shared__ int cnt[NPG];
    __shared__ int tmp[NPG];
    __shared__ int scol[EPG];   // 64KB
    int g = blockIdx.x, tid = threadIdx.x;
    int ebase = g * EPG;
    cnt[tid] = 0;
    __syncthreads();
    for (int e = tid; e < EPG; e += 1024)
        atomicAdd(&cnt[dst[ebase + e] & (NPG - 1)], 1);
    __syncthreads();
    int* a = cnt; int* b = tmp;
#pragma unroll
    for (int off = 1; off < 1024; off <<= 1) {
        int u = a[tid] + ((tid >= off) ? a[tid - off] : 0);
        __syncthreads();
        b[tid] = u;
        __syncthreads();
        int* t = a; a = b; b = t;
    }
    int excl = tid ? a[tid - 1] : 0;
    rowptr[g * NPG + tid] = ebase + excl;
    if (g == B_GRAPHS - 1 && tid == 0) rowptr[N_NODES] = E_TOTAL;
    b[tid] = excl;
    __syncthreads();
    for (int e = tid; e < EPG; e += 1024) {
        int d = dst[ebase + e] & (NPG - 1);
        int p = atomicAdd(&b[d], 1);
        scol[p] = src[ebase + e];
    }
    __syncthreads();
    int4* cg = (int4*)(col + ebase);
    const int4* cs = (const int4*)scol;
    for (int i = tid; i < EPG / 4; i += 1024) cg[i] = cs[i];
}

// ---------------- W -> fragment-linear f16 ----------------
__global__ __launch_bounds__(256) void k_wfrag(const float* __restrict__ Ws1, const float* __restrict__ Wd1,
                                               const float* __restrict__ Ws2, const float* __restrict__ Wd2,
                                               __half* __restrict__ Wf1, __half* __restrict__ Wf2) {
    int id = blockIdx.x * 256 + threadIdx.x;   // 40960 total
    if (id < 32768) {
        int j = id & 7, l = (id >> 3) & 63, c = (id >> 9) & 3, T = id >> 11;
        int k = c * 32 + (l >> 4) * 8 + j;
        int n = (T & 7) * 16 + (l & 15);
        const float* W = (T < 8) ? Ws1 : Wd1;
        Wf1[id] = __float2half_rn(W[k * 128 + n]);
    } else if (id < 40960) {
        int rem = id - 32768;
        int j = rem & 7, l = (rem >> 3) & 63, T = rem >> 9;
        int k = (l >> 4) * 8 + j;
        int n = (T & 7) * 16 + (l & 15);
        const float* W = (T < 8) ? Ws2 : Wd2;
        Wf2[rem] = __float2half_rn(W[k * 128 + n]);
    }
}

// ---------------- MFMA dual GEMM, f16 single, fragment-linear W ----------------
template <int K>
__global__ __launch_bounds__(512) void k_gemm_mfma(const float* __restrict__ X,
                                                   const __half* __restrict__ Wf,
                                                   const float* __restrict__ bs, const float* __restrict__ bd,
                                                   u16* __restrict__ fsd) {
    constexpr int NC = K / 32;
    constexpr int LDK = K + 8;
    __shared__ float xsbuf[4352];          // stage 32 x LDK f32 / epilogue 32 x 264 halfs
    float* xs = xsbuf;
    u16* eb = (u16*)xsbuf;
    int tid = threadIdx.x;
    int lane = tid & 63, wv = tid >> 6;
    int l15 = lane & 15, kg = lane >> 4;
    int ng = wv & 1, Tb = (wv >> 1) * 4;
    int nb = blockIdx.x * 32;

    if (K == 128) {
#pragma unroll
        for (int j = 0; j < 2; ++j) {
            int f = tid + j * 512;
            int r = f >> 5, c4 = f & 31;
            *(float4*)(xs + r * LDK + c4 * 4) = *(const float4*)(X + (size_t)(nb + r) * K + c4 * 4);
        }
    } else {
        if (tid < 256) {
            int r = tid >> 3, c4 = tid & 7;
            *(float4*)(xs + r * LDK + c4 * 4) = *(const float4*)(X + (size_t)(nb + r) * K + c4 * 4);
        }
    }
    __syncthreads();

    int ridx = ng * 16 + l15;
    FragH xf[NC];
#pragma unroll
    for (int c = 0; c < NC; ++c) {
        const float* xr = xs + ridx * LDK + c * 32 + kg * 8;
        float4 v0 = *(const float4*)xr;
        float4 v1 = *(const float4*)(xr + 4);
        xf[c].u[0] = f2h2(v0.x, v0.y);
        xf[c].u[1] = f2h2(v0.z, v0.w);
        xf[c].u[2] = f2h2(v1.x, v1.y);
        xf[c].u[3] = f2h2(v1.z, v1.w);
    }

    f32x4 acc[4];
#pragma unroll
    for (int i = 0; i < 4; ++i) acc[i] = (f32x4){0.f, 0.f, 0.f, 0.f};

#pragma unroll
    for (int i = 0; i < 4; ++i) {
        int T = Tb + i;
        const __half* wp = Wf + ((size_t)(T * NC) * 64 + lane) * 8;
#pragma unroll
        for (int c = 0; c < NC; ++c) {
            FragH wfr;
            wfr.i = *(const i32x4*)(wp + (size_t)c * 512);
            acc[i] = __builtin_amdgcn_mfma_f32_16x16x32_f16(wfr.h, xf[c].h, acc[i], 0, 0, 0);
        }
    }
    __syncthreads();

#pragma unroll
    for (int i = 0; i < 4; ++i) {
        int T = Tb + i;
        const float* bp = (T < 8) ? bs : bd;
        float4 bv = *(const float4*)(bp + (T & 7) * 16 + kg * 4);
        uint2 pk;
        pk.x = f2h2(acc[i][0] + bv.x, acc[i][1] + bv.y);
        pk.y = f2h2(acc[i][2] + bv.z, acc[i][3] + bv.w);
        int colh = (T & 7) * 16 + (T >> 3) * 128 + kg * 4;
        *(uint2*)(eb + (ng * 16 + l15) * 264 + colh) = pk;
    }
    __syncthreads();

#pragma unroll
    for (int j = 0; j < 2; ++j) {
        int f = tid + j * 512;
        int r = f >> 5, c = f & 31;
        i32x4 v = *(const i32x4*)(eb + r * 264 + c * 8);
        *(i32x4*)(fsd + (size_t)(nb + r) * 256 + c * 8) = v;
    }
}

// ---------------- GATv2 edge aggregation + head maxpool ----------------
// 4 nodes per wave (one per 16-lane quarter): quarter q owns node nb*16 + w*4 + q,
// iterates its own CSR range serially (1 edge/iter) with per-lane predication.
// s = lane&15 -> dims s*8..s*8+7; head = s>>2. z and accumulators complete per-lane
// (no cross-quarter combine). Cross-lane via __shfl_xor only [validated R12].
__global__ __launch_bounds__(256) void k_edge(const u16* __restrict__ fsd,
                                              const int* __restrict__ rowptr, const int* __restrict__ col,
                                              const float* __restrict__ attn, float* __restrict__ hout) {
    int w = threadIdx.x >> 6, lane = threadIdx.x & 63;
    int bid = blockIdx.x;
    int nb = (bid & 7) * 512 + (bid >> 3);   // XCD-aware swizzle (bijective: 4096 = 8*512)
    int q = lane >> 4, s = lane & 15;
    int n = nb * 16 + w * 4 + q;
    const char* fsdb = (const char*)fsd;

    // attn weights for this lane's 8 dims: head = s>>2, within-head off = (s&3)*8
    const float* ap = attn + (s >> 2) * 32 + (s & 3) * 8;
    float4 a0 = *(const float4*)ap;
    float4 a1 = *(const float4*)(ap + 4);
    const float L2E = 1.44269504089f;
    h2v av0, av1, av2, av3;
    { H2U t; t.u = f2h2(a0.x * L2E, a0.y * L2E); av0 = t.h;
      t.u = f2h2(a0.z * L2E, a0.w * L2E); av1 = t.h;
      t.u = f2h2(a1.x * L2E, a1.y * L2E); av2 = t.h;
      t.u = f2h2(a1.z * L2E, a1.w * L2E); av3 = t.h; }
    h2v neg2; neg2[0] = (_Float16)NEG; neg2[1] = (_Float16)NEG;

    // fd dims for this lane's node: row n, bytes 256 + s*16
    i32x4 fdq = *(const i32x4*)(fsdb + ((size_t)n << 9) + 256 + (s << 4));
    H2U fd0, fd1, fd2, fd3;
    fd0.u = (uint32)fdq[0]; fd1.u = (uint32)fdq[1]; fd2.u = (uint32)fdq[2]; fd3.u = (uint32)fdq[3];

    int start = rowptr[n];
    int end   = rowptr[n + 1];
    int m = end - start;
    { int t16 = __shfl_xor(m, 16); m = (t16 > m) ? t16 : m;
      int t32 = __shfl_xor(m, 32); m = (t32 > m) ? t32 : m; }
    int niter = __builtin_amdgcn_readfirstlane(m);   // max degree over the 4 quarters

    uint32 soff = (uint32)(s << 4);
    float z = 0.f;
    float c0 = 0.f, c1 = 0.f, c2 = 0.f, c3 = 0.f, c4 = 0.f, c5 = 0.f, c6 = 0.f, c7 = 0.f;

#pragma unroll 2
    for (int k = 0; k < niter; ++k) {
        int idx = start + k;
        bool valid = idx < end;
        int idxc = valid ? idx : 0;                          // always in-bounds
        uint32 cc = (uint32)col[idxc] & (N_NODES - 1);       // clamp (safety)
        i32x4 fv = *(const i32x4*)(fsdb + (((size_t)cc << 9) | soff));
        uint32 w0 = (uint32)fv[0], w1 = (uint32)fv[1], w2 = (uint32)fv[2], w3 = (uint32)fv[3];
        float sp = dot_term(w0, fd0.h, neg2, av0, 0.f);
        sp = dot_term(w1, fd1.h, neg2, av1, sp);
        sp = dot_term(w2, fd2.h, neg2, av2, sp);
        sp = dot_term(w3, fd3.h, neg2, av3, sp);
        // head logit: reduce over the quad (bits 0-1)
        sp += __shfl_xor(sp, 1);
        sp += __shfl_xor(sp, 2);
        float pe = fast_exp2(sp);
        pe = valid ? pe : 0.f;
        z += pe;
        fma_mix_lo(c0, pe, w0); fma_mix_hi(c1, pe, w0);
        fma_mix_lo(c2, pe, w1); fma_mix_hi(c3, pe, w1);
        fma_mix_lo(c4, pe, w2); fma_mix_hi(c5, pe, w2);
        fma_mix_lo(c6, pe, w3); fma_mix_hi(c7, pe, w3);
    }

    float r = (z > 0.f) ? 1.f / z : 0.f;   // deg==0 -> output 0
    c0 *= r; c1 *= r; c2 *= r; c3 *= r; c4 *= r; c5 *= r; c6 *= r; c7 *= r;

    // maxpool over heads: coset {s, s^4, s^8, s^12} within the quarter (bits 2-3)
    c0 = fmaxf(c0, __shfl_xor(c0, 4)); c0 = fmaxf(c0, __shfl_xor(c0, 8));
    c1 = fmaxf(c1, __shfl_xor(c1, 4)); c1 = fmaxf(c1, __shfl_xor(c1, 8));
    c2 = fmaxf(c2, __shfl_xor(c2, 4)); c2 = fmaxf(c2, __shfl_xor(c2, 8));
    c3 = fmaxf(c3, __shfl_xor(c3, 4)); c3 = fmaxf(c3, __shfl_xor(c3, 8));
    c4 = fmaxf(c4, __shfl_xor(c4, 4)); c4 = fmaxf(c4, __shfl_xor(c4, 8));
    c5 = fmaxf(c5, __shfl_xor(c5, 4)); c5 = fmaxf(c5, __shfl_xor(c5, 8));
    c6 = fmaxf(c6, __shfl_xor(c6, 4)); c6 = fmaxf(c6, __shfl_xor(c6, 8));
    c7 = fmaxf(c7, __shfl_xor(c7, 4)); c7 = fmaxf(c7, __shfl_xor(c7, 8));

    if (s < 4) {   // s = within-head block 0..3 -> dims s*8..s*8+7 (per quarter's node)
        float* op = hout + ((size_t)n << 5) + (s << 3);
        *(float4*)op = make_float4(c0, c1, c2, c3);
        *(float4*)(op + 4) = make_float4(c4, c5, c6, c7);
    }
}

// ---------------- global attention pooling ----------------
__global__ __launch_bounds__(256) void k_pool(const float* __restrict__ h2, const float* __restrict__ gW,
                                              const float* __restrict__ gb, float* __restrict__ out) {
    int b = blockIdx.x, tid = threadIdx.x;
    __shared__ float ga[NPG];
    __shared__ float red[256];
    __shared__ float gws[32];
    const float* hb = h2 + (size_t)b * NPG * 32;
    if (tid < 32) gws[tid] = gW[tid];
    __syncthreads();
    float gbv = gb[0];
    float lmax = -INFINITY;
    float gloc[4];
#pragma unroll
    for (int j = 0; j < 4; ++j) {
        int nl = tid + j * 256;
        const float* row = hb + nl * 32;
        float dot = 0.f;
#pragma unroll
        for (int c = 0; c < 32; c += 4) {
            float4 v = *(const float4*)(row + c);
            dot += v.x * gws[c] + v.y * gws[c + 1] + v.z * gws[c + 2] + v.w * gws[c + 3];
        }
        gloc[j] = dot + gbv;
        lmax = fmaxf(lmax, gloc[j]);
    }
    red[tid] = lmax; __syncthreads();
    for (int s2 = 128; s2 > 0; s2 >>= 1) { if (tid < s2) red[tid] = fmaxf(red[tid], red[tid + s2]); __syncthreads(); }
    float m = red[0];
    __syncthreads();
    float lsum = 0.f;
#pragma unroll
    for (int j = 0; j < 4; ++j) {
        int nl = tid + j * 256;
        float a = __expf(gloc[j] - m);
        ga[nl] = a;
        lsum += a;
    }
    red[tid] = lsum; __syncthreads();
    for (int s2 = 128; s2 > 0; s2 >>= 1) { if (tid < s2) red[tid] += red[tid + s2]; __syncthreads(); }
    float z = red[0];
    __syncthreads();
    int d = tid & 31, ng = tid >> 5;
    float acc = 0.f;
    for (int nl = ng; nl < NPG; nl += 8) acc += ga[nl] * hb[nl * 32 + d];
    red[tid] = acc; __syncthreads();
    if (tid < 32) {
        float s = red[tid];
#pragma unroll
        for (int g2 = 1; g2 < 8; ++g2) s += red[g2 * 32 + tid];
        out[b * 32 + tid] = s / z;
    }
}

extern "C" void kernel_launch(void* const* d_in, const int* in_sizes, int n_in,
                              void* d_out, int out_size, void* d_ws, size_t ws_size,
                              hipStream_t stream) {
    const float* x     = (const float*)d_in[0];
    const int*   src   = (const int*)d_in[1];
    const int*   dst   = (const int*)d_in[2];
    const float* Ws1   = (const float*)d_in[4];
    const float* bs1   = (const float*)d_in[5];
    const float* Wd1   = (const float*)d_in[6];
    const float* bd1   = (const float*)d_in[7];
    const float* attn1 = (const float*)d_in[8];
    const float* Ws2   = (const float*)d_in[9];
    const float* bs2   = (const float*)d_in[10];
    const float* Wd2   = (const float*)d_in[11];
    const float* bd2   = (const float*)d_in[12];
    const float* attn2 = (const float*)d_in[13];
    const float* gW    = (const float*)d_in[14];
    const float* gb    = (const float*)d_in[15];
    float* out = (float*)d_out;

    // workspace layout (~55 MB)
    u16* fsd   = (u16*)d_ws;                               // N*256 halfs (fs|fd interleaved)
    float* h1  = (float*)(fsd + (size_t)N_NODES * 256);    // N*32 f32
    float* h2  = h1 + (size_t)N_NODES * 32;                // N*32 f32
    int* rowptr = (int*)(h2 + (size_t)N_NODES * 32);       // N+1 (padded)
    int* col    = rowptr + (N_NODES + 4);                  // E
    __half* Wf1 = (__half*)(col + E_TOTAL);                // 32768 halfs
    __half* Wf2 = Wf1 + 32768;                             // 8192 halfs

    k_wfrag<<<160, 256, 0, stream>>>(Ws1, Wd1, Ws2, Wd2, Wf1, Wf2);
    k_csr<<<B_GRAPHS, 1024, 0, stream>>>(src, dst, rowptr, col);

    // layer 1
    k_gemm_mfma<128><<<N_NODES / 32, 512, 0, stream>>>(x, Wf1, bs1, bd1, fsd);
    k_edge<<<N_NODES / 16, 256, 0, stream>>>(fsd, rowptr, col, attn1, h1);

    // layer 2 (overwrites fsd)
    k_gemm_mfma<32><<<N_NODES / 32, 512, 0, stream>>>(h1, Wf2, bs2, bd2, fsd);
    k_edge<<<N_NODES / 16, 256, 0, stream>>>(fsd, rowptr, col, attn2, h2);

    // global attention pooling
    k_pool<<<B_GRAPHS, 256, 0, stream>>>(h2, gW, gb, out);
}

// Round 14
// 148.840 us; speedup vs baseline: 1.6371x; 1.0656x over previous
//
#include <hip/hip_runtime.h>
#include <hip/hip_fp16.h>
#include <math.h>

#define N_NODES 65536
#define B_GRAPHS 64
#define NPG 1024
#define EPG 16384
#define E_TOTAL (B_GRAPHS * EPG)
#define NEG 0.2f

typedef float f32x4 __attribute__((ext_vector_type(4)));
typedef _Float16 f16x8 __attribute__((ext_vector_type(8)));
typedef _Float16 h2v __attribute__((ext_vector_type(2)));
typedef int i32x4 __attribute__((ext_vector_type(4)));
typedef unsigned int uint32;
typedef unsigned short u16;

union FragH { i32x4 i; f16x8 h; uint32 u[4]; };
union H2U { uint32 u; h2v h; };

// raw v_exp_f32 (2^x) — logits bounded by construction [validated R8/R9/R12/R13]
__device__ __forceinline__ float fast_exp2(float x) {
    float r;
    asm("v_exp_f32 %0, %1" : "=v"(r) : "v"(x));
    return r;
}

__device__ __forceinline__ uint32 f2h2(float a, float b) {
    __half2 h = __float22half2_rn(make_float2(a, b));
    return *(uint32*)&h;
}

// acc += p * f16(lo/hi of fv), f32 accumulate (v_fma_mix_f32) [validated R8+]
__device__ __forceinline__ void fma_mix_lo(float& acc, float p, uint32 fv) {
    asm("v_fma_mix_f32 %0, %1, %2, %0 op_sel_hi:[0,1,0]" : "+v"(acc) : "v"(p), "v"(fv));
}
__device__ __forceinline__ void fma_mix_hi(float& acc, float p, uint32 fv) {
    asm("v_fma_mix_f32 %0, %1, %2, %0 op_sel:[0,1,0] op_sel_hi:[0,1,0]" : "+v"(acc) : "v"(p), "v"(fv));
}

// e = fv + fd; e = max(e, NEG*e); sp += dot2(e, av)   (f32 accumulate) [validated R8+]
__device__ __forceinline__ float dot_term(uint32 fvu, h2v fdv, h2v neg2, h2v av, float accum) {
    H2U fv; fv.u = fvu;
    h2v e = fv.h + fdv;                  // v_pk_add_f16
    h2v en = e * neg2;                   // v_pk_mul_f16
    h2v em;
    asm("v_pk_max_f16 %0, %1, %2" : "=v"(em) : "v"(e), "v"(en));
    float sp;
    asm("v_dot2_f32_f16 %0, %1, %2, %3" : "=v"(sp) : "v"(em), "v"(av), "v"(accum));
    return sp;
}

// ---------------- CSR build: one block per graph, LDS count-sort ----------------
__global__ __launch_bounds__(1024) void k_csr(const int* __restrict__ src, const int* __restrict__ dst,
                                              int* __restrict__ rowptr, int* __restrict__ col) {
    __shared__ int cnt[NPG];
    __shared__ int tmp[NPG];
    __shared__ int scol[EPG];   // 64KB
    int g = blockIdx.x, tid = threadIdx.x;
    int ebase = g * EPG;
    cnt[tid] = 0;
    __syncthreads();
    for (int e = tid; e < EPG; e += 1024)
        atomicAdd(&cnt[dst[ebase + e] & (NPG - 1)], 1);
    __syncthreads();
    int* a = cnt; int* b = tmp;
#pragma unroll
    for (int off = 1; off < 1024; off <<= 1) {
        int u = a[tid] + ((tid >= off) ? a[tid - off] : 0);
        __syncthreads();
        b[tid] = u;
        __syncthreads();
        int* t = a; a = b; b = t;
    }
    int excl = tid ? a[tid - 1] : 0;
    rowptr[g * NPG + tid] = ebase + excl;
    if (g == B_GRAPHS - 1 && tid == 0) rowptr[N_NODES] = E_TOTAL;
    b[tid] = excl;
    __syncthreads();
    for (int e = tid; e < EPG; e += 1024) {
        int d = dst[ebase + e] & (NPG - 1);
        int p = atomicAdd(&b[d], 1);
        scol[p] = src[ebase + e];
    }
    __syncthreads();
    int4* cg = (int4*)(col + ebase);
    const int4* cs = (const int4*)scol;
    for (int i = tid; i < EPG / 4; i += 1024) cg[i] = cs[i];
}

// ---------------- W -> fragment-linear f16 ----------------
__global__ __launch_bounds__(256) void k_wfrag(const float* __restrict__ Ws1, const float* __restrict__ Wd1,
                                               const float* __restrict__ Ws2, const float* __restrict__ Wd2,
                                               __half* __restrict__ Wf1, __half* __restrict__ Wf2) {
    int id = blockIdx.x * 256 + threadIdx.x;   // 40960 total
    if (id < 32768) {
        int j = id & 7, l = (id >> 3) & 63, c = (id >> 9) & 3, T = id >> 11;
        int k = c * 32 + (l >> 4) * 8 + j;
        int n = (T & 7) * 16 + (l & 15);
        const float* W = (T < 8) ? Ws1 : Wd1;
        Wf1[id] = __float2half_rn(W[k * 128 + n]);
    } else if (id < 40960) {
        int rem = id - 32768;
        int j = rem & 7, l = (rem >> 3) & 63, T = rem >> 9;
        int k = (l >> 4) * 8 + j;
        int n = (T & 7) * 16 + (l & 15);
        const float* W = (T < 8) ? Ws2 : Wd2;
        Wf2[rem] = __float2half_rn(W[k * 128 + n]);
    }
}

// ---------------- MFMA dual GEMM, f16 single, fragment-linear W ----------------
template <int K>
__global__ __launch_bounds__(512) void k_gemm_mfma(const float* __restrict__ X,
                                                   const __half* __restrict__ Wf,
                                                   const float* __restrict__ bs, const float* __restrict__ bd,
                                                   u16* __restrict__ fsd) {
    constexpr int NC = K / 32;
    constexpr int LDK = K + 8;
    __shared__ float xsbuf[4352];          // stage 32 x LDK f32 / epilogue 32 x 264 halfs
    float* xs = xsbuf;
    u16* eb = (u16*)xsbuf;
    int tid = threadIdx.x;
    int lane = tid & 63, wv = tid >> 6;
    int l15 = lane & 15, kg = lane >> 4;
    int ng = wv & 1, Tb = (wv >> 1) * 4;
    int nb = blockIdx.x * 32;

    if (K == 128) {
#pragma unroll
        for (int j = 0; j < 2; ++j) {
            int f = tid + j * 512;
            int r = f >> 5, c4 = f & 31;
            *(float4*)(xs + r * LDK + c4 * 4) = *(const float4*)(X + (size_t)(nb + r) * K + c4 * 4);
        }
    } else {
        if (tid < 256) {
            int r = tid >> 3, c4 = tid & 7;
            *(float4*)(xs + r * LDK + c4 * 4) = *(const float4*)(X + (size_t)(nb + r) * K + c4 * 4);
        }
    }
    __syncthreads();

    int ridx = ng * 16 + l15;
    FragH xf[NC];
#pragma unroll
    for (int c = 0; c < NC; ++c) {
        const float* xr = xs + ridx * LDK + c * 32 + kg * 8;
        float4 v0 = *(const float4*)xr;
        float4 v1 = *(const float4*)(xr + 4);
        xf[c].u[0] = f2h2(v0.x, v0.y);
        xf[c].u[1] = f2h2(v0.z, v0.w);
        xf[c].u[2] = f2h2(v1.x, v1.y);
        xf[c].u[3] = f2h2(v1.z, v1.w);
    }

    f32x4 acc[4];
#pragma unroll
    for (int i = 0; i < 4; ++i) acc[i] = (f32x4){0.f, 0.f, 0.f, 0.f};

#pragma unroll
    for (int i = 0; i < 4; ++i) {
        int T = Tb + i;
        const __half* wp = Wf + ((size_t)(T * NC) * 64 + lane) * 8;
#pragma unroll
        for (int c = 0; c < NC; ++c) {
            FragH wfr;
            wfr.i = *(const i32x4*)(wp + (size_t)c * 512);
            acc[i] = __builtin_amdgcn_mfma_f32_16x16x32_f16(wfr.h, xf[c].h, acc[i], 0, 0, 0);
        }
    }
    __syncthreads();

#pragma unroll
    for (int i = 0; i < 4; ++i) {
        int T = Tb + i;
        const float* bp = (T < 8) ? bs : bd;
        float4 bv = *(const float4*)(bp + (T & 7) * 16 + kg * 4);
        uint2 pk;
        pk.x = f2h2(acc[i][0] + bv.x, acc[i][1] + bv.y);
        pk.y = f2h2(acc[i][2] + bv.z, acc[i][3] + bv.w);
        int colh = (T & 7) * 16 + (T >> 3) * 128 + kg * 4;
        *(uint2*)(eb + (ng * 16 + l15) * 264 + colh) = pk;
    }
    __syncthreads();

#pragma unroll
    for (int j = 0; j < 2; ++j) {
        int f = tid + j * 512;
        int r = f >> 5, c = f & 31;
        i32x4 v = *(const i32x4*)(eb + r * 264 + c * 8);
        *(i32x4*)(fsd + (size_t)(nb + r) * 256 + c * 8) = v;
    }
}

// ---------------- GATv2 edge aggregation + head maxpool ----------------
// 4 nodes per wave (one per 16-lane quarter). Per quarter: TWO independent edge
// chains (halves of the CSR range) + 1-deep fv prefetch -> 4 loads in flight.
// s = lane&15 -> dims s*8..s*8+7; head = s>>2. Cross-lane via __shfl_xor only.
__global__ __launch_bounds__(256) void k_edge(const u16* __restrict__ fsd,
                                              const int* __restrict__ rowptr, const int* __restrict__ col,
                                              const float* __restrict__ attn, float* __restrict__ hout) {
    int w = threadIdx.x >> 6, lane = threadIdx.x & 63;
    int bid = blockIdx.x;
    int nb = (bid & 7) * 512 + (bid >> 3);   // XCD-aware swizzle (bijective: 4096 = 8*512)
    int q = lane >> 4, s = lane & 15;
    int n = nb * 16 + w * 4 + q;
    const char* fsdb = (const char*)fsd;

    // attn weights for this lane's 8 dims: head = s>>2, within-head off = (s&3)*8
    const float* ap = attn + (s >> 2) * 32 + (s & 3) * 8;
    float4 a0 = *(const float4*)ap;
    float4 a1 = *(const float4*)(ap + 4);
    const float L2E = 1.44269504089f;
    h2v av0, av1, av2, av3;
    { H2U t; t.u = f2h2(a0.x * L2E, a0.y * L2E); av0 = t.h;
      t.u = f2h2(a0.z * L2E, a0.w * L2E); av1 = t.h;
      t.u = f2h2(a1.x * L2E, a1.y * L2E); av2 = t.h;
      t.u = f2h2(a1.z * L2E, a1.w * L2E); av3 = t.h; }
    h2v neg2; neg2[0] = (_Float16)NEG; neg2[1] = (_Float16)NEG;

    // fd dims for this lane's node: row n, bytes 256 + s*16
    i32x4 fdq = *(const i32x4*)(fsdb + ((size_t)n << 9) + 256 + (s << 4));
    H2U fd0, fd1, fd2, fd3;
    fd0.u = (uint32)fdq[0]; fd1.u = (uint32)fdq[1]; fd2.u = (uint32)fdq[2]; fd3.u = (uint32)fdq[3];

    int start = rowptr[n];
    int end   = rowptr[n + 1];
    int deg = end - start;
    int lenA = (deg + 1) >> 1;       // chain A: [start, start+lenA)
    int lenB = deg - lenA;           // chain B: [start+lenA, end)
    int baseB = start + lenA;
    int m = lenA;
    { int t16 = __shfl_xor(m, 16); m = (t16 > m) ? t16 : m;
      int t32 = __shfl_xor(m, 32); m = (t32 > m) ? t32 : m; }
    int niter = __builtin_amdgcn_readfirstlane(m);   // max lenA over the 4 quarters

    uint32 soff = (uint32)(s << 4);

    auto ld = [&](int idx, bool valid) -> i32x4 {
        int idxc = valid ? idx : 0;                        // col[0] always in-bounds
        uint32 cc = (uint32)col[idxc] & (N_NODES - 1);     // clamp (safety)
        return *(const i32x4*)(fsdb + (((size_t)cc << 9) | soff));
    };

    float z = 0.f;
    float c0 = 0.f, c1 = 0.f, c2 = 0.f, c3 = 0.f, c4 = 0.f, c5 = 0.f, c6 = 0.f, c7 = 0.f;

    i32x4 fvA = ld(start, 0 < lenA);
    i32x4 fvB = ld(baseB, 0 < lenB);

    for (int k = 0; k < niter; ++k) {
        bool vA = k < lenA, vB = k < lenB;
        i32x4 fA = fvA, fB = fvB;
        // prefetch next iteration's gathers (independent of this iteration's compute)
        fvA = ld(start + k + 1, k + 1 < lenA);
        fvB = ld(baseB + k + 1, k + 1 < lenB);

        uint32 a0w = (uint32)fA[0], a1w = (uint32)fA[1], a2w = (uint32)fA[2], a3w = (uint32)fA[3];
        uint32 b0w = (uint32)fB[0], b1w = (uint32)fB[1], b2w = (uint32)fB[2], b3w = (uint32)fB[3];

        float spA = dot_term(a0w, fd0.h, neg2, av0, 0.f);
        spA = dot_term(a1w, fd1.h, neg2, av1, spA);
        spA = dot_term(a2w, fd2.h, neg2, av2, spA);
        spA = dot_term(a3w, fd3.h, neg2, av3, spA);
        float spB = dot_term(b0w, fd0.h, neg2, av0, 0.f);
        spB = dot_term(b1w, fd1.h, neg2, av1, spB);
        spB = dot_term(b2w, fd2.h, neg2, av2, spB);
        spB = dot_term(b3w, fd3.h, neg2, av3, spB);
        // head logit: reduce over the quad (bits 0-1)
        spA += __shfl_xor(spA, 1); spA += __shfl_xor(spA, 2);
        spB += __shfl_xor(spB, 1); spB += __shfl_xor(spB, 2);
        float pA = fast_exp2(spA); pA = vA ? pA : 0.f;
        float pB = fast_exp2(spB); pB = vB ? pB : 0.f;
        z += pA; z += pB;
        fma_mix_lo(c0, pA, a0w); fma_mix_hi(c1, pA, a0w);
        fma_mix_lo(c2, pA, a1w); fma_mix_hi(c3, pA, a1w);
        fma_mix_lo(c4, pA, a2w); fma_mix_hi(c5, pA, a2w);
        fma_mix_lo(c6, pA, a3w); fma_mix_hi(c7, pA, a3w);
        fma_mix_lo(c0, pB, b0w); fma_mix_hi(c1, pB, b0w);
        fma_mix_lo(c2, pB, b1w); fma_mix_hi(c3, pB, b1w);
        fma_mix_lo(c4, pB, b2w); fma_mix_hi(c5, pB, b2w);
        fma_mix_lo(c6, pB, b3w); fma_mix_hi(c7, pB, b3w);
    }

    float r = (z > 0.f) ? 1.f / z : 0.f;   // deg==0 -> output 0
    c0 *= r; c1 *= r; c2 *= r; c3 *= r; c4 *= r; c5 *= r; c6 *= r; c7 *= r;

    // maxpool over heads: coset {s, s^4, s^8, s^12} within the quarter (bits 2-3)
    c0 = fmaxf(c0, __shfl_xor(c0, 4)); c0 = fmaxf(c0, __shfl_xor(c0, 8));
    c1 = fmaxf(c1, __shfl_xor(c1, 4)); c1 = fmaxf(c1, __shfl_xor(c1, 8));
    c2 = fmaxf(c2, __shfl_xor(c2, 4)); c2 = fmaxf(c2, __shfl_xor(c2, 8));
    c3 = fmaxf(c3, __shfl_xor(c3, 4)); c3 = fmaxf(c3, __shfl_xor(c3, 8));
    c4 = fmaxf(c4, __shfl_xor(c4, 4)); c4 = fmaxf(c4, __shfl_xor(c4, 8));
    c5 = fmaxf(c5, __shfl_xor(c5, 4)); c5 = fmaxf(c5, __shfl_xor(c5, 8));
    c6 = fmaxf(c6, __shfl_xor(c6, 4)); c6 = fmaxf(c6, __shfl_xor(c6, 8));
    c7 = fmaxf(c7, __shfl_xor(c7, 4)); c7 = fmaxf(c7, __shfl_xor(c7, 8));

    if (s < 4) {   // s = within-head block 0..3 -> dims s*8..s*8+7 (per quarter's node)
        float* op = hout + ((size_t)n << 5) + (s << 3);
        *(float4*)op = make_float4(c0, c1, c2, c3);
        *(float4*)(op + 4) = make_float4(c4, c5, c6, c7);
    }
}

// ---------------- global attention pooling ----------------
__global__ __launch_bounds__(256) void k_pool(const float* __restrict__ h2, const float* __restrict__ gW,
                                              const float* __restrict__ gb, float* __restrict__ out) {
    int b = blockIdx.x, tid = threadIdx.x;
    __shared__ float ga[NPG];
    __shared__ float red[256];
    __shared__ float gws[32];
    const float* hb = h2 + (size_t)b * NPG * 32;
    if (tid < 32) gws[tid] = gW[tid];
    __syncthreads();
    float gbv = gb[0];
    float lmax = -INFINITY;
    float gloc[4];
#pragma unroll
    for (int j = 0; j < 4; ++j) {
        int nl = tid + j * 256;
        const float* row = hb + nl * 32;
        float dot = 0.f;
#pragma unroll
        for (int c = 0; c < 32; c += 4) {
            float4 v = *(const float4*)(row + c);
            dot += v.x * gws[c] + v.y * gws[c + 1] + v.z * gws[c + 2] + v.w * gws[c + 3];
        }
        gloc[j] = dot + gbv;
        lmax = fmaxf(lmax, gloc[j]);
    }
    red[tid] = lmax; __syncthreads();
    for (int s2 = 128; s2 > 0; s2 >>= 1) { if (tid < s2) red[tid] = fmaxf(red[tid], red[tid + s2]); __syncthreads(); }
    float m = red[0];
    __syncthreads();
    float lsum = 0.f;
#pragma unroll
    for (int j = 0; j < 4; ++j) {
        int nl = tid + j * 256;
        float a = __expf(gloc[j] - m);
        ga[nl] = a;
        lsum += a;
    }
    red[tid] = lsum; __syncthreads();
    for (int s2 = 128; s2 > 0; s2 >>= 1) { if (tid < s2) red[tid] += red[tid + s2]; __syncthreads(); }
    float z = red[0];
    __syncthreads();
    int d = tid & 31, ng = tid >> 5;
    float acc = 0.f;
    for (int nl = ng; nl < NPG; nl += 8) acc += ga[nl] * hb[nl * 32 + d];
    red[tid] = acc; __syncthreads();
    if (tid < 32) {
        float s = red[tid];
#pragma unroll
        for (int g2 = 1; g2 < 8; ++g2) s += red[g2 * 32 + tid];
        out[b * 32 + tid] = s / z;
    }
}

extern "C" void kernel_launch(void* const* d_in, const int* in_sizes, int n_in,
                              void* d_out, int out_size, void* d_ws, size_t ws_size,
                              hipStream_t stream) {
    const float* x     = (const float*)d_in[0];
    const int*   src   = (const int*)d_in[1];
    const int*   dst   = (const int*)d_in[2];
    const float* Ws1   = (const float*)d_in[4];
    const float* bs1   = (const float*)d_in[5];
    const float* Wd1   = (const float*)d_in[6];
    const float* bd1   = (const float*)d_in[7];
    const float* attn1 = (const float*)d_in[8];
    const float* Ws2   = (const float*)d_in[9];
    const float* bs2   = (const float*)d_in[10];
    const float* Wd2   = (const float*)d_in[11];
    const float* bd2   = (const float*)d_in[12];
    const float* attn2 = (const float*)d_in[13];
    const float* gW    = (const float*)d_in[14];
    const float* gb    = (const float*)d_in[15];
    float* out = (float*)d_out;

    // workspace layout (~55 MB)
    u16* fsd   = (u16*)d_ws;                               // N*256 halfs (fs|fd interleaved)
    float* h1  = (float*)(fsd + (size_t)N_NODES * 256);    // N*32 f32
    float* h2  = h1 + (size_t)N_NODES * 32;                // N*32 f32
    int* rowptr = (int*)(h2 + (size_t)N_NODES * 32);       // N+1 (padded)
    int* col    = rowptr + (N_NODES + 4);                  // E
    __half* Wf1 = (__half*)(col + E_TOTAL);                // 32768 halfs
    __half* Wf2 = Wf1 + 32768;                             // 8192 halfs

    k_wfrag<<<160, 256, 0, stream>>>(Ws1, Wd1, Ws2, Wd2, Wf1, Wf2);
    k_csr<<<B_GRAPHS, 1024, 0, stream>>>(src, dst, rowptr, col);

    // layer 1
    k_gemm_mfma<128><<<N_NODES / 32, 512, 0, stream>>>(x, Wf1, bs1, bd1, fsd);
    k_edge<<<N_NODES / 16, 256, 0, stream>>>(fsd, rowptr, col, attn1, h1);

    // layer 2 (overwrites fsd)
    k_gemm_mfma<32><<<N_NODES / 32, 512, 0, stream>>>(h1, Wf2, bs2, bd2, fsd);
    k_edge<<<N_NODES / 16, 256, 0, stream>>>(fsd, rowptr, col, attn2, h2);

    // global attention pooling
    k_pool<<<B_GRAPHS, 256, 0, stream>>>(h2, gW, gb, out);
}

// Round 15
// 148.306 us; speedup vs baseline: 1.6430x; 1.0036x over previous
//
#include <hip/hip_runtime.h>
#include <hip/hip_fp16.h>
#include <math.h>

#define N_NODES 65536
#define B_GRAPHS 64
#define NPG 1024
#define EPG 16384
#define E_TOTAL (B_GRAPHS * EPG)
#define NEG 0.2f

typedef float f32x4 __attribute__((ext_vector_type(4)));
typedef _Float16 f16x8 __attribute__((ext_vector_type(8)));
typedef _Float16 h2v __attribute__((ext_vector_type(2)));
typedef int i32x4 __attribute__((ext_vector_type(4)));
typedef unsigned int uint32;
typedef unsigned short u16;

union FragH { i32x4 i; f16x8 h; uint32 u[4]; };
union H2U { uint32 u; h2v h; };

// raw v_exp_f32 (2^x) — logits bounded by construction [validated R8+]
__device__ __forceinline__ float fast_exp2(float x) {
    float r;
    asm("v_exp_f32 %0, %1" : "=v"(r) : "v"(x));
    return r;
}

__device__ __forceinline__ uint32 f2h2(float a, float b) {
    __half2 h = __float22half2_rn(make_float2(a, b));
    return *(uint32*)&h;
}

// acc += p * f16(lo/hi of fv), f32 accumulate (v_fma_mix_f32) [validated R8+]
__device__ __forceinline__ void fma_mix_lo(float& acc, float p, uint32 fv) {
    asm("v_fma_mix_f32 %0, %1, %2, %0 op_sel_hi:[0,1,0]" : "+v"(acc) : "v"(p), "v"(fv));
}
__device__ __forceinline__ void fma_mix_hi(float& acc, float p, uint32 fv) {
    asm("v_fma_mix_f32 %0, %1, %2, %0 op_sel:[0,1,0] op_sel_hi:[0,1,0]" : "+v"(acc) : "v"(p), "v"(fv));
}

// e = fv + fd; e = max(e, NEG*e); sp += dot2(e, av)   (f32 accumulate) [validated R8+]
__device__ __forceinline__ float dot_term(uint32 fvu, h2v fdv, h2v neg2, h2v av, float accum) {
    H2U fv; fv.u = fvu;
    h2v e = fv.h + fdv;                  // v_pk_add_f16
    h2v en = e * neg2;                   // v_pk_mul_f16
    h2v em;
    asm("v_pk_max_f16 %0, %1, %2" : "=v"(em) : "v"(e), "v"(en));
    float sp;
    asm("v_dot2_f32_f16 %0, %1, %2, %3" : "=v"(sp) : "v"(em), "v"(av), "v"(accum));
    return sp;
}

// ---------------- CSR build: one block per graph, LDS count-sort ----------------
__global__ __launch_bounds__(1024) void k_csr(const int* __restrict__ src, const int* __restrict__ dst,
                                              int* __restrict__ rowptr, int* __restrict__ col) {
    __shared__ int cnt[NPG];
    __shared__ int tmp[NPG];
    __shared__ int scol[EPG];   // 64KB
    int g = blockIdx.x, tid = threadIdx.x;
    int ebase = g * EPG;
    cnt[tid] = 0;
    __syncthreads();
    for (int e = tid; e < EPG; e += 1024)
        atomicAdd(&cnt[dst[ebase + e] & (NPG - 1)], 1);
    __syncthreads();
    int* a = cnt; int* b = tmp;
#pragma unroll
    for (int off = 1; off < 1024; off <<= 1) {
        int u = a[tid] + ((tid >= off) ? a[tid - off] : 0);
        __syncthreads();
        b[tid] = u;
        __syncthreads();
        int* t = a; a = b; b = t;
    }
    int excl = tid ? a[tid - 1] : 0;
    rowptr[g * NPG + tid] = ebase + excl;
    if (g == B_GRAPHS - 1 && tid == 0) rowptr[N_NODES] = E_TOTAL;
    b[tid] = excl;
    __syncthreads();
    for (int e = tid; e < EPG; e += 1024) {
        int d = dst[ebase + e] & (NPG - 1);
        int p = atomicAdd(&b[d], 1);
        scol[p] = src[ebase + e];
    }
    __syncthreads();
    int4* cg = (int4*)(col + ebase);
    const int4* cs = (const int4*)scol;
    for (int i = tid; i < EPG / 4; i += 1024) cg[i] = cs[i];
}

// ---------------- W -> fragment-linear f16 ----------------
__global__ __launch_bounds__(256) void k_wfrag(const float* __restrict__ Ws1, const float* __restrict__ Wd1,
                                               const float* __restrict__ Ws2, const float* __restrict__ Wd2,
                                               __half* __restrict__ Wf1, __half* __restrict__ Wf2) {
    int id = blockIdx.x * 256 + threadIdx.x;   // 40960 total
    if (id < 32768) {
        int j = id & 7, l = (id >> 3) & 63, c = (id >> 9) & 3, T = id >> 11;
        int k = c * 32 + (l >> 4) * 8 + j;
        int n = (T & 7) * 16 + (l & 15);
        const float* W = (T < 8) ? Ws1 : Wd1;
        Wf1[id] = __float2half_rn(W[k * 128 + n]);
    } else if (id < 40960) {
        int rem = id - 32768;
        int j = rem & 7, l = (rem >> 3) & 63, T = rem >> 9;
        int k = (l >> 4) * 8 + j;
        int n = (T & 7) * 16 + (l & 15);
        const float* W = (T < 8) ? Ws2 : Wd2;
        Wf2[rem] = __float2half_rn(W[k * 128 + n]);
    }
}

// ---------------- MFMA dual GEMM, f16 single, fragment-linear W ----------------
template <int K>
__global__ __launch_bounds__(512) void k_gemm_mfma(const float* __restrict__ X,
                                                   const __half* __restrict__ Wf,
                                                   const float* __restrict__ bs, const float* __restrict__ bd,
                                                   u16* __restrict__ fsd) {
    constexpr int NC = K / 32;
    constexpr int LDK = K + 8;
    __shared__ float xsbuf[4352];          // stage 32 x LDK f32 / epilogue 32 x 264 halfs
    float* xs = xsbuf;
    u16* eb = (u16*)xsbuf;
    int tid = threadIdx.x;
    int lane = tid & 63, wv = tid >> 6;
    int l15 = lane & 15, kg = lane >> 4;
    int ng = wv & 1, Tb = (wv >> 1) * 4;
    int nb = blockIdx.x * 32;

    if (K == 128) {
#pragma unroll
        for (int j = 0; j < 2; ++j) {
            int f = tid + j * 512;
            int r = f >> 5, c4 = f & 31;
            *(float4*)(xs + r * LDK + c4 * 4) = *(const float4*)(X + (size_t)(nb + r) * K + c4 * 4);
        }
    } else {
        if (tid < 256) {
            int r = tid >> 3, c4 = tid & 7;
            *(float4*)(xs + r * LDK + c4 * 4) = *(const float4*)(X + (size_t)(nb + r) * K + c4 * 4);
        }
    }
    __syncthreads();

    int ridx = ng * 16 + l15;
    FragH xf[NC];
#pragma unroll
    for (int c = 0; c < NC; ++c) {
        const float* xr = xs + ridx * LDK + c * 32 + kg * 8;
        float4 v0 = *(const float4*)xr;
        float4 v1 = *(const float4*)(xr + 4);
        xf[c].u[0] = f2h2(v0.x, v0.y);
        xf[c].u[1] = f2h2(v0.z, v0.w);
        xf[c].u[2] = f2h2(v1.x, v1.y);
        xf[c].u[3] = f2h2(v1.z, v1.w);
    }

    f32x4 acc[4];
#pragma unroll
    for (int i = 0; i < 4; ++i) acc[i] = (f32x4){0.f, 0.f, 0.f, 0.f};

#pragma unroll
    for (int i = 0; i < 4; ++i) {
        int T = Tb + i;
        const __half* wp = Wf + ((size_t)(T * NC) * 64 + lane) * 8;
#pragma unroll
        for (int c = 0; c < NC; ++c) {
            FragH wfr;
            wfr.i = *(const i32x4*)(wp + (size_t)c * 512);
            acc[i] = __builtin_amdgcn_mfma_f32_16x16x32_f16(wfr.h, xf[c].h, acc[i], 0, 0, 0);
        }
    }
    __syncthreads();

#pragma unroll
    for (int i = 0; i < 4; ++i) {
        int T = Tb + i;
        const float* bp = (T < 8) ? bs : bd;
        float4 bv = *(const float4*)(bp + (T & 7) * 16 + kg * 4);
        uint2 pk;
        pk.x = f2h2(acc[i][0] + bv.x, acc[i][1] + bv.y);
        pk.y = f2h2(acc[i][2] + bv.z, acc[i][3] + bv.w);
        int colh = (T & 7) * 16 + (T >> 3) * 128 + kg * 4;
        *(uint2*)(eb + (ng * 16 + l15) * 264 + colh) = pk;
    }
    __syncthreads();

#pragma unroll
    for (int j = 0; j < 2; ++j) {
        int f = tid + j * 512;
        int r = f >> 5, c = f & 31;
        i32x4 v = *(const i32x4*)(eb + r * 264 + c * 8);
        *(i32x4*)(fsd + (size_t)(nb + r) * 256 + c * 8) = v;
    }
}

// ---------------- GATv2 edge aggregation + head maxpool ----------------
// 4 nodes per wave (one per 16-lane quarter). Per quarter: FOUR interleaved edge
// chains (chain i = edges start+4k+i) each with 1-deep fv prefetch -> 8 gathers
// in flight. s = lane&15 -> dims s*8..s*8+7; head = s>>2. shfl_xor only.
__global__ __launch_bounds__(256) void k_edge(const u16* __restrict__ fsd,
                                              const int* __restrict__ rowptr, const int* __restrict__ col,
                                              const float* __restrict__ attn, float* __restrict__ hout) {
    int w = threadIdx.x >> 6, lane = threadIdx.x & 63;
    int bid = blockIdx.x;
    int nb = (bid & 7) * 512 + (bid >> 3);   // XCD-aware swizzle (bijective: 4096 = 8*512)
    int q = lane >> 4, s = lane & 15;
    int n = nb * 16 + w * 4 + q;
    const char* fsdb = (const char*)fsd;

    // attn weights for this lane's 8 dims: head = s>>2, within-head off = (s&3)*8
    const float* ap = attn + (s >> 2) * 32 + (s & 3) * 8;
    float4 a0 = *(const float4*)ap;
    float4 a1 = *(const float4*)(ap + 4);
    const float L2E = 1.44269504089f;
    h2v av0, av1, av2, av3;
    { H2U t; t.u = f2h2(a0.x * L2E, a0.y * L2E); av0 = t.h;
      t.u = f2h2(a0.z * L2E, a0.w * L2E); av1 = t.h;
      t.u = f2h2(a1.x * L2E, a1.y * L2E); av2 = t.h;
      t.u = f2h2(a1.z * L2E, a1.w * L2E); av3 = t.h; }
    h2v neg2; neg2[0] = (_Float16)NEG; neg2[1] = (_Float16)NEG;

    // fd dims for this lane's node: row n, bytes 256 + s*16
    i32x4 fdq = *(const i32x4*)(fsdb + ((size_t)n << 9) + 256 + (s << 4));
    H2U fd0, fd1, fd2, fd3;
    fd0.u = (uint32)fdq[0]; fd1.u = (uint32)fdq[1]; fd2.u = (uint32)fdq[2]; fd3.u = (uint32)fdq[3];

    int start = rowptr[n];
    int end   = rowptr[n + 1];
    int deg = end - start;
    int m = deg;
    { int t16 = __shfl_xor(m, 16); m = (t16 > m) ? t16 : m;
      int t32 = __shfl_xor(m, 32); m = (t32 > m) ? t32 : m; }
    int niter = (__builtin_amdgcn_readfirstlane(m) + 3) >> 2;   // ceil(maxdeg/4)

    uint32 soff = (uint32)(s << 4);

    // e = edge ordinal within this node's range
    auto ld = [&](int e) -> i32x4 {
        int idxc = (e < deg) ? (start + e) : 0;            // col[0] always in-bounds
        uint32 cc = (uint32)col[idxc] & (N_NODES - 1);     // clamp (safety)
        return *(const i32x4*)(fsdb + (((size_t)cc << 9) | soff));
    };

    float z = 0.f;
    float c0 = 0.f, c1 = 0.f, c2 = 0.f, c3 = 0.f, c4 = 0.f, c5 = 0.f, c6 = 0.f, c7 = 0.f;

    i32x4 fv0 = ld(0), fv1 = ld(1), fv2 = ld(2), fv3 = ld(3);

    auto proc = [&](i32x4 f, int e) {
        uint32 w0 = (uint32)f[0], w1 = (uint32)f[1], w2 = (uint32)f[2], w3 = (uint32)f[3];
        float sp = dot_term(w0, fd0.h, neg2, av0, 0.f);
        sp = dot_term(w1, fd1.h, neg2, av1, sp);
        sp = dot_term(w2, fd2.h, neg2, av2, sp);
        sp = dot_term(w3, fd3.h, neg2, av3, sp);
        sp += __shfl_xor(sp, 1);     // head logit: quad reduce (bits 0-1)
        sp += __shfl_xor(sp, 2);
        float pe = fast_exp2(sp);
        pe = (e < deg) ? pe : 0.f;
        z += pe;
        fma_mix_lo(c0, pe, w0); fma_mix_hi(c1, pe, w0);
        fma_mix_lo(c2, pe, w1); fma_mix_hi(c3, pe, w1);
        fma_mix_lo(c4, pe, w2); fma_mix_hi(c5, pe, w2);
        fma_mix_lo(c6, pe, w3); fma_mix_hi(c7, pe, w3);
    };

    for (int k = 0; k < niter; ++k) {
        int e = k * 4;
        i32x4 a = fv0, b = fv1, c = fv2, d = fv3;
        // prefetch next iteration's gathers (independent of this iteration's compute)
        fv0 = ld(e + 4); fv1 = ld(e + 5); fv2 = ld(e + 6); fv3 = ld(e + 7);
        proc(a, e + 0);
        proc(b, e + 1);
        proc(c, e + 2);
        proc(d, e + 3);
    }

    float r = (z > 0.f) ? 1.f / z : 0.f;   // deg==0 -> output 0
    c0 *= r; c1 *= r; c2 *= r; c3 *= r; c4 *= r; c5 *= r; c6 *= r; c7 *= r;

    // maxpool over heads: coset {s, s^4, s^8, s^12} within the quarter (bits 2-3)
    c0 = fmaxf(c0, __shfl_xor(c0, 4)); c0 = fmaxf(c0, __shfl_xor(c0, 8));
    c1 = fmaxf(c1, __shfl_xor(c1, 4)); c1 = fmaxf(c1, __shfl_xor(c1, 8));
    c2 = fmaxf(c2, __shfl_xor(c2, 4)); c2 = fmaxf(c2, __shfl_xor(c2, 8));
    c3 = fmaxf(c3, __shfl_xor(c3, 4)); c3 = fmaxf(c3, __shfl_xor(c3, 8));
    c4 = fmaxf(c4, __shfl_xor(c4, 4)); c4 = fmaxf(c4, __shfl_xor(c4, 8));
    c5 = fmaxf(c5, __shfl_xor(c5, 4)); c5 = fmaxf(c5, __shfl_xor(c5, 8));
    c6 = fmaxf(c6, __shfl_xor(c6, 4)); c6 = fmaxf(c6, __shfl_xor(c6, 8));
    c7 = fmaxf(c7, __shfl_xor(c7, 4)); c7 = fmaxf(c7, __shfl_xor(c7, 8));

    if (s < 4) {   // s = within-head block 0..3 -> dims s*8..s*8+7 (per quarter's node)
        float* op = hout + ((size_t)n << 5) + (s << 3);
        *(float4*)op = make_float4(c0, c1, c2, c3);
        *(float4*)(op + 4) = make_float4(c4, c5, c6, c7);
    }
}

// ---------------- global attention pooling ----------------
__global__ __launch_bounds__(256) void k_pool(const float* __restrict__ h2, const float* __restrict__ gW,
                                              const float* __restrict__ gb, float* __restrict__ out) {
    int b = blockIdx.x, tid = threadIdx.x;
    __shared__ float ga[NPG];
    __shared__ float red[256];
    __shared__ float gws[32];
    const float* hb = h2 + (size_t)b * NPG * 32;
    if (tid < 32) gws[tid] = gW[tid];
    __syncthreads();
    float gbv = gb[0];
    float lmax = -INFINITY;
    float gloc[4];
#pragma unroll
    for (int j = 0; j < 4; ++j) {
        int nl = tid + j * 256;
        const float* row = hb + nl * 32;
        float dot = 0.f;
#pragma unroll
        for (int c = 0; c < 32; c += 4) {
            float4 v = *(const float4*)(row + c);
            dot += v.x * gws[c] + v.y * gws[c + 1] + v.z * gws[c + 2] + v.w * gws[c + 3];
        }
        gloc[j] = dot + gbv;
        lmax = fmaxf(lmax, gloc[j]);
    }
    red[tid] = lmax; __syncthreads();
    for (int s2 = 128; s2 > 0; s2 >>= 1) { if (tid < s2) red[tid] = fmaxf(red[tid], red[tid + s2]); __syncthreads(); }
    float m = red[0];
    __syncthreads();
    float lsum = 0.f;
#pragma unroll
    for (int j = 0; j < 4; ++j) {
        int nl = tid + j * 256;
        float a = __expf(gloc[j] - m);
        ga[nl] = a;
        lsum += a;
    }
    red[tid] = lsum; __syncthreads();
    for (int s2 = 128; s2 > 0; s2 >>= 1) { if (tid < s2) red[tid] += red[tid + s2]; __syncthreads(); }
    float z = red[0];
    __syncthreads();
    int d = tid & 31, ng = tid >> 5;
    float acc = 0.f;
    for (int nl = ng; nl < NPG; nl += 8) acc += ga[nl] * hb[nl * 32 + d];
    red[tid] = acc; __syncthreads();
    if (tid < 32) {
        float s = red[tid];
#pragma unroll
        for (int g2 = 1; g2 < 8; ++g2) s += red[g2 * 32 + tid];
        out[b * 32 + tid] = s / z;
    }
}

extern "C" void kernel_launch(void* const* d_in, const int* in_sizes, int n_in,
                              void* d_out, int out_size, void* d_ws, size_t ws_size,
                              hipStream_t stream) {
    const float* x     = (const float*)d_in[0];
    const int*   src   = (const int*)d_in[1];
    const int*   dst   = (const int*)d_in[2];
    const float* Ws1   = (const float*)d_in[4];
    const float* bs1   = (const float*)d_in[5];
    const float* Wd1   = (const float*)d_in[6];
    const float* bd1   = (const float*)d_in[7];
    const float* attn1 = (const float*)d_in[8];
    const float* Ws2   = (const float*)d_in[9];
    const float* bs2   = (const float*)d_in[10];
    const float* Wd2   = (const float*)d_in[11];
    const float* bd2   = (const float*)d_in[12];
    const float* attn2 = (const float*)d_in[13];
    const float* gW    = (const float*)d_in[14];
    const float* gb    = (const float*)d_in[15];
    float* out = (float*)d_out;

    // workspace layout (~55 MB)
    u16* fsd   = (u16*)d_ws;                               // N*256 halfs (fs|fd interleaved)
    float* h1  = (float*)(fsd + (size_t)N_NODES * 256);    // N*32 f32
    float* h2  = h1 + (size_t)N_NODES * 32;                // N*32 f32
    int* rowptr = (int*)(h2 + (size_t)N_NODES * 32);       // N+1 (padded)
    int* col    = rowptr + (N_NODES + 4);                  // E
    __half* Wf1 = (__half*)(col + E_TOTAL);                // 32768 halfs
    __half* Wf2 = Wf1 + 32768;                             // 8192 halfs

    k_wfrag<<<160, 256, 0, stream>>>(Ws1, Wd1, Ws2, Wd2, Wf1, Wf2);
    k_csr<<<B_GRAPHS, 1024, 0, stream>>>(src, dst, rowptr, col);

    // layer 1
    k_gemm_mfma<128><<<N_NODES / 32, 512, 0, stream>>>(x, Wf1, bs1, bd1, fsd);
    k_edge<<<N_NODES / 16, 256, 0, stream>>>(fsd, rowptr, col, attn1, h1);

    // layer 2 (overwrites fsd)
    k_gemm_mfma<32><<<N_NODES / 32, 512, 0, stream>>>(h1, Wf2, bs2, bd2, fsd);
    k_edge<<<N_NODES / 16, 256, 0, stream>>>(fsd, rowptr, col, attn2, h2);

    // global attention pooling
    k_pool<<<B_GRAPHS, 256, 0, stream>>>(h2, gW, gb, out);
}

// Round 16
// 143.455 us; speedup vs baseline: 1.6985x; 1.0338x over previous
//
#include <hip/hip_runtime.h>
#include <hip/hip_fp16.h>
#include <math.h>

#define N_NODES 65536
#define B_GRAPHS 64
#define NPG 1024
#define EPG 16384
#define E_TOTAL (B_GRAPHS * EPG)
#define NEG 0.2f

typedef float f32x4 __attribute__((ext_vector_type(4)));
typedef _Float16 f16x8 __attribute__((ext_vector_type(8)));
typedef _Float16 h2v __attribute__((ext_vector_type(2)));
typedef int i32x4 __attribute__((ext_vector_type(4)));
typedef unsigned int uint32;
typedef unsigned short u16;

union FragH { i32x4 i; f16x8 h; uint32 u[4]; };
union H2U { uint32 u; h2v h; };

// raw v_exp_f32 (2^x) — logits bounded by construction [validated R8+]
__device__ __forceinline__ float fast_exp2(float x) {
    float r;
    asm("v_exp_f32 %0, %1" : "=v"(r) : "v"(x));
    return r;
}

__device__ __forceinline__ uint32 f2h2(float a, float b) {
    __half2 h = __float22half2_rn(make_float2(a, b));
    return *(uint32*)&h;
}

// acc += p * f16(lo/hi of fv), f32 accumulate (v_fma_mix_f32) [validated R8+]
__device__ __forceinline__ void fma_mix_lo(float& acc, float p, uint32 fv) {
    asm("v_fma_mix_f32 %0, %1, %2, %0 op_sel_hi:[0,1,0]" : "+v"(acc) : "v"(p), "v"(fv));
}
__device__ __forceinline__ void fma_mix_hi(float& acc, float p, uint32 fv) {
    asm("v_fma_mix_f32 %0, %1, %2, %0 op_sel:[0,1,0] op_sel_hi:[0,1,0]" : "+v"(acc) : "v"(p), "v"(fv));
}

// e = fv + fd; e = max(e, NEG*e); sp += dot2(e, av)   (f32 accumulate) [validated R8+]
__device__ __forceinline__ float dot_term(uint32 fvu, h2v fdv, h2v neg2, h2v av, float accum) {
    H2U fv; fv.u = fvu;
    h2v e = fv.h + fdv;                  // v_pk_add_f16
    h2v en = e * neg2;                   // v_pk_mul_f16
    h2v em;
    asm("v_pk_max_f16 %0, %1, %2" : "=v"(em) : "v"(e), "v"(en));
    float sp;
    asm("v_dot2_f32_f16 %0, %1, %2, %3" : "=v"(sp) : "v"(em), "v"(av), "v"(accum));
    return sp;
}

// ---------------- prep: CSR count-sort (blocks 0..63) + W fragment conversion ----------------
__global__ __launch_bounds__(1024) void k_prep(const int* __restrict__ src, const int* __restrict__ dst,
                                               int* __restrict__ rowptr, int* __restrict__ col,
                                               const float* __restrict__ Ws1, const float* __restrict__ Wd1,
                                               const float* __restrict__ Ws2, const float* __restrict__ Wd2,
                                               __half* __restrict__ Wf1, __half* __restrict__ Wf2) {
    __shared__ int cnt[NPG];
    __shared__ int tmp[NPG];
    __shared__ int scol[EPG];   // 64KB
    if (blockIdx.x >= B_GRAPHS) {
        // W -> fragment-linear f16 (40 blocks x 1024 threads = 40960 items)
        int id = (blockIdx.x - B_GRAPHS) * 1024 + threadIdx.x;
        if (id < 32768) {
            int j = id & 7, l = (id >> 3) & 63, c = (id >> 9) & 3, T = id >> 11;
            int k = c * 32 + (l >> 4) * 8 + j;
            int n = (T & 7) * 16 + (l & 15);
            const float* W = (T < 8) ? Ws1 : Wd1;
            Wf1[id] = __float2half_rn(W[k * 128 + n]);
        } else if (id < 40960) {
            int rem = id - 32768;
            int j = rem & 7, l = (rem >> 3) & 63, T = rem >> 9;
            int k = (l >> 4) * 8 + j;
            int n = (T & 7) * 16 + (l & 15);
            const float* W = (T < 8) ? Ws2 : Wd2;
            Wf2[rem] = __float2half_rn(W[k * 128 + n]);
        }
        return;
    }
    int g = blockIdx.x, tid = threadIdx.x;
    int ebase = g * EPG;
    cnt[tid] = 0;
    __syncthreads();
    for (int e = tid; e < EPG; e += 1024)
        atomicAdd(&cnt[dst[ebase + e] & (NPG - 1)], 1);
    __syncthreads();
    int* a = cnt; int* b = tmp;
#pragma unroll
    for (int off = 1; off < 1024; off <<= 1) {
        int u = a[tid] + ((tid >= off) ? a[tid - off] : 0);
        __syncthreads();
        b[tid] = u;
        __syncthreads();
        int* t = a; a = b; b = t;
    }
    int excl = tid ? a[tid - 1] : 0;
    rowptr[g * NPG + tid] = ebase + excl;
    if (g == B_GRAPHS - 1 && tid == 0) rowptr[N_NODES] = E_TOTAL;
    b[tid] = excl;
    __syncthreads();
    for (int e = tid; e < EPG; e += 1024) {
        int d = dst[ebase + e] & (NPG - 1);
        int p = atomicAdd(&b[d], 1);
        scol[p] = src[ebase + e];
    }
    __syncthreads();
    int4* cg = (int4*)(col + ebase);
    const int4* cs = (const int4*)scol;
    for (int i = tid; i < EPG / 4; i += 1024) cg[i] = cs[i];
}

// ---------------- MFMA dual GEMM, f16 single, fragment-linear W ----------------
template <int K>
__global__ __launch_bounds__(512) void k_gemm_mfma(const float* __restrict__ X,
                                                   const __half* __restrict__ Wf,
                                                   const float* __restrict__ bs, const float* __restrict__ bd,
                                                   u16* __restrict__ fsd) {
    constexpr int NC = K / 32;
    constexpr int LDK = K + 8;
    __shared__ float xsbuf[4352];          // stage 32 x LDK f32 / epilogue 32 x 264 halfs
    float* xs = xsbuf;
    u16* eb = (u16*)xsbuf;
    int tid = threadIdx.x;
    int lane = tid & 63, wv = tid >> 6;
    int l15 = lane & 15, kg = lane >> 4;
    int ng = wv & 1, Tb = (wv >> 1) * 4;
    int nb = blockIdx.x * 32;

    if (K == 128) {
#pragma unroll
        for (int j = 0; j < 2; ++j) {
            int f = tid + j * 512;
            int r = f >> 5, c4 = f & 31;
            *(float4*)(xs + r * LDK + c4 * 4) = *(const float4*)(X + (size_t)(nb + r) * K + c4 * 4);
        }
    } else {
        if (tid < 256) {
            int r = tid >> 3, c4 = tid & 7;
            *(float4*)(xs + r * LDK + c4 * 4) = *(const float4*)(X + (size_t)(nb + r) * K + c4 * 4);
        }
    }
    __syncthreads();

    int ridx = ng * 16 + l15;
    FragH xf[NC];
#pragma unroll
    for (int c = 0; c < NC; ++c) {
        const float* xr = xs + ridx * LDK + c * 32 + kg * 8;
        float4 v0 = *(const float4*)xr;
        float4 v1 = *(const float4*)(xr + 4);
        xf[c].u[0] = f2h2(v0.x, v0.y);
        xf[c].u[1] = f2h2(v0.z, v0.w);
        xf[c].u[2] = f2h2(v1.x, v1.y);
        xf[c].u[3] = f2h2(v1.z, v1.w);
    }

    f32x4 acc[4];
#pragma unroll
    for (int i = 0; i < 4; ++i) acc[i] = (f32x4){0.f, 0.f, 0.f, 0.f};

#pragma unroll
    for (int i = 0; i < 4; ++i) {
        int T = Tb + i;
        const __half* wp = Wf + ((size_t)(T * NC) * 64 + lane) * 8;
#pragma unroll
        for (int c = 0; c < NC; ++c) {
            FragH wfr;
            wfr.i = *(const i32x4*)(wp + (size_t)c * 512);
            acc[i] = __builtin_amdgcn_mfma_f32_16x16x32_f16(wfr.h, xf[c].h, acc[i], 0, 0, 0);
        }
    }
    __syncthreads();

#pragma unroll
    for (int i = 0; i < 4; ++i) {
        int T = Tb + i;
        const float* bp = (T < 8) ? bs : bd;
        float4 bv = *(const float4*)(bp + (T & 7) * 16 + kg * 4);
        uint2 pk;
        pk.x = f2h2(acc[i][0] + bv.x, acc[i][1] + bv.y);
        pk.y = f2h2(acc[i][2] + bv.z, acc[i][3] + bv.w);
        int colh = (T & 7) * 16 + (T >> 3) * 128 + kg * 4;
        *(uint2*)(eb + (ng * 16 + l15) * 264 + colh) = pk;
    }
    __syncthreads();

#pragma unroll
    for (int j = 0; j < 2; ++j) {
        int f = tid + j * 512;
        int r = f >> 5, c = f & 31;
        i32x4 v = *(const i32x4*)(eb + r * 264 + c * 8);
        *(i32x4*)(fsd + (size_t)(nb + r) * 256 + c * 8) = v;
    }
}

// ---------------- GATv2 edge aggregation + head maxpool ----------------
// 4 nodes per wave (one per 16-lane quarter), 4 edge-chains per quarter,
// 2-LEVEL pipeline: col[k+2] loads || fv[k+1] gathers (from resident cols) || compute fv[k].
// s = lane&15 -> dims s*8..s*8+7; head = s>>2. Cross-lane via __shfl_xor only.
__global__ __launch_bounds__(256) void k_edge(const u16* __restrict__ fsd,
                                              const int* __restrict__ rowptr, const int* __restrict__ col,
                                              const float* __restrict__ attn, float* __restrict__ hout) {
    int w = threadIdx.x >> 6, lane = threadIdx.x & 63;
    int bid = blockIdx.x;
    int nb = (bid & 7) * 512 + (bid >> 3);   // XCD-aware swizzle (bijective: 4096 = 8*512)
    int q = lane >> 4, s = lane & 15;
    int n = nb * 16 + w * 4 + q;
    const char* fsdb = (const char*)fsd;

    // attn weights for this lane's 8 dims: head = s>>2, within-head off = (s&3)*8
    const float* ap = attn + (s >> 2) * 32 + (s & 3) * 8;
    float4 a0 = *(const float4*)ap;
    float4 a1 = *(const float4*)(ap + 4);
    const float L2E = 1.44269504089f;
    h2v av0, av1, av2, av3;
    { H2U t; t.u = f2h2(a0.x * L2E, a0.y * L2E); av0 = t.h;
      t.u = f2h2(a0.z * L2E, a0.w * L2E); av1 = t.h;
      t.u = f2h2(a1.x * L2E, a1.y * L2E); av2 = t.h;
      t.u = f2h2(a1.z * L2E, a1.w * L2E); av3 = t.h; }
    h2v neg2; neg2[0] = (_Float16)NEG; neg2[1] = (_Float16)NEG;

    // fd dims for this lane's node: row n, bytes 256 + s*16
    i32x4 fdq = *(const i32x4*)(fsdb + ((size_t)n << 9) + 256 + (s << 4));
    H2U fd0, fd1, fd2, fd3;
    fd0.u = (uint32)fdq[0]; fd1.u = (uint32)fdq[1]; fd2.u = (uint32)fdq[2]; fd3.u = (uint32)fdq[3];

    int start = rowptr[n];
    int end   = rowptr[n + 1];
    int deg = end - start;
    int m = deg;
    { int t16 = __shfl_xor(m, 16); m = (t16 > m) ? t16 : m;
      int t32 = __shfl_xor(m, 32); m = (t32 > m) ? t32 : m; }
    int niter = (__builtin_amdgcn_readfirstlane(m) + 3) >> 2;   // ceil(maxdeg/4)

    uint32 soff = (uint32)(s << 4);

    auto colat = [&](int e) -> uint32 {
        int idxc = (e < deg) ? (start + e) : 0;            // col[0] always in-bounds
        return (uint32)col[idxc];
    };
    auto gather = [&](uint32 cval) -> i32x4 {
        uint32 cc = cval & (N_NODES - 1);                  // clamp (safety)
        return *(const i32x4*)(fsdb + (((size_t)cc << 9) | soff));
    };

    float z = 0.f;
    float c0 = 0.f, c1 = 0.f, c2 = 0.f, c3 = 0.f, c4 = 0.f, c5 = 0.f, c6 = 0.f, c7 = 0.f;

    auto proc = [&](i32x4 f, int e) {
        uint32 w0 = (uint32)f[0], w1 = (uint32)f[1], w2 = (uint32)f[2], w3 = (uint32)f[3];
        float sp = dot_term(w0, fd0.h, neg2, av0, 0.f);
        sp = dot_term(w1, fd1.h, neg2, av1, sp);
        sp = dot_term(w2, fd2.h, neg2, av2, sp);
        sp = dot_term(w3, fd3.h, neg2, av3, sp);
        sp += __shfl_xor(sp, 1);     // head logit: quad reduce (bits 0-1)
        sp += __shfl_xor(sp, 2);
        float pe = fast_exp2(sp);
        pe = (e < deg) ? pe : 0.f;
        z += pe;
        fma_mix_lo(c0, pe, w0); fma_mix_hi(c1, pe, w0);
        fma_mix_lo(c2, pe, w1); fma_mix_hi(c3, pe, w1);
        fma_mix_lo(c4, pe, w2); fma_mix_hi(c5, pe, w2);
        fma_mix_lo(c6, pe, w3); fma_mix_hi(c7, pe, w3);
    };

    // pipeline prologue: cols for iter 0 and 1; gathers for iter 0
    uint32 cnxt0 = colat(4), cnxt1 = colat(5), cnxt2 = colat(6), cnxt3 = colat(7);
    i32x4 fv0 = gather(colat(0)), fv1 = gather(colat(1)), fv2 = gather(colat(2)), fv3 = gather(colat(3));

    for (int k = 0; k < niter; ++k) {
        int e = k * 4;
        i32x4 a = fv0, b = fv1, c = fv2, d = fv3;
        // issue iter-(k+1) gathers from RESIDENT cols (no col->fv serialization)
        fv0 = gather(cnxt0); fv1 = gather(cnxt1); fv2 = gather(cnxt2); fv3 = gather(cnxt3);
        // issue iter-(k+2) col loads (2 iterations of latency cover)
        cnxt0 = colat(e + 8); cnxt1 = colat(e + 9); cnxt2 = colat(e + 10); cnxt3 = colat(e + 11);
        proc(a, e + 0);
        proc(b, e + 1);
        proc(c, e + 2);
        proc(d, e + 3);
    }

    float r = (z > 0.f) ? 1.f / z : 0.f;   // deg==0 -> output 0
    c0 *= r; c1 *= r; c2 *= r; c3 *= r; c4 *= r; c5 *= r; c6 *= r; c7 *= r;

    // maxpool over heads: coset {s, s^4, s^8, s^12} within the quarter (bits 2-3)
    c0 = fmaxf(c0, __shfl_xor(c0, 4)); c0 = fmaxf(c0, __shfl_xor(c0, 8));
    c1 = fmaxf(c1, __shfl_xor(c1, 4)); c1 = fmaxf(c1, __shfl_xor(c1, 8));
    c2 = fmaxf(c2, __shfl_xor(c2, 4)); c2 = fmaxf(c2, __shfl_xor(c2, 8));
    c3 = fmaxf(c3, __shfl_xor(c3, 4)); c3 = fmaxf(c3, __shfl_xor(c3, 8));
    c4 = fmaxf(c4, __shfl_xor(c4, 4)); c4 = fmaxf(c4, __shfl_xor(c4, 8));
    c5 = fmaxf(c5, __shfl_xor(c5, 4)); c5 = fmaxf(c5, __shfl_xor(c5, 8));
    c6 = fmaxf(c6, __shfl_xor(c6, 4)); c6 = fmaxf(c6, __shfl_xor(c6, 8));
    c7 = fmaxf(c7, __shfl_xor(c7, 4)); c7 = fmaxf(c7, __shfl_xor(c7, 8));

    if (s < 4) {   // s = within-head block 0..3 -> dims s*8..s*8+7 (per quarter's node)
        float* op = hout + ((size_t)n << 5) + (s << 3);
        *(float4*)op = make_float4(c0, c1, c2, c3);
        *(float4*)(op + 4) = make_float4(c4, c5, c6, c7);
    }
}

// ---------------- global attention pooling ----------------
__global__ __launch_bounds__(256) void k_pool(const float* __restrict__ h2, const float* __restrict__ gW,
                                              const float* __restrict__ gb, float* __restrict__ out) {
    int b = blockIdx.x, tid = threadIdx.x;
    __shared__ float ga[NPG];
    __shared__ float red[256];
    __shared__ float gws[32];
    const float* hb = h2 + (size_t)b * NPG * 32;
    if (tid < 32) gws[tid] = gW[tid];
    __syncthreads();
    float gbv = gb[0];
    float lmax = -INFINITY;
    float gloc[4];
#pragma unroll
    for (int j = 0; j < 4; ++j) {
        int nl = tid + j * 256;
        const float* row = hb + nl * 32;
        float dot = 0.f;
#pragma unroll
        for (int c = 0; c < 32; c += 4) {
            float4 v = *(const float4*)(row + c);
            dot += v.x * gws[c] + v.y * gws[c + 1] + v.z * gws[c + 2] + v.w * gws[c + 3];
        }
        gloc[j] = dot + gbv;
        lmax = fmaxf(lmax, gloc[j]);
    }
    red[tid] = lmax; __syncthreads();
    for (int s2 = 128; s2 > 0; s2 >>= 1) { if (tid < s2) red[tid] = fmaxf(red[tid], red[tid + s2]); __syncthreads(); }
    float m = red[0];
    __syncthreads();
    float lsum = 0.f;
#pragma unroll
    for (int j = 0; j < 4; ++j) {
        int nl = tid + j * 256;
        float a = __expf(gloc[j] - m);
        ga[nl] = a;
        lsum += a;
    }
    red[tid] = lsum; __syncthreads();
    for (int s2 = 128; s2 > 0; s2 >>= 1) { if (tid < s2) red[tid] += red[tid + s2]; __syncthreads(); }
    float z = red[0];
    __syncthreads();
    int d = tid & 31, ng = tid >> 5;
    float acc = 0.f;
    for (int nl = ng; nl < NPG; nl += 8) acc += ga[nl] * hb[nl * 32 + d];
    red[tid] = acc; __syncthreads();
    if (tid < 32) {
        float s = red[tid];
#pragma unroll
        for (int g2 = 1; g2 < 8; ++g2) s += red[g2 * 32 + tid];
        out[b * 32 + tid] = s / z;
    }
}

extern "C" void kernel_launch(void* const* d_in, const int* in_sizes, int n_in,
                              void* d_out, int out_size, void* d_ws, size_t ws_size,
                              hipStream_t stream) {
    const float* x     = (const float*)d_in[0];
    const int*   src   = (const int*)d_in[1];
    const int*   dst   = (const int*)d_in[2];
    const float* Ws1   = (const float*)d_in[4];
    const float* bs1   = (const float*)d_in[5];
    const float* Wd1   = (const float*)d_in[6];
    const float* bd1   = (const float*)d_in[7];
    const float* attn1 = (const float*)d_in[8];
    const float* Ws2   = (const float*)d_in[9];
    const float* bs2   = (const float*)d_in[10];
    const float* Wd2   = (const float*)d_in[11];
    const float* bd2   = (const float*)d_in[12];
    const float* attn2 = (const float*)d_in[13];
    const float* gW    = (const float*)d_in[14];
    const float* gb    = (const float*)d_in[15];
    float* out = (float*)d_out;

    // workspace layout (~55 MB)
    u16* fsd   = (u16*)d_ws;                               // N*256 halfs (fs|fd interleaved)
    float* h1  = (float*)(fsd + (size_t)N_NODES * 256);    // N*32 f32
    float* h2  = h1 + (size_t)N_NODES * 32;                // N*32 f32
    int* rowptr = (int*)(h2 + (size_t)N_NODES * 32);       // N+1 (padded)
    int* col    = rowptr + (N_NODES + 4);                  // E
    __half* Wf1 = (__half*)(col + E_TOTAL);                // 32768 halfs
    __half* Wf2 = Wf1 + 32768;                             // 8192 halfs

    // CSR build (blocks 0..63) + W fragment conversion (blocks 64..103)
    k_prep<<<B_GRAPHS + 40, 1024, 0, stream>>>(src, dst, rowptr, col,
                                               Ws1, Wd1, Ws2, Wd2, Wf1, Wf2);

    // layer 1
    k_gemm_mfma<128><<<N_NODES / 32, 512, 0, stream>>>(x, Wf1, bs1, bd1, fsd);
    k_edge<<<N_NODES / 16, 256, 0, stream>>>(fsd, rowptr, col, attn1, h1);

    // layer 2 (overwrites fsd)
    k_gemm_mfma<32><<<N_NODES / 32, 512, 0, stream>>>(h1, Wf2, bs2, bd2, fsd);
    k_edge<<<N_NODES / 16, 256, 0, stream>>>(fsd, rowptr, col, attn2, h2);

    // global attention pooling
    k_pool<<<B_GRAPHS, 256, 0, stream>>>(h2, gW, gb, out);
}

// Round 17
// 139.778 us; speedup vs baseline: 1.7432x; 1.0263x over previous
//
#include <hip/hip_runtime.h>
#include <hip/hip_fp16.h>
#include <math.h>

#define N_NODES 65536
#define B_GRAPHS 64
#define NPG 1024
#define EPG 16384
#define E_TOTAL (B_GRAPHS * EPG)
#define NEG 0.2f

typedef float f32x4 __attribute__((ext_vector_type(4)));
typedef _Float16 f16x8 __attribute__((ext_vector_type(8)));
typedef _Float16 h2v __attribute__((ext_vector_type(2)));
typedef int i32x4 __attribute__((ext_vector_type(4)));
typedef unsigned int uint32;
typedef unsigned short u16;

union FragH { i32x4 i; f16x8 h; uint32 u[4]; };
union H2U { uint32 u; h2v h; };

// raw v_exp_f32 (2^x) — logits bounded by construction [validated R8+]
__device__ __forceinline__ float fast_exp2(float x) {
    float r;
    asm("v_exp_f32 %0, %1" : "=v"(r) : "v"(x));
    return r;
}

__device__ __forceinline__ uint32 f2h2(float a, float b) {
    __half2 h = __float22half2_rn(make_float2(a, b));
    return *(uint32*)&h;
}

// acc += p * f16(lo/hi of fv), f32 accumulate (v_fma_mix_f32) [validated R8+]
__device__ __forceinline__ void fma_mix_lo(float& acc, float p, uint32 fv) {
    asm("v_fma_mix_f32 %0, %1, %2, %0 op_sel_hi:[0,1,0]" : "+v"(acc) : "v"(p), "v"(fv));
}
__device__ __forceinline__ void fma_mix_hi(float& acc, float p, uint32 fv) {
    asm("v_fma_mix_f32 %0, %1, %2, %0 op_sel:[0,1,0] op_sel_hi:[0,1,0]" : "+v"(acc) : "v"(p), "v"(fv));
}

// e = fv + fd; e = max(e, NEG*e); sp += dot2(e, av)   (f32 accumulate) [validated R8+]
__device__ __forceinline__ float dot_term(uint32 fvu, h2v fdv, h2v neg2, h2v av, float accum) {
    H2U fv; fv.u = fvu;
    h2v e = fv.h + fdv;                  // v_pk_add_f16
    h2v en = e * neg2;                   // v_pk_mul_f16
    h2v em;
    asm("v_pk_max_f16 %0, %1, %2" : "=v"(em) : "v"(e), "v"(en));
    float sp;
    asm("v_dot2_f32_f16 %0, %1, %2, %3" : "=v"(sp) : "v"(em), "v"(av), "v"(accum));
    return sp;
}

// ---------------- prep: CSR count-sort + degree-sorted perm (blocks 0..63) + W frag conv ----------------
__global__ __launch_bounds__(1024) void k_prep(const int* __restrict__ src, const int* __restrict__ dst,
                                               int* __restrict__ rowptr, int* __restrict__ colb,
                                               int* __restrict__ perm,
                                               const float* __restrict__ Ws1, const float* __restrict__ Wd1,
                                               const float* __restrict__ Ws2, const float* __restrict__ Wd2,
                                               __half* __restrict__ Wf1, __half* __restrict__ Wf2) {
    __shared__ int cnt[NPG];
    __shared__ int tmp[NPG];
    __shared__ int degs[NPG];
    __shared__ int scol[EPG];   // 64KB
    __shared__ int hd[64];
    __shared__ int hcur[64];
    if (blockIdx.x >= B_GRAPHS) {
        // W -> fragment-linear f16 (40 blocks x 1024 threads = 40960 items)
        int id = (blockIdx.x - B_GRAPHS) * 1024 + threadIdx.x;
        if (id < 32768) {
            int j = id & 7, l = (id >> 3) & 63, c = (id >> 9) & 3, T = id >> 11;
            int k = c * 32 + (l >> 4) * 8 + j;
            int n = (T & 7) * 16 + (l & 15);
            const float* W = (T < 8) ? Ws1 : Wd1;
            Wf1[id] = __float2half_rn(W[k * 128 + n]);
        } else if (id < 40960) {
            int rem = id - 32768;
            int j = rem & 7, l = (rem >> 3) & 63, T = rem >> 9;
            int k = (l >> 4) * 8 + j;
            int n = (T & 7) * 16 + (l & 15);
            const float* W = (T < 8) ? Ws2 : Wd2;
            Wf2[rem] = __float2half_rn(W[k * 128 + n]);
        }
        return;
    }
    int g = blockIdx.x, tid = threadIdx.x;
    int ebase = g * EPG;
    cnt[tid] = 0;
    __syncthreads();
    for (int e = tid; e < EPG; e += 1024)
        atomicAdd(&cnt[dst[ebase + e] & (NPG - 1)], 1);
    __syncthreads();
    degs[tid] = cnt[tid];                 // save degrees for the sort
    int* a = cnt; int* b = tmp;
#pragma unroll
    for (int off = 1; off < 1024; off <<= 1) {
        int u = a[tid] + ((tid >= off) ? a[tid - off] : 0);
        __syncthreads();
        b[tid] = u;
        __syncthreads();
        int* t = a; a = b; b = t;
    }
    int excl = tid ? a[tid - 1] : 0;
    rowptr[g * NPG + tid] = ebase + excl;
    if (g == B_GRAPHS - 1 && tid == 0) rowptr[N_NODES] = E_TOTAL;
    b[tid] = excl;
    __syncthreads();
    for (int e = tid; e < EPG; e += 1024) {
        int d = dst[ebase + e] & (NPG - 1);
        int p = atomicAdd(&b[d], 1);
        scol[p] = src[ebase + e] << 9;    // pre-shifted byte offset (fsd row stride 512B)
    }
    // degree-sorted node permutation (64-bin count-sort)
    if (tid < 64) hd[tid] = 0;
    __syncthreads();
    int dc = degs[tid]; dc = (dc > 63) ? 63 : dc;
    atomicAdd(&hd[dc], 1);
    // coalesced writeback of sorted edges
    int4* cg = (int4*)(colb + ebase);
    const int4* cs = (const int4*)scol;
    for (int i = tid; i < EPG / 4; i += 1024) cg[i] = cs[i];
    __syncthreads();
    if (tid == 0) {
        int run = 0;
#pragma unroll 8
        for (int i = 0; i < 64; ++i) { hcur[i] = run; run += hd[i]; }
    }
    __syncthreads();
    int pos = atomicAdd(&hcur[dc], 1);
    perm[g * NPG + pos] = g * NPG + tid;
}

// ---------------- MFMA dual GEMM, f16 single, fragment-linear W ----------------
template <int K>
__global__ __launch_bounds__(512) void k_gemm_mfma(const float* __restrict__ X,
                                                   const __half* __restrict__ Wf,
                                                   const float* __restrict__ bs, const float* __restrict__ bd,
                                                   u16* __restrict__ fsd) {
    constexpr int NC = K / 32;
    constexpr int LDK = K + 8;
    __shared__ float xsbuf[4352];          // stage 32 x LDK f32 / epilogue 32 x 264 halfs
    float* xs = xsbuf;
    u16* eb = (u16*)xsbuf;
    int tid = threadIdx.x;
    int lane = tid & 63, wv = tid >> 6;
    int l15 = lane & 15, kg = lane >> 4;
    int ng = wv & 1, Tb = (wv >> 1) * 4;
    int nb = blockIdx.x * 32;

    if (K == 128) {
#pragma unroll
        for (int j = 0; j < 2; ++j) {
            int f = tid + j * 512;
            int r = f >> 5, c4 = f & 31;
            *(float4*)(xs + r * LDK + c4 * 4) = *(const float4*)(X + (size_t)(nb + r) * K + c4 * 4);
        }
    } else {
        if (tid < 256) {
            int r = tid >> 3, c4 = tid & 7;
            *(float4*)(xs + r * LDK + c4 * 4) = *(const float4*)(X + (size_t)(nb + r) * K + c4 * 4);
        }
    }
    __syncthreads();

    int ridx = ng * 16 + l15;
    FragH xf[NC];
#pragma unroll
    for (int c = 0; c < NC; ++c) {
        const float* xr = xs + ridx * LDK + c * 32 + kg * 8;
        float4 v0 = *(const float4*)xr;
        float4 v1 = *(const float4*)(xr + 4);
        xf[c].u[0] = f2h2(v0.x, v0.y);
        xf[c].u[1] = f2h2(v0.z, v0.w);
        xf[c].u[2] = f2h2(v1.x, v1.y);
        xf[c].u[3] = f2h2(v1.z, v1.w);
    }

    f32x4 acc[4];
#pragma unroll
    for (int i = 0; i < 4; ++i) acc[i] = (f32x4){0.f, 0.f, 0.f, 0.f};

#pragma unroll
    for (int i = 0; i < 4; ++i) {
        int T = Tb + i;
        const __half* wp = Wf + ((size_t)(T * NC) * 64 + lane) * 8;
#pragma unroll
        for (int c = 0; c < NC; ++c) {
            FragH wfr;
            wfr.i = *(const i32x4*)(wp + (size_t)c * 512);
            acc[i] = __builtin_amdgcn_mfma_f32_16x16x32_f16(wfr.h, xf[c].h, acc[i], 0, 0, 0);
        }
    }
    __syncthreads();

#pragma unroll
    for (int i = 0; i < 4; ++i) {
        int T = Tb + i;
        const float* bp = (T < 8) ? bs : bd;
        float4 bv = *(const float4*)(bp + (T & 7) * 16 + kg * 4);
        uint2 pk;
        pk.x = f2h2(acc[i][0] + bv.x, acc[i][1] + bv.y);
        pk.y = f2h2(acc[i][2] + bv.z, acc[i][3] + bv.w);
        int colh = (T & 7) * 16 + (T >> 3) * 128 + kg * 4;
        *(uint2*)(eb + (ng * 16 + l15) * 264 + colh) = pk;
    }
    __syncthreads();

#pragma unroll
    for (int j = 0; j < 2; ++j) {
        int f = tid + j * 512;
        int r = f >> 5, c = f & 31;
        i32x4 v = *(const i32x4*)(eb + r * 264 + c * 8);
        *(i32x4*)(fsd + (size_t)(nb + r) * 256 + c * 8) = v;
    }
}

// ---------------- GATv2 edge aggregation + head maxpool ----------------
// 4 nodes per wave via degree-sorted perm (the 4 nodes have near-equal degree ->
// minimal masking waste). 4 edge-chains/quarter, 2-level pipeline (cols k+2,
// gathers k+1, compute k). colb holds pre-shifted byte offsets (src<<9).
__global__ __launch_bounds__(256) void k_edge(const u16* __restrict__ fsd,
                                              const int* __restrict__ rowptr, const int* __restrict__ colb,
                                              const int* __restrict__ perm,
                                              const float* __restrict__ attn, float* __restrict__ hout) {
    int w = threadIdx.x >> 6, lane = threadIdx.x & 63;
    int bid = blockIdx.x;
    int nb = (bid & 7) * 512 + (bid >> 3);   // XCD-aware swizzle (bijective: 4096 = 8*512)
    int q = lane >> 4, s = lane & 15;
    int n = perm[nb * 16 + w * 4 + q];       // degree-sorted assignment
    const char* fsdb = (const char*)fsd;

    // attn weights for this lane's 8 dims: head = s>>2, within-head off = (s&3)*8
    const float* ap = attn + (s >> 2) * 32 + (s & 3) * 8;
    float4 a0 = *(const float4*)ap;
    float4 a1 = *(const float4*)(ap + 4);
    const float L2E = 1.44269504089f;
    h2v av0, av1, av2, av3;
    { H2U t; t.u = f2h2(a0.x * L2E, a0.y * L2E); av0 = t.h;
      t.u = f2h2(a0.z * L2E, a0.w * L2E); av1 = t.h;
      t.u = f2h2(a1.x * L2E, a1.y * L2E); av2 = t.h;
      t.u = f2h2(a1.z * L2E, a1.w * L2E); av3 = t.h; }
    h2v neg2; neg2[0] = (_Float16)NEG; neg2[1] = (_Float16)NEG;

    // fd dims for this lane's node: row n, bytes 256 + s*16
    i32x4 fdq = *(const i32x4*)(fsdb + ((size_t)n << 9) + 256 + (s << 4));
    H2U fd0, fd1, fd2, fd3;
    fd0.u = (uint32)fdq[0]; fd1.u = (uint32)fdq[1]; fd2.u = (uint32)fdq[2]; fd3.u = (uint32)fdq[3];

    int start = rowptr[n];
    int end   = rowptr[n + 1];
    int deg = end - start;
    int m = deg;
    { int t16 = __shfl_xor(m, 16); m = (t16 > m) ? t16 : m;
      int t32 = __shfl_xor(m, 32); m = (t32 > m) ? t32 : m; }
    int niter = (__builtin_amdgcn_readfirstlane(m) + 3) >> 2;   // ceil(maxdeg/4), ~ceil(deg/4) after sort

    uint32 soff = (uint32)(s << 4);

    auto colat = [&](int e) -> uint32 {
        int idxc = (e < deg) ? (start + e) : 0;            // colb[0] always in-bounds
        return (uint32)colb[idxc];                          // pre-shifted byte offset
    };
    auto gather = [&](uint32 cval) -> i32x4 {
        return *(const i32x4*)(fsdb + ((size_t)(cval | soff)));
    };

    float z = 0.f;
    float c0 = 0.f, c1 = 0.f, c2 = 0.f, c3 = 0.f, c4 = 0.f, c5 = 0.f, c6 = 0.f, c7 = 0.f;

    auto proc = [&](i32x4 f, int e) {
        uint32 w0 = (uint32)f[0], w1 = (uint32)f[1], w2 = (uint32)f[2], w3 = (uint32)f[3];
        float sp = dot_term(w0, fd0.h, neg2, av0, 0.f);
        sp = dot_term(w1, fd1.h, neg2, av1, sp);
        sp = dot_term(w2, fd2.h, neg2, av2, sp);
        sp = dot_term(w3, fd3.h, neg2, av3, sp);
        sp += __shfl_xor(sp, 1);     // head logit: quad reduce (bits 0-1)
        sp += __shfl_xor(sp, 2);
        float pe = fast_exp2(sp);
        pe = (e < deg) ? pe : 0.f;
        z += pe;
        fma_mix_lo(c0, pe, w0); fma_mix_hi(c1, pe, w0);
        fma_mix_lo(c2, pe, w1); fma_mix_hi(c3, pe, w1);
        fma_mix_lo(c4, pe, w2); fma_mix_hi(c5, pe, w2);
        fma_mix_lo(c6, pe, w3); fma_mix_hi(c7, pe, w3);
    };

    // pipeline prologue: cols for iter 0 and 1; gathers for iter 0
    uint32 cnxt0 = colat(4), cnxt1 = colat(5), cnxt2 = colat(6), cnxt3 = colat(7);
    i32x4 fv0 = gather(colat(0)), fv1 = gather(colat(1)), fv2 = gather(colat(2)), fv3 = gather(colat(3));

    for (int k = 0; k < niter; ++k) {
        int e = k * 4;
        i32x4 a = fv0, b = fv1, c = fv2, d = fv3;
        fv0 = gather(cnxt0); fv1 = gather(cnxt1); fv2 = gather(cnxt2); fv3 = gather(cnxt3);
        cnxt0 = colat(e + 8); cnxt1 = colat(e + 9); cnxt2 = colat(e + 10); cnxt3 = colat(e + 11);
        proc(a, e + 0);
        proc(b, e + 1);
        proc(c, e + 2);
        proc(d, e + 3);
    }

    float r = (z > 0.f) ? 1.f / z : 0.f;   // deg==0 -> output 0
    c0 *= r; c1 *= r; c2 *= r; c3 *= r; c4 *= r; c5 *= r; c6 *= r; c7 *= r;

    // maxpool over heads: coset {s, s^4, s^8, s^12} within the quarter (bits 2-3)
    c0 = fmaxf(c0, __shfl_xor(c0, 4)); c0 = fmaxf(c0, __shfl_xor(c0, 8));
    c1 = fmaxf(c1, __shfl_xor(c1, 4)); c1 = fmaxf(c1, __shfl_xor(c1, 8));
    c2 = fmaxf(c2, __shfl_xor(c2, 4)); c2 = fmaxf(c2, __shfl_xor(c2, 8));
    c3 = fmaxf(c3, __shfl_xor(c3, 4)); c3 = fmaxf(c3, __shfl_xor(c3, 8));
    c4 = fmaxf(c4, __shfl_xor(c4, 4)); c4 = fmaxf(c4, __shfl_xor(c4, 8));
    c5 = fmaxf(c5, __shfl_xor(c5, 4)); c5 = fmaxf(c5, __shfl_xor(c5, 8));
    c6 = fmaxf(c6, __shfl_xor(c6, 4)); c6 = fmaxf(c6, __shfl_xor(c6, 8));
    c7 = fmaxf(c7, __shfl_xor(c7, 4)); c7 = fmaxf(c7, __shfl_xor(c7, 8));

    if (s < 4) {   // s = within-head block 0..3 -> dims s*8..s*8+7 (per quarter's node)
        float* op = hout + ((size_t)n << 5) + (s << 3);
        *(float4*)op = make_float4(c0, c1, c2, c3);
        *(float4*)(op + 4) = make_float4(c4, c5, c6, c7);
    }
}

// ---------------- global attention pooling ----------------
__global__ __launch_bounds__(256) void k_pool(const float* __restrict__ h2, const float* __restrict__ gW,
                                              const float* __restrict__ gb, float* __restrict__ out) {
    int b = blockIdx.x, tid = threadIdx.x;
    __shared__ float ga[NPG];
    __shared__ float red[256];
    __shared__ float gws[32];
    const float* hb = h2 + (size_t)b * NPG * 32;
    if (tid < 32) gws[tid] = gW[tid];
    __syncthreads();
    float gbv = gb[0];
    float lmax = -INFINITY;
    float gloc[4];
#pragma unroll
    for (int j = 0; j < 4; ++j) {
        int nl = tid + j * 256;
        const float* row = hb + nl * 32;
        float dot = 0.f;
#pragma unroll
        for (int c = 0; c < 32; c += 4) {
            float4 v = *(const float4*)(row + c);
            dot += v.x * gws[c] + v.y * gws[c + 1] + v.z * gws[c + 2] + v.w * gws[c + 3];
        }
        gloc[j] = dot + gbv;
        lmax = fmaxf(lmax, gloc[j]);
    }
    red[tid] = lmax; __syncthreads();
    for (int s2 = 128; s2 > 0; s2 >>= 1) { if (tid < s2) red[tid] = fmaxf(red[tid], red[tid + s2]); __syncthreads(); }
    float m = red[0];
    __syncthreads();
    float lsum = 0.f;
#pragma unroll
    for (int j = 0; j < 4; ++j) {
        int nl = tid + j * 256;
        float a = __expf(gloc[j] - m);
        ga[nl] = a;
        lsum += a;
    }
    red[tid] = lsum; __syncthreads();
    for (int s2 = 128; s2 > 0; s2 >>= 1) { if (tid < s2) red[tid] += red[tid + s2]; __syncthreads(); }
    float z = red[0];
    __syncthreads();
    int d = tid & 31, ng = tid >> 5;
    float acc = 0.f;
    for (int nl = ng; nl < NPG; nl += 8) acc += ga[nl] * hb[nl * 32 + d];
    red[tid] = acc; __syncthreads();
    if (tid < 32) {
        float s = red[tid];
#pragma unroll
        for (int g2 = 1; g2 < 8; ++g2) s += red[g2 * 32 + tid];
        out[b * 32 + tid] = s / z;
    }
}

extern "C" void kernel_launch(void* const* d_in, const int* in_sizes, int n_in,
                              void* d_out, int out_size, void* d_ws, size_t ws_size,
                              hipStream_t stream) {
    const float* x     = (const float*)d_in[0];
    const int*   src   = (const int*)d_in[1];
    const int*   dst   = (const int*)d_in[2];
    const float* Ws1   = (const float*)d_in[4];
    const float* bs1   = (const float*)d_in[5];
    const float* Wd1   = (const float*)d_in[6];
    const float* bd1   = (const float*)d_in[7];
    const float* attn1 = (const float*)d_in[8];
    const float* Ws2   = (const float*)d_in[9];
    const float* bs2   = (const float*)d_in[10];
    const float* Wd2   = (const float*)d_in[11];
    const float* bd2   = (const float*)d_in[12];
    const float* attn2 = (const float*)d_in[13];
    const float* gW    = (const float*)d_in[14];
    const float* gb    = (const float*)d_in[15];
    float* out = (float*)d_out;

    // workspace layout (~55 MB)
    u16* fsd   = (u16*)d_ws;                               // N*256 halfs (fs|fd interleaved)
    float* h1  = (float*)(fsd + (size_t)N_NODES * 256);    // N*32 f32
    float* h2  = h1 + (size_t)N_NODES * 32;                // N*32 f32
    int* rowptr = (int*)(h2 + (size_t)N_NODES * 32);       // N+1 (padded)
    int* colb   = rowptr + (N_NODES + 4);                  // E (pre-shifted byte offsets)
    __half* Wf1 = (__half*)(colb + E_TOTAL);               // 32768 halfs
    __half* Wf2 = Wf1 + 32768;                             // 8192 halfs
    int* perm   = (int*)(Wf2 + 8192);                      // N ints (degree-sorted node ids)

    // CSR build + degree-sort (blocks 0..63) + W fragment conversion (blocks 64..103)
    k_prep<<<B_GRAPHS + 40, 1024, 0, stream>>>(src, dst, rowptr, colb, perm,
                                               Ws1, Wd1, Ws2, Wd2, Wf1, Wf2);

    // layer 1
    k_gemm_mfma<128><<<N_NODES / 32, 512, 0, stream>>>(x, Wf1, bs1, bd1, fsd);
    k_edge<<<N_NODES / 16, 256, 0, stream>>>(fsd, rowptr, colb, perm, attn1, h1);

    // layer 2 (overwrites fsd)
    k_gemm_mfma<32><<<N_NODES / 32, 512, 0, stream>>>(h1, Wf2, bs2, bd2, fsd);
    k_edge<<<N_NODES / 16, 256, 0, stream>>>(fsd, rowptr, colb, perm, attn2, h2);

    // global attention pooling
    k_pool<<<B_GRAPHS, 256, 0, stream>>>(h2, gW, gb, out);
}

// Round 18
// 136.566 us; speedup vs baseline: 1.7842x; 1.0235x over previous
//
#include <hip/hip_runtime.h>
#include <hip/hip_fp16.h>
#include <math.h>

#define N_NODES 65536
#define B_GRAPHS 64
#define NPG 1024
#define EPG 16384
#define E_TOTAL (B_GRAPHS * EPG)
#define NEG 0.2f

typedef float f32x4 __attribute__((ext_vector_type(4)));
typedef _Float16 f16x8 __attribute__((ext_vector_type(8)));
typedef _Float16 h2v __attribute__((ext_vector_type(2)));
typedef int i32x4 __attribute__((ext_vector_type(4)));
typedef unsigned int uint32;
typedef unsigned short u16;

union FragH { i32x4 i; f16x8 h; uint32 u[4]; };
union H2U { uint32 u; h2v h; };

// raw v_exp_f32 (2^x) — logits bounded by construction [validated R8+]
__device__ __forceinline__ float fast_exp2(float x) {
    float r;
    asm("v_exp_f32 %0, %1" : "=v"(r) : "v"(x));
    return r;
}

__device__ __forceinline__ uint32 f2h2(float a, float b) {
    __half2 h = __float22half2_rn(make_float2(a, b));
    return *(uint32*)&h;
}

// acc += p * f16(lo/hi of fv), f32 accumulate (v_fma_mix_f32) [validated R8+]
__device__ __forceinline__ void fma_mix_lo(float& acc, float p, uint32 fv) {
    asm("v_fma_mix_f32 %0, %1, %2, %0 op_sel_hi:[0,1,0]" : "+v"(acc) : "v"(p), "v"(fv));
}
__device__ __forceinline__ void fma_mix_hi(float& acc, float p, uint32 fv) {
    asm("v_fma_mix_f32 %0, %1, %2, %0 op_sel:[0,1,0] op_sel_hi:[0,1,0]" : "+v"(acc) : "v"(p), "v"(fv));
}

// e = fv + fd; e = max(e, NEG*e); sp += dot2(e, av)   (f32 accumulate) [validated R8+]
__device__ __forceinline__ float dot_term(uint32 fvu, h2v fdv, h2v neg2, h2v av, float accum) {
    H2U fv; fv.u = fvu;
    h2v e = fv.h + fdv;                  // v_pk_add_f16
    h2v en = e * neg2;                   // v_pk_mul_f16
    h2v em;
    asm("v_pk_max_f16 %0, %1, %2" : "=v"(em) : "v"(e), "v"(en));
    float sp;
    asm("v_dot2_f32_f16 %0, %1, %2, %3" : "=v"(sp) : "v"(em), "v"(av), "v"(accum));
    return sp;
}

// ---------------- prep: CSR count-sort + degree-sorted perm (blocks 0..63) + W frag conv ----------------
__global__ __launch_bounds__(1024) void k_prep(const int* __restrict__ src, const int* __restrict__ dst,
                                               int* __restrict__ rowptr, int* __restrict__ colb,
                                               int* __restrict__ perm,
                                               const float* __restrict__ Ws1, const float* __restrict__ Wd1,
                                               const float* __restrict__ Ws2, const float* __restrict__ Wd2,
                                               __half* __restrict__ Wf1, __half* __restrict__ Wf2) {
    __shared__ int cnt[NPG];
    __shared__ int cur[NPG];
    __shared__ int scol[EPG];   // 64KB
    __shared__ int wsum[16];
    __shared__ int hd[64];
    __shared__ int hcur[64];
    if (blockIdx.x >= B_GRAPHS) {
        // W -> fragment-linear f16 (40 blocks x 1024 threads = 40960 items)
        int id = (blockIdx.x - B_GRAPHS) * 1024 + threadIdx.x;
        if (id < 32768) {
            int j = id & 7, l = (id >> 3) & 63, c = (id >> 9) & 3, T = id >> 11;
            int k = c * 32 + (l >> 4) * 8 + j;
            int n = (T & 7) * 16 + (l & 15);
            const float* W = (T < 8) ? Ws1 : Wd1;
            Wf1[id] = __float2half_rn(W[k * 128 + n]);
        } else if (id < 40960) {
            int rem = id - 32768;
            int j = rem & 7, l = (rem >> 3) & 63, T = rem >> 9;
            int k = (l >> 4) * 8 + j;
            int n = (T & 7) * 16 + (l & 15);
            const float* W = (T < 8) ? Ws2 : Wd2;
            Wf2[rem] = __float2half_rn(W[k * 128 + n]);
        }
        return;
    }
    int g = blockIdx.x, tid = threadIdx.x;
    int lane = tid & 63, wid = tid >> 6;
    int ebase = g * EPG;
    cnt[tid] = 0;
    __syncthreads();
    for (int e = tid; e < EPG; e += 1024)
        atomicAdd(&cnt[dst[ebase + e] & (NPG - 1)], 1);
    __syncthreads();
    int deg0 = cnt[tid];
    // wave-shuffle inclusive scan (no barriers within wave)
    int v = deg0;
#pragma unroll
    for (int off = 1; off < 64; off <<= 1) {
        int t = __shfl_up(v, off);
        if (lane >= off) v += t;
    }
    if (lane == 63) wsum[wid] = v;
    __syncthreads();
    if (tid < 16) {
        int sv = wsum[tid];
#pragma unroll
        for (int off = 1; off < 16; off <<= 1) {
            int t = __shfl_up(sv, off);
            if (tid >= off) sv += t;
        }
        wsum[tid] = sv;
    }
    __syncthreads();
    int excl = v + (wid ? wsum[wid - 1] : 0) - deg0;
    rowptr[g * NPG + tid] = ebase + excl;
    if (g == B_GRAPHS - 1 && tid == 0) rowptr[N_NODES] = E_TOTAL;
    cur[tid] = excl;
    __syncthreads();
    for (int e = tid; e < EPG; e += 1024) {
        int d = dst[ebase + e] & (NPG - 1);
        int p = atomicAdd(&cur[d], 1);
        scol[p] = src[ebase + e] << 9;    // pre-shifted byte offset (fsd row stride 512B)
    }
    // degree-sorted node permutation (64-bin count-sort)
    if (tid < 64) hd[tid] = 0;
    __syncthreads();
    int dc = deg0; dc = (dc > 63) ? 63 : dc;
    atomicAdd(&hd[dc], 1);
    // coalesced writeback of sorted edges
    int4* cg = (int4*)(colb + ebase);
    const int4* cs = (const int4*)scol;
    for (int i = tid; i < EPG / 4; i += 1024) cg[i] = cs[i];
    __syncthreads();
    if (tid == 0) {
        int run = 0;
#pragma unroll 8
        for (int i = 0; i < 64; ++i) { hcur[i] = run; run += hd[i]; }
    }
    __syncthreads();
    int pos = atomicAdd(&hcur[dc], 1);
    perm[g * NPG + pos] = g * NPG + tid;
}

// ---------------- MFMA dual GEMM, f16 single, fragment-linear W ----------------
template <int K>
__global__ __launch_bounds__(512) void k_gemm_mfma(const float* __restrict__ X,
                                                   const __half* __restrict__ Wf,
                                                   const float* __restrict__ bs, const float* __restrict__ bd,
                                                   u16* __restrict__ fsd) {
    constexpr int NC = K / 32;
    constexpr int LDK = K + 8;
    __shared__ float xsbuf[4352];          // stage 32 x LDK f32 / epilogue 32 x 264 halfs
    float* xs = xsbuf;
    u16* eb = (u16*)xsbuf;
    int tid = threadIdx.x;
    int lane = tid & 63, wv = tid >> 6;
    int l15 = lane & 15, kg = lane >> 4;
    int ng = wv & 1, Tb = (wv >> 1) * 4;
    int nb = blockIdx.x * 32;

    if (K == 128) {
#pragma unroll
        for (int j = 0; j < 2; ++j) {
            int f = tid + j * 512;
            int r = f >> 5, c4 = f & 31;
            *(float4*)(xs + r * LDK + c4 * 4) = *(const float4*)(X + (size_t)(nb + r) * K + c4 * 4);
        }
    } else {
        if (tid < 256) {
            int r = tid >> 3, c4 = tid & 7;
            *(float4*)(xs + r * LDK + c4 * 4) = *(const float4*)(X + (size_t)(nb + r) * K + c4 * 4);
        }
    }
    __syncthreads();

    int ridx = ng * 16 + l15;
    FragH xf[NC];
#pragma unroll
    for (int c = 0; c < NC; ++c) {
        const float* xr = xs + ridx * LDK + c * 32 + kg * 8;
        float4 v0 = *(const float4*)xr;
        float4 v1 = *(const float4*)(xr + 4);
        xf[c].u[0] = f2h2(v0.x, v0.y);
        xf[c].u[1] = f2h2(v0.z, v0.w);
        xf[c].u[2] = f2h2(v1.x, v1.y);
        xf[c].u[3] = f2h2(v1.z, v1.w);
    }

    f32x4 acc[4];
#pragma unroll
    for (int i = 0; i < 4; ++i) acc[i] = (f32x4){0.f, 0.f, 0.f, 0.f};

#pragma unroll
    for (int i = 0; i < 4; ++i) {
        int T = Tb + i;
        const __half* wp = Wf + ((size_t)(T * NC) * 64 + lane) * 8;
#pragma unroll
        for (int c = 0; c < NC; ++c) {
            FragH wfr;
            wfr.i = *(const i32x4*)(wp + (size_t)c * 512);
            acc[i] = __builtin_amdgcn_mfma_f32_16x16x32_f16(wfr.h, xf[c].h, acc[i], 0, 0, 0);
        }
    }
    __syncthreads();

#pragma unroll
    for (int i = 0; i < 4; ++i) {
        int T = Tb + i;
        const float* bp = (T < 8) ? bs : bd;
        float4 bv = *(const float4*)(bp + (T & 7) * 16 + kg * 4);
        uint2 pk;
        pk.x = f2h2(acc[i][0] + bv.x, acc[i][1] + bv.y);
        pk.y = f2h2(acc[i][2] + bv.z, acc[i][3] + bv.w);
        int colh = (T & 7) * 16 + (T >> 3) * 128 + kg * 4;
        *(uint2*)(eb + (ng * 16 + l15) * 264 + colh) = pk;
    }
    __syncthreads();

#pragma unroll
    for (int j = 0; j < 2; ++j) {
        int f = tid + j * 512;
        int r = f >> 5, c = f & 31;
        i32x4 v = *(const i32x4*)(eb + r * 264 + c * 8);
        *(i32x4*)(fsd + (size_t)(nb + r) * 256 + c * 8) = v;
    }
}

// ---------------- GATv2 edge aggregation + head maxpool ----------------
// 4 nodes per wave via degree-sorted perm, 4 edge-chains/quarter, 2-level pipeline.
// Addressing diet: unconditional col loads (base+imm offsets; <=256B overrun stays
// inside colb+Wf pad), gather address masked into the 32MB fsd region; invalid
// edges zeroed via the e<deg pe-mask.
__global__ __launch_bounds__(256) void k_edge(const u16* __restrict__ fsd,
                                              const int* __restrict__ rowptr, const int* __restrict__ colb,
                                              const int* __restrict__ perm,
                                              const float* __restrict__ attn, float* __restrict__ hout) {
    int w = threadIdx.x >> 6, lane = threadIdx.x & 63;
    int bid = blockIdx.x;
    int nb = (bid & 7) * 512 + (bid >> 3);   // XCD-aware swizzle (bijective: 4096 = 8*512)
    int q = lane >> 4, s = lane & 15;
    int n = perm[nb * 16 + w * 4 + q];       // degree-sorted assignment
    const char* fsdb = (const char*)fsd;

    // attn weights for this lane's 8 dims: head = s>>2, within-head off = (s&3)*8
    const float* ap = attn + (s >> 2) * 32 + (s & 3) * 8;
    float4 a0 = *(const float4*)ap;
    float4 a1 = *(const float4*)(ap + 4);
    const float L2E = 1.44269504089f;
    h2v av0, av1, av2, av3;
    { H2U t; t.u = f2h2(a0.x * L2E, a0.y * L2E); av0 = t.h;
      t.u = f2h2(a0.z * L2E, a0.w * L2E); av1 = t.h;
      t.u = f2h2(a1.x * L2E, a1.y * L2E); av2 = t.h;
      t.u = f2h2(a1.z * L2E, a1.w * L2E); av3 = t.h; }
    h2v neg2; neg2[0] = (_Float16)NEG; neg2[1] = (_Float16)NEG;

    // fd dims for this lane's node: row n, bytes 256 + s*16
    i32x4 fdq = *(const i32x4*)(fsdb + ((size_t)n << 9) + 256 + (s << 4));
    H2U fd0, fd1, fd2, fd3;
    fd0.u = (uint32)fdq[0]; fd1.u = (uint32)fdq[1]; fd2.u = (uint32)fdq[2]; fd3.u = (uint32)fdq[3];

    int start = rowptr[n];
    int end   = rowptr[n + 1];
    int deg = end - start;
    int m = deg;
    { int t16 = __shfl_xor(m, 16); m = (t16 > m) ? t16 : m;
      int t32 = __shfl_xor(m, 32); m = (t32 > m) ? t32 : m; }
    int niter = (__builtin_amdgcn_readfirstlane(m) + 3) >> 2;   // ~ceil(deg/4) after sort

    const char* fb = fsdb + (s << 4);        // per-lane gather base (soff folded in)
    const int* cb = colb + start;            // per-quarter col base (unconditional loads)

    float z = 0.f;
    float c0 = 0.f, c1 = 0.f, c2 = 0.f, c3 = 0.f, c4 = 0.f, c5 = 0.f, c6 = 0.f, c7 = 0.f;

    auto gather = [&](uint32 cval) -> i32x4 {
        return *(const i32x4*)(fb + (cval & 0x01FFFE00u));   // mask keeps addr inside fsd
    };

    auto proc = [&](i32x4 f, int e) {
        uint32 w0 = (uint32)f[0], w1 = (uint32)f[1], w2 = (uint32)f[2], w3 = (uint32)f[3];
        float sp = dot_term(w0, fd0.h, neg2, av0, 0.f);
        sp = dot_term(w1, fd1.h, neg2, av1, sp);
        sp = dot_term(w2, fd2.h, neg2, av2, sp);
        sp = dot_term(w3, fd3.h, neg2, av3, sp);
        sp += __shfl_xor(sp, 1);     // head logit: quad reduce (bits 0-1)
        sp += __shfl_xor(sp, 2);
        float pe = fast_exp2(sp);
        pe = (e < deg) ? pe : 0.f;
        z += pe;
        fma_mix_lo(c0, pe, w0); fma_mix_hi(c1, pe, w0);
        fma_mix_lo(c2, pe, w1); fma_mix_hi(c3, pe, w1);
        fma_mix_lo(c4, pe, w2); fma_mix_hi(c5, pe, w2);
        fma_mix_lo(c6, pe, w3); fma_mix_hi(c7, pe, w3);
    };

    // pipeline prologue: cols for iter 0 and 1; gathers for iter 0
    uint32 cnxt0 = (uint32)cb[4], cnxt1 = (uint32)cb[5], cnxt2 = (uint32)cb[6], cnxt3 = (uint32)cb[7];
    i32x4 fv0 = gather((uint32)cb[0]), fv1 = gather((uint32)cb[1]),
          fv2 = gather((uint32)cb[2]), fv3 = gather((uint32)cb[3]);

    for (int k = 0; k < niter; ++k) {
        int e = k * 4;
        i32x4 a = fv0, b = fv1, c = fv2, d = fv3;
        // issue iter-(k+1) gathers from RESIDENT cols
        fv0 = gather(cnxt0); fv1 = gather(cnxt1); fv2 = gather(cnxt2); fv3 = gather(cnxt3);
        // issue iter-(k+2) col loads (base + immediate offsets)
        cnxt0 = (uint32)cb[e + 8]; cnxt1 = (uint32)cb[e + 9];
        cnxt2 = (uint32)cb[e + 10]; cnxt3 = (uint32)cb[e + 11];
        proc(a, e + 0);
        proc(b, e + 1);
        proc(c, e + 2);
        proc(d, e + 3);
    }

    float r = (z > 0.f) ? 1.f / z : 0.f;   // deg==0 -> output 0
    c0 *= r; c1 *= r; c2 *= r; c3 *= r; c4 *= r; c5 *= r; c6 *= r; c7 *= r;

    // maxpool over heads: coset {s, s^4, s^8, s^12} within the quarter (bits 2-3)
    c0 = fmaxf(c0, __shfl_xor(c0, 4)); c0 = fmaxf(c0, __shfl_xor(c0, 8));
    c1 = fmaxf(c1, __shfl_xor(c1, 4)); c1 = fmaxf(c1, __shfl_xor(c1, 8));
    c2 = fmaxf(c2, __shfl_xor(c2, 4)); c2 = fmaxf(c2, __shfl_xor(c2, 8));
    c3 = fmaxf(c3, __shfl_xor(c3, 4)); c3 = fmaxf(c3, __shfl_xor(c3, 8));
    c4 = fmaxf(c4, __shfl_xor(c4, 4)); c4 = fmaxf(c4, __shfl_xor(c4, 8));
    c5 = fmaxf(c5, __shfl_xor(c5, 4)); c5 = fmaxf(c5, __shfl_xor(c5, 8));
    c6 = fmaxf(c6, __shfl_xor(c6, 4)); c6 = fmaxf(c6, __shfl_xor(c6, 8));
    c7 = fmaxf(c7, __shfl_xor(c7, 4)); c7 = fmaxf(c7, __shfl_xor(c7, 8));

    if (s < 4) {   // s = within-head block 0..3 -> dims s*8..s*8+7 (per quarter's node)
        float* op = hout + ((size_t)n << 5) + (s << 3);
        *(float4*)op = make_float4(c0, c1, c2, c3);
        *(float4*)(op + 4) = make_float4(c4, c5, c6, c7);
    }
}

// ---------------- global attention pooling ----------------
__global__ __launch_bounds__(256) void k_pool(const float* __restrict__ h2, const float* __restrict__ gW,
                                              const float* __restrict__ gb, float* __restrict__ out) {
    int b = blockIdx.x, tid = threadIdx.x;
    __shared__ float ga[NPG];
    __shared__ float red[256];
    __shared__ float gws[32];
    const float* hb = h2 + (size_t)b * NPG * 32;
    if (tid < 32) gws[tid] = gW[tid];
    __syncthreads();
    float gbv = gb[0];
    float lmax = -INFINITY;
    float gloc[4];
#pragma unroll
    for (int j = 0; j < 4; ++j) {
        int nl = tid + j * 256;
        const float* row = hb + nl * 32;
        float dot = 0.f;
#pragma unroll
        for (int c = 0; c < 32; c += 4) {
            float4 v = *(const float4*)(row + c);
            dot += v.x * gws[c] + v.y * gws[c + 1] + v.z * gws[c + 2] + v.w * gws[c + 3];
        }
        gloc[j] = dot + gbv;
        lmax = fmaxf(lmax, gloc[j]);
    }
    red[tid] = lmax; __syncthreads();
    for (int s2 = 128; s2 > 0; s2 >>= 1) { if (tid < s2) red[tid] = fmaxf(red[tid], red[tid + s2]); __syncthreads(); }
    float m = red[0];
    __syncthreads();
    float lsum = 0.f;
#pragma unroll
    for (int j = 0; j < 4; ++j) {
        int nl = tid + j * 256;
        float a = __expf(gloc[j] - m);
        ga[nl] = a;
        lsum += a;
    }
    red[tid] = lsum; __syncthreads();
    for (int s2 = 128; s2 > 0; s2 >>= 1) { if (tid < s2) red[tid] += red[tid + s2]; __syncthreads(); }
    float z = red[0];
    __syncthreads();
    int d = tid & 31, ng = tid >> 5;
    float acc = 0.f;
    for (int nl = ng; nl < NPG; nl += 8) acc += ga[nl] * hb[nl * 32 + d];
    red[tid] = acc; __syncthreads();
    if (tid < 32) {
        float s = red[tid];
#pragma unroll
        for (int g2 = 1; g2 < 8; ++g2) s += red[g2 * 32 + tid];
        out[b * 32 + tid] = s / z;
    }
}

extern "C" void kernel_launch(void* const* d_in, const int* in_sizes, int n_in,
                              void* d_out, int out_size, void* d_ws, size_t ws_size,
                              hipStream_t stream) {
    const float* x     = (const float*)d_in[0];
    const int*   src   = (const int*)d_in[1];
    const int*   dst   = (const int*)d_in[2];
    const float* Ws1   = (const float*)d_in[4];
    const float* bs1   = (const float*)d_in[5];
    const float* Wd1   = (const float*)d_in[6];
    const float* bd1   = (const float*)d_in[7];
    const float* attn1 = (const float*)d_in[8];
    const float* Ws2   = (const float*)d_in[9];
    const float* bs2   = (const float*)d_in[10];
    const float* Wd2   = (const float*)d_in[11];
    const float* bd2   = (const float*)d_in[12];
    const float* attn2 = (const float*)d_in[13];
    const float* gW    = (const float*)d_in[14];
    const float* gb    = (const float*)d_in[15];
    float* out = (float*)d_out;

    // workspace layout (~55 MB)
    u16* fsd   = (u16*)d_ws;                               // N*256 halfs (fs|fd interleaved)
    float* h1  = (float*)(fsd + (size_t)N_NODES * 256);    // N*32 f32
    float* h2  = h1 + (size_t)N_NODES * 32;                // N*32 f32
    int* rowptr = (int*)(h2 + (size_t)N_NODES * 32);       // N+1 (padded)
    int* colb   = rowptr + (N_NODES + 4);                  // E (pre-shifted byte offsets)
    __half* Wf1 = (__half*)(colb + E_TOTAL);               // 32768 halfs
    __half* Wf2 = Wf1 + 32768;                             // 8192 halfs
    int* perm   = (int*)(Wf2 + 8192);                      // N ints (degree-sorted node ids)

    // CSR build + degree-sort (blocks 0..63) + W fragment conversion (blocks 64..103)
    k_prep<<<B_GRAPHS + 40, 1024, 0, stream>>>(src, dst, rowptr, colb, perm,
                                               Ws1, Wd1, Ws2, Wd2, Wf1, Wf2);

    // layer 1
    k_gemm_mfma<128><<<N_NODES / 32, 512, 0, stream>>>(x, Wf1, bs1, bd1, fsd);
    k_edge<<<N_NODES / 16, 256, 0, stream>>>(fsd, rowptr, colb, perm, attn1, h1);

    // layer 2 (overwrites fsd)
    k_gemm_mfma<32><<<N_NODES / 32, 512, 0, stream>>>(h1, Wf2, bs2, bd2, fsd);
    k_edge<<<N_NODES / 16, 256, 0, stream>>>(fsd, rowptr, colb, perm, attn2, h2);

    // global attention pooling
    k_pool<<<B_GRAPHS, 256, 0, stream>>>(h2, gW, gb, out);
}

// Round 19
// 132.517 us; speedup vs baseline: 1.8387x; 1.0306x over previous
//
#include <hip/hip_runtime.h>
#include <hip/hip_fp16.h>
#include <math.h>

#define N_NODES 65536
#define B_GRAPHS 64
#define NPG 1024
#define EPG 16384
#define E_TOTAL (B_GRAPHS * EPG)
#define NEG 0.2f

typedef float f32x4 __attribute__((ext_vector_type(4)));
typedef _Float16 f16x8 __attribute__((ext_vector_type(8)));
typedef _Float16 h2v __attribute__((ext_vector_type(2)));
typedef int i32x4 __attribute__((ext_vector_type(4)));
typedef unsigned int uint32;
typedef unsigned short u16;

union FragH { i32x4 i; f16x8 h; uint32 u[4]; };
union H2U { uint32 u; h2v h; };

// raw v_exp_f32 (2^x) — logits bounded by construction [validated R8+]
__device__ __forceinline__ float fast_exp2(float x) {
    float r;
    asm("v_exp_f32 %0, %1" : "=v"(r) : "v"(x));
    return r;
}

__device__ __forceinline__ uint32 f2h2(float a, float b) {
    __half2 h = __float22half2_rn(make_float2(a, b));
    return *(uint32*)&h;
}

// acc += p * f16(lo/hi of fv), f32 accumulate (v_fma_mix_f32) [validated R8+]
__device__ __forceinline__ void fma_mix_lo(float& acc, float p, uint32 fv) {
    asm("v_fma_mix_f32 %0, %1, %2, %0 op_sel_hi:[0,1,0]" : "+v"(acc) : "v"(p), "v"(fv));
}
__device__ __forceinline__ void fma_mix_hi(float& acc, float p, uint32 fv) {
    asm("v_fma_mix_f32 %0, %1, %2, %0 op_sel:[0,1,0] op_sel_hi:[0,1,0]" : "+v"(acc) : "v"(p), "v"(fv));
}

// e = fv + fd; e = max(e, NEG*e); sp += dot2(e, av)   (f32 accumulate) [validated R8+]
__device__ __forceinline__ float dot_term(uint32 fvu, h2v fdv, h2v neg2, h2v av, float accum) {
    H2U fv; fv.u = fvu;
    h2v e = fv.h + fdv;                  // v_pk_add_f16
    h2v en = e * neg2;                   // v_pk_mul_f16
    h2v em;
    asm("v_pk_max_f16 %0, %1, %2" : "=v"(em) : "v"(e), "v"(en));
    float sp;
    asm("v_dot2_f32_f16 %0, %1, %2, %3" : "=v"(sp) : "v"(em), "v"(av), "v"(accum));
    return sp;
}

// ---------------- prep: CSR count-sort + degree-sorted descriptors + W frag conv ----------------
__global__ __launch_bounds__(1024) void k_prep(const int* __restrict__ src, const int* __restrict__ dst,
                                               int* __restrict__ rowptr, int* __restrict__ colb,
                                               int2* __restrict__ ndpack,
                                               const float* __restrict__ Ws1, const float* __restrict__ Wd1,
                                               const float* __restrict__ Ws2, const float* __restrict__ Wd2,
                                               __half* __restrict__ Wf1, __half* __restrict__ Wf2) {
    __shared__ int cnt[NPG];
    __shared__ int cur[NPG];
    __shared__ int scol[EPG];   // 64KB
    __shared__ int wsum[16];
    __shared__ int hd[64];
    __shared__ int hcur[64];
    if (blockIdx.x >= B_GRAPHS) {
        // W -> fragment-linear f16 (40 blocks x 1024 threads = 40960 items)
        int id = (blockIdx.x - B_GRAPHS) * 1024 + threadIdx.x;
        if (id < 32768) {
            int j = id & 7, l = (id >> 3) & 63, c = (id >> 9) & 3, T = id >> 11;
            int k = c * 32 + (l >> 4) * 8 + j;
            int n = (T & 7) * 16 + (l & 15);
            const float* W = (T < 8) ? Ws1 : Wd1;
            Wf1[id] = __float2half_rn(W[k * 128 + n]);
        } else if (id < 40960) {
            int rem = id - 32768;
            int j = rem & 7, l = (rem >> 3) & 63, T = rem >> 9;
            int k = (l >> 4) * 8 + j;
            int n = (T & 7) * 16 + (l & 15);
            const float* W = (T < 8) ? Ws2 : Wd2;
            Wf2[rem] = __float2half_rn(W[k * 128 + n]);
        }
        return;
    }
    int g = blockIdx.x, tid = threadIdx.x;
    int lane = tid & 63, wid = tid >> 6;
    int ebase = g * EPG;
    cnt[tid] = 0;
    __syncthreads();
    for (int e = tid; e < EPG; e += 1024)
        atomicAdd(&cnt[dst[ebase + e] & (NPG - 1)], 1);
    __syncthreads();
    int deg0 = cnt[tid];
    // wave-shuffle inclusive scan (no barriers within wave)
    int v = deg0;
#pragma unroll
    for (int off = 1; off < 64; off <<= 1) {
        int t = __shfl_up(v, off);
        if (lane >= off) v += t;
    }
    if (lane == 63) wsum[wid] = v;
    __syncthreads();
    if (tid < 16) {
        int sv = wsum[tid];
#pragma unroll
        for (int off = 1; off < 16; off <<= 1) {
            int t = __shfl_up(sv, off);
            if (tid >= off) sv += t;
        }
        wsum[tid] = sv;
    }
    __syncthreads();
    int excl = v + (wid ? wsum[wid - 1] : 0) - deg0;
    rowptr[g * NPG + tid] = ebase + excl;
    if (g == B_GRAPHS - 1 && tid == 0) rowptr[N_NODES] = E_TOTAL;
    cur[tid] = excl;
    __syncthreads();
    for (int e = tid; e < EPG; e += 1024) {
        int d = dst[ebase + e] & (NPG - 1);
        int p = atomicAdd(&cur[d], 1);
        scol[p] = src[ebase + e] << 9;    // pre-shifted byte offset (fsd row stride 512B)
    }
    // degree-sorted node descriptors (64-bin count-sort)
    if (tid < 64) hd[tid] = 0;
    __syncthreads();
    int dc = deg0; dc = (dc > 63) ? 63 : dc;
    atomicAdd(&hd[dc], 1);
    // coalesced writeback of sorted edges
    int4* cg = (int4*)(colb + ebase);
    const int4* cs = (const int4*)scol;
    for (int i = tid; i < EPG / 4; i += 1024) cg[i] = cs[i];
    __syncthreads();
    if (tid == 0) {
        int run = 0;
#pragma unroll 8
        for (int i = 0; i < 64; ++i) { hcur[i] = run; run += hd[i]; }
    }
    __syncthreads();
    int pos = atomicAdd(&hcur[dc], 1);
    // packed descriptor: x = global edge start, y = node | (deg<<16)
    ndpack[g * NPG + pos] = make_int2(ebase + excl, (g * NPG + tid) | (deg0 << 16));
}

// ---------------- MFMA dual GEMM, f16 single, fragment-linear W ----------------
template <int K>
__global__ __launch_bounds__(512) void k_gemm_mfma(const float* __restrict__ X,
                                                   const __half* __restrict__ Wf,
                                                   const float* __restrict__ bs, const float* __restrict__ bd,
                                                   u16* __restrict__ fsd) {
    constexpr int NC = K / 32;
    constexpr int LDK = K + 8;
    __shared__ float xsbuf[4352];          // stage 32 x LDK f32 / epilogue 32 x 264 halfs
    float* xs = xsbuf;
    u16* eb = (u16*)xsbuf;
    int tid = threadIdx.x;
    int lane = tid & 63, wv = tid >> 6;
    int l15 = lane & 15, kg = lane >> 4;
    int ng = wv & 1, Tb = (wv >> 1) * 4;
    int nb = blockIdx.x * 32;

    if (K == 128) {
#pragma unroll
        for (int j = 0; j < 2; ++j) {
            int f = tid + j * 512;
            int r = f >> 5, c4 = f & 31;
            *(float4*)(xs + r * LDK + c4 * 4) = *(const float4*)(X + (size_t)(nb + r) * K + c4 * 4);
        }
    } else {
        if (tid < 256) {
            int r = tid >> 3, c4 = tid & 7;
            *(float4*)(xs + r * LDK + c4 * 4) = *(const float4*)(X + (size_t)(nb + r) * K + c4 * 4);
        }
    }
    __syncthreads();

    int ridx = ng * 16 + l15;
    FragH xf[NC];
#pragma unroll
    for (int c = 0; c < NC; ++c) {
        const float* xr = xs + ridx * LDK + c * 32 + kg * 8;
        float4 v0 = *(const float4*)xr;
        float4 v1 = *(const float4*)(xr + 4);
        xf[c].u[0] = f2h2(v0.x, v0.y);
        xf[c].u[1] = f2h2(v0.z, v0.w);
        xf[c].u[2] = f2h2(v1.x, v1.y);
        xf[c].u[3] = f2h2(v1.z, v1.w);
    }

    f32x4 acc[4];
#pragma unroll
    for (int i = 0; i < 4; ++i) acc[i] = (f32x4){0.f, 0.f, 0.f, 0.f};

#pragma unroll
    for (int i = 0; i < 4; ++i) {
        int T = Tb + i;
        const __half* wp = Wf + ((size_t)(T * NC) * 64 + lane) * 8;
#pragma unroll
        for (int c = 0; c < NC; ++c) {
            FragH wfr;
            wfr.i = *(const i32x4*)(wp + (size_t)c * 512);
            acc[i] = __builtin_amdgcn_mfma_f32_16x16x32_f16(wfr.h, xf[c].h, acc[i], 0, 0, 0);
        }
    }
    __syncthreads();

#pragma unroll
    for (int i = 0; i < 4; ++i) {
        int T = Tb + i;
        const float* bp = (T < 8) ? bs : bd;
        float4 bv = *(const float4*)(bp + (T & 7) * 16 + kg * 4);
        uint2 pk;
        pk.x = f2h2(acc[i][0] + bv.x, acc[i][1] + bv.y);
        pk.y = f2h2(acc[i][2] + bv.z, acc[i][3] + bv.w);
        int colh = (T & 7) * 16 + (T >> 3) * 128 + kg * 4;
        *(uint2*)(eb + (ng * 16 + l15) * 264 + colh) = pk;
    }
    __syncthreads();

#pragma unroll
    for (int j = 0; j < 2; ++j) {
        int f = tid + j * 512;
        int r = f >> 5, c = f & 31;
        i32x4 v = *(const i32x4*)(eb + r * 264 + c * 8);
        *(i32x4*)(fsd + (size_t)(nb + r) * 256 + c * 8) = v;
    }
}

// ---------------- GATv2 edge aggregation + head maxpool ----------------
// 4 nodes per wave via degree-sorted quads; BALANCED quad->block map (each block
// gets 4 quads spread across the degree spectrum -> equal block durations).
// Packed int2 descriptor (start, n|deg<<16) kills the perm->rowptr load chain.
// 4 edge-chains/quarter, 2-level pipeline, unconditional col loads.
__global__ __launch_bounds__(256) void k_edge(const u16* __restrict__ fsd,
                                              const int* __restrict__ colb,
                                              const int2* __restrict__ ndpack,
                                              const float* __restrict__ attn, float* __restrict__ hout) {
    int w = threadIdx.x >> 6, lane = threadIdx.x & 63;
    int bid = blockIdx.x;
    int nb = (bid & 7) * 512 + (bid >> 3);   // XCD-aware swizzle (8 graphs = 4MB fsd per XCD L2)
    int g2 = nb >> 6, bb = nb & 63;          // graph, block-in-graph
    int q = lane >> 4, s = lane & 15;
    int wgl = bb * 4 + w;                    // 0..255 wave-in-graph
    int quad = (wgl & 3) * 64 + (wgl >> 2);  // balanced bijection over sorted quads
    int2 nd = ndpack[g2 * NPG + quad * 4 + q];
    int start = nd.x;
    int n = nd.y & 0xFFFF;
    int deg = nd.y >> 16;
    const char* fsdb = (const char*)fsd;

    // attn weights for this lane's 8 dims: head = s>>2, within-head off = (s&3)*8
    const float* ap = attn + (s >> 2) * 32 + (s & 3) * 8;
    float4 a0 = *(const float4*)ap;
    float4 a1 = *(const float4*)(ap + 4);
    const float L2E = 1.44269504089f;
    h2v av0, av1, av2, av3;
    { H2U t; t.u = f2h2(a0.x * L2E, a0.y * L2E); av0 = t.h;
      t.u = f2h2(a0.z * L2E, a0.w * L2E); av1 = t.h;
      t.u = f2h2(a1.x * L2E, a1.y * L2E); av2 = t.h;
      t.u = f2h2(a1.z * L2E, a1.w * L2E); av3 = t.h; }
    h2v neg2; neg2[0] = (_Float16)NEG; neg2[1] = (_Float16)NEG;

    // fd dims for this lane's node: row n, bytes 256 + s*16
    i32x4 fdq = *(const i32x4*)(fsdb + ((size_t)n << 9) + 256 + (s << 4));
    H2U fd0, fd1, fd2, fd3;
    fd0.u = (uint32)fdq[0]; fd1.u = (uint32)fdq[1]; fd2.u = (uint32)fdq[2]; fd3.u = (uint32)fdq[3];

    int m = deg;
    { int t16 = __shfl_xor(m, 16); m = (t16 > m) ? t16 : m;
      int t32 = __shfl_xor(m, 32); m = (t32 > m) ? t32 : m; }
    int niter = (__builtin_amdgcn_readfirstlane(m) + 3) >> 2;   // ~ceil(deg/4) after sort

    const char* fb = fsdb + (s << 4);        // per-lane gather base (soff folded in)
    const int* cb = colb + start;            // per-quarter col base (unconditional loads)

    float z = 0.f;
    float c0 = 0.f, c1 = 0.f, c2 = 0.f, c3 = 0.f, c4 = 0.f, c5 = 0.f, c6 = 0.f, c7 = 0.f;

    auto gather = [&](uint32 cval) -> i32x4 {
        return *(const i32x4*)(fb + (cval & 0x01FFFE00u));   // mask keeps addr inside fsd
    };

    auto proc = [&](i32x4 f, int e) {
        uint32 w0 = (uint32)f[0], w1 = (uint32)f[1], w2 = (uint32)f[2], w3 = (uint32)f[3];
        float sp = dot_term(w0, fd0.h, neg2, av0, 0.f);
        sp = dot_term(w1, fd1.h, neg2, av1, sp);
        sp = dot_term(w2, fd2.h, neg2, av2, sp);
        sp = dot_term(w3, fd3.h, neg2, av3, sp);
        sp += __shfl_xor(sp, 1);     // head logit: quad reduce (bits 0-1)
        sp += __shfl_xor(sp, 2);
        float pe = fast_exp2(sp);
        pe = (e < deg) ? pe : 0.f;
        z += pe;
        fma_mix_lo(c0, pe, w0); fma_mix_hi(c1, pe, w0);
        fma_mix_lo(c2, pe, w1); fma_mix_hi(c3, pe, w1);
        fma_mix_lo(c4, pe, w2); fma_mix_hi(c5, pe, w2);
        fma_mix_lo(c6, pe, w3); fma_mix_hi(c7, pe, w3);
    };

    // pipeline prologue: cols for iter 0 and 1; gathers for iter 0
    uint32 cnxt0 = (uint32)cb[4], cnxt1 = (uint32)cb[5], cnxt2 = (uint32)cb[6], cnxt3 = (uint32)cb[7];
    i32x4 fv0 = gather((uint32)cb[0]), fv1 = gather((uint32)cb[1]),
          fv2 = gather((uint32)cb[2]), fv3 = gather((uint32)cb[3]);

    for (int k = 0; k < niter; ++k) {
        int e = k * 4;
        i32x4 a = fv0, b = fv1, c = fv2, d = fv3;
        // issue iter-(k+1) gathers from RESIDENT cols
        fv0 = gather(cnxt0); fv1 = gather(cnxt1); fv2 = gather(cnxt2); fv3 = gather(cnxt3);
        // issue iter-(k+2) col loads (base + immediate offsets)
        cnxt0 = (uint32)cb[e + 8]; cnxt1 = (uint32)cb[e + 9];
        cnxt2 = (uint32)cb[e + 10]; cnxt3 = (uint32)cb[e + 11];
        proc(a, e + 0);
        proc(b, e + 1);
        proc(c, e + 2);
        proc(d, e + 3);
    }

    float r = (z > 0.f) ? 1.f / z : 0.f;   // deg==0 -> output 0
    c0 *= r; c1 *= r; c2 *= r; c3 *= r; c4 *= r; c5 *= r; c6 *= r; c7 *= r;

    // maxpool over heads: coset {s, s^4, s^8, s^12} within the quarter (bits 2-3)
    c0 = fmaxf(c0, __shfl_xor(c0, 4)); c0 = fmaxf(c0, __shfl_xor(c0, 8));
    c1 = fmaxf(c1, __shfl_xor(c1, 4)); c1 = fmaxf(c1, __shfl_xor(c1, 8));
    c2 = fmaxf(c2, __shfl_xor(c2, 4)); c2 = fmaxf(c2, __shfl_xor(c2, 8));
    c3 = fmaxf(c3, __shfl_xor(c3, 4)); c3 = fmaxf(c3, __shfl_xor(c3, 8));
    c4 = fmaxf(c4, __shfl_xor(c4, 4)); c4 = fmaxf(c4, __shfl_xor(c4, 8));
    c5 = fmaxf(c5, __shfl_xor(c5, 4)); c5 = fmaxf(c5, __shfl_xor(c5, 8));
    c6 = fmaxf(c6, __shfl_xor(c6, 4)); c6 = fmaxf(c6, __shfl_xor(c6, 8));
    c7 = fmaxf(c7, __shfl_xor(c7, 4)); c7 = fmaxf(c7, __shfl_xor(c7, 8));

    if (s < 4) {   // s = within-head block 0..3 -> dims s*8..s*8+7 (per quarter's node)
        float* op = hout + ((size_t)n << 5) + (s << 3);
        *(float4*)op = make_float4(c0, c1, c2, c3);
        *(float4*)(op + 4) = make_float4(c4, c5, c6, c7);
    }
}

// ---------------- global attention pooling ----------------
__global__ __launch_bounds__(256) void k_pool(const float* __restrict__ h2, const float* __restrict__ gW,
                                              const float* __restrict__ gb, float* __restrict__ out) {
    int b = blockIdx.x, tid = threadIdx.x;
    __shared__ float ga[NPG];
    __shared__ float red[256];
    __shared__ float gws[32];
    const float* hb = h2 + (size_t)b * NPG * 32;
    if (tid < 32) gws[tid] = gW[tid];
    __syncthreads();
    float gbv = gb[0];
    float lmax = -INFINITY;
    float gloc[4];
#pragma unroll
    for (int j = 0; j < 4; ++j) {
        int nl = tid + j * 256;
        const float* row = hb + nl * 32;
        float dot = 0.f;
#pragma unroll
        for (int c = 0; c < 32; c += 4) {
            float4 v = *(const float4*)(row + c);
            dot += v.x * gws[c] + v.y * gws[c + 1] + v.z * gws[c + 2] + v.w * gws[c + 3];
        }
        gloc[j] = dot + gbv;
        lmax = fmaxf(lmax, gloc[j]);
    }
    red[tid] = lmax; __syncthreads();
    for (int s2 = 128; s2 > 0; s2 >>= 1) { if (tid < s2) red[tid] = fmaxf(red[tid], red[tid + s2]); __syncthreads(); }
    float m = red[0];
    __syncthreads();
    float lsum = 0.f;
#pragma unroll
    for (int j = 0; j < 4; ++j) {
        int nl = tid + j * 256;
        float a = __expf(gloc[j] - m);
        ga[nl] = a;
        lsum += a;
    }
    red[tid] = lsum; __syncthreads();
    for (int s2 = 128; s2 > 0; s2 >>= 1) { if (tid < s2) red[tid] += red[tid + s2]; __syncthreads(); }
    float z = red[0];
    __syncthreads();
    int d = tid & 31, ng = tid >> 5;
    float acc = 0.f;
    for (int nl = ng; nl < NPG; nl += 8) acc += ga[nl] * hb[nl * 32 + d];
    red[tid] = acc; __syncthreads();
    if (tid < 32) {
        float s = red[tid];
#pragma unroll
        for (int g2 = 1; g2 < 8; ++g2) s += red[g2 * 32 + tid];
        out[b * 32 + tid] = s / z;
    }
}

extern "C" void kernel_launch(void* const* d_in, const int* in_sizes, int n_in,
                              void* d_out, int out_size, void* d_ws, size_t ws_size,
                              hipStream_t stream) {
    const float* x     = (const float*)d_in[0];
    const int*   src   = (const int*)d_in[1];
    const int*   dst   = (const int*)d_in[2];
    const float* Ws1   = (const float*)d_in[4];
    const float* bs1   = (const float*)d_in[5];
    const float* Wd1   = (const float*)d_in[6];
    const float* bd1   = (const float*)d_in[7];
    const float* attn1 = (const float*)d_in[8];
    const float* Ws2   = (const float*)d_in[9];
    const float* bs2   = (const float*)d_in[10];
    const float* Wd2   = (const float*)d_in[11];
    const float* bd2   = (const float*)d_in[12];
    const float* attn2 = (const float*)d_in[13];
    const float* gW    = (const float*)d_in[14];
    const float* gb    = (const float*)d_in[15];
    float* out = (float*)d_out;

    // workspace layout (~56 MB)
    u16* fsd   = (u16*)d_ws;                               // N*256 halfs (fs|fd interleaved)
    float* h1  = (float*)(fsd + (size_t)N_NODES * 256);    // N*32 f32
    float* h2  = h1 + (size_t)N_NODES * 32;                // N*32 f32
    int* rowptr = (int*)(h2 + (size_t)N_NODES * 32);       // N+1 (padded)
    int* colb   = rowptr + (N_NODES + 4);                  // E (pre-shifted byte offsets)
    __half* Wf1 = (__half*)(colb + E_TOTAL);               // 32768 halfs
    __half* Wf2 = Wf1 + 32768;                             // 8192 halfs
    int2* ndpack = (int2*)(Wf2 + 8192);                    // N int2 (sorted descriptors)

    // CSR build + degree-sort (blocks 0..63) + W fragment conversion (blocks 64..103)
    k_prep<<<B_GRAPHS + 40, 1024, 0, stream>>>(src, dst, rowptr, colb, ndpack,
                                               Ws1, Wd1, Ws2, Wd2, Wf1, Wf2);

    // layer 1
    k_gemm_mfma<128><<<N_NODES / 32, 512, 0, stream>>>(x, Wf1, bs1, bd1, fsd);
    k_edge<<<N_NODES / 16, 256, 0, stream>>>(fsd, colb, ndpack, attn1, h1);

    // layer 2 (overwrites fsd)
    k_gemm_mfma<32><<<N_NODES / 32, 512, 0, stream>>>(h1, Wf2, bs2, bd2, fsd);
    k_edge<<<N_NODES / 16, 256, 0, stream>>>(fsd, colb, ndpack, attn2, h2);

    // global attention pooling
    k_pool<<<B_GRAPHS, 256, 0, stream>>>(h2, gW, gb, out);
}

// Round 20
// 129.968 us; speedup vs baseline: 1.8748x; 1.0196x over previous
//
#include <hip/hip_runtime.h>
#include <hip/hip_fp16.h>
#include <math.h>

#define N_NODES 65536
#define B_GRAPHS 64
#define NPG 1024
#define EPG 16384
#define E_TOTAL (B_GRAPHS * EPG)
#define NEG 0.2f

typedef float f32x4 __attribute__((ext_vector_type(4)));
typedef _Float16 f16x8 __attribute__((ext_vector_type(8)));
typedef _Float16 h2v __attribute__((ext_vector_type(2)));
typedef int i32x4 __attribute__((ext_vector_type(4)));
typedef unsigned int uint32;
typedef unsigned short u16;

union FragH { i32x4 i; f16x8 h; uint32 u[4]; };
union H2U { uint32 u; h2v h; };

// raw v_exp_f32 (2^x) — logits bounded by construction [validated R8+]
__device__ __forceinline__ float fast_exp2(float x) {
    float r;
    asm("v_exp_f32 %0, %1" : "=v"(r) : "v"(x));
    return r;
}

__device__ __forceinline__ uint32 f2h2(float a, float b) {
    __half2 h = __float22half2_rn(make_float2(a, b));
    return *(uint32*)&h;
}
__device__ __forceinline__ float2 h2f(uint32 u) {
    __half2 h = *(__half2*)&u;
    return __half22float2(h);
}

// packed f16 accumulate: acc = fv * pe2 + acc   (v_pk_fma_f16)
__device__ __forceinline__ void pk_fma_acc(uint32& acc, uint32 fv, uint32 pe2) {
    asm("v_pk_fma_f16 %0, %1, %2, %0" : "+v"(acc) : "v"(fv), "v"(pe2));
}

// e = fv + fd; e = max(e, NEG*e); sp += dot2(e, av)   (f32 accumulate) [validated R8+]
__device__ __forceinline__ float dot_term(uint32 fvu, h2v fdv, h2v neg2, h2v av, float accum) {
    H2U fv; fv.u = fvu;
    h2v e = fv.h + fdv;                  // v_pk_add_f16
    h2v en = e * neg2;                   // v_pk_mul_f16
    h2v em;
    asm("v_pk_max_f16 %0, %1, %2" : "=v"(em) : "v"(e), "v"(en));
    float sp;
    asm("v_dot2_f32_f16 %0, %1, %2, %3" : "=v"(sp) : "v"(em), "v"(av), "v"(accum));
    return sp;
}

// ---------------- prep: CSR count-sort + degree-sorted descriptors + W frag conv ----------------
__global__ __launch_bounds__(1024) void k_prep(const int* __restrict__ src, const int* __restrict__ dst,
                                               int* __restrict__ rowptr, int* __restrict__ colb,
                                               int2* __restrict__ ndpack,
                                               const float* __restrict__ Ws1, const float* __restrict__ Wd1,
                                               const float* __restrict__ Ws2, const float* __restrict__ Wd2,
                                               __half* __restrict__ Wf1, __half* __restrict__ Wf2) {
    __shared__ int cnt[NPG];
    __shared__ int cur[NPG];
    __shared__ int scol[EPG];   // 64KB
    __shared__ int wsum[16];
    __shared__ int hd[64];
    __shared__ int hcur[64];
    if (blockIdx.x >= B_GRAPHS) {
        int id = (blockIdx.x - B_GRAPHS) * 1024 + threadIdx.x;
        if (id < 32768) {
            int j = id & 7, l = (id >> 3) & 63, c = (id >> 9) & 3, T = id >> 11;
            int k = c * 32 + (l >> 4) * 8 + j;
            int n = (T & 7) * 16 + (l & 15);
            const float* W = (T < 8) ? Ws1 : Wd1;
            Wf1[id] = __float2half_rn(W[k * 128 + n]);
        } else if (id < 40960) {
            int rem = id - 32768;
            int j = rem & 7, l = (rem >> 3) & 63, T = rem >> 9;
            int k = (l >> 4) * 8 + j;
            int n = (T & 7) * 16 + (l & 15);
            const float* W = (T < 8) ? Ws2 : Wd2;
            Wf2[rem] = __float2half_rn(W[k * 128 + n]);
        }
        return;
    }
    int g = blockIdx.x, tid = threadIdx.x;
    int lane = tid & 63, wid = tid >> 6;
    int ebase = g * EPG;
    cnt[tid] = 0;
    __syncthreads();
    for (int e = tid; e < EPG; e += 1024)
        atomicAdd(&cnt[dst[ebase + e] & (NPG - 1)], 1);
    __syncthreads();
    int deg0 = cnt[tid];
    int v = deg0;
#pragma unroll
    for (int off = 1; off < 64; off <<= 1) {
        int t = __shfl_up(v, off);
        if (lane >= off) v += t;
    }
    if (lane == 63) wsum[wid] = v;
    __syncthreads();
    if (tid < 16) {
        int sv = wsum[tid];
#pragma unroll
        for (int off = 1; off < 16; off <<= 1) {
            int t = __shfl_up(sv, off);
            if (tid >= off) sv += t;
        }
        wsum[tid] = sv;
    }
    __syncthreads();
    int excl = v + (wid ? wsum[wid - 1] : 0) - deg0;
    rowptr[g * NPG + tid] = ebase + excl;
    if (g == B_GRAPHS - 1 && tid == 0) rowptr[N_NODES] = E_TOTAL;
    cur[tid] = excl;
    __syncthreads();
    for (int e = tid; e < EPG; e += 1024) {
        int d = dst[ebase + e] & (NPG - 1);
        int p = atomicAdd(&cur[d], 1);
        scol[p] = src[ebase + e] << 9;    // pre-shifted byte offset (fsd row stride 512B)
    }
    if (tid < 64) hd[tid] = 0;
    __syncthreads();
    int dc = deg0; dc = (dc > 63) ? 63 : dc;
    atomicAdd(&hd[dc], 1);
    int4* cg = (int4*)(colb + ebase);
    const int4* cs = (const int4*)scol;
    for (int i = tid; i < EPG / 4; i += 1024) cg[i] = cs[i];
    __syncthreads();
    if (tid == 0) {
        int run = 0;
#pragma unroll 8
        for (int i = 0; i < 64; ++i) { hcur[i] = run; run += hd[i]; }
    }
    __syncthreads();
    int pos = atomicAdd(&hcur[dc], 1);
    ndpack[g * NPG + pos] = make_int2(ebase + excl, (g * NPG + tid) | (deg0 << 16));
}

// ---------------- MFMA dual GEMM, f16 single, fragment-linear W ----------------
template <int K>
__global__ __launch_bounds__(512) void k_gemm_mfma(const float* __restrict__ X,
                                                   const __half* __restrict__ Wf,
                                                   const float* __restrict__ bs, const float* __restrict__ bd,
                                                   u16* __restrict__ fsd) {
    constexpr int NC = K / 32;
    constexpr int LDK = K + 8;
    __shared__ float xsbuf[4352];
    float* xs = xsbuf;
    u16* eb = (u16*)xsbuf;
    int tid = threadIdx.x;
    int lane = tid & 63, wv = tid >> 6;
    int l15 = lane & 15, kg = lane >> 4;
    int ng = wv & 1, Tb = (wv >> 1) * 4;
    int nb = blockIdx.x * 32;

    if (K == 128) {
#pragma unroll
        for (int j = 0; j < 2; ++j) {
            int f = tid + j * 512;
            int r = f >> 5, c4 = f & 31;
            *(float4*)(xs + r * LDK + c4 * 4) = *(const float4*)(X + (size_t)(nb + r) * K + c4 * 4);
        }
    } else {
        if (tid < 256) {
            int r = tid >> 3, c4 = tid & 7;
            *(float4*)(xs + r * LDK + c4 * 4) = *(const float4*)(X + (size_t)(nb + r) * K + c4 * 4);
        }
    }
    __syncthreads();

    int ridx = ng * 16 + l15;
    FragH xf[NC];
#pragma unroll
    for (int c = 0; c < NC; ++c) {
        const float* xr = xs + ridx * LDK + c * 32 + kg * 8;
        float4 v0 = *(const float4*)xr;
        float4 v1 = *(const float4*)(xr + 4);
        xf[c].u[0] = f2h2(v0.x, v0.y);
        xf[c].u[1] = f2h2(v0.z, v0.w);
        xf[c].u[2] = f2h2(v1.x, v1.y);
        xf[c].u[3] = f2h2(v1.z, v1.w);
    }

    f32x4 acc[4];
#pragma unroll
    for (int i = 0; i < 4; ++i) acc[i] = (f32x4){0.f, 0.f, 0.f, 0.f};

#pragma unroll
    for (int i = 0; i < 4; ++i) {
        int T = Tb + i;
        const __half* wp = Wf + ((size_t)(T * NC) * 64 + lane) * 8;
#pragma unroll
        for (int c = 0; c < NC; ++c) {
            FragH wfr;
            wfr.i = *(const i32x4*)(wp + (size_t)c * 512);
            acc[i] = __builtin_amdgcn_mfma_f32_16x16x32_f16(wfr.h, xf[c].h, acc[i], 0, 0, 0);
        }
    }
    __syncthreads();

#pragma unroll
    for (int i = 0; i < 4; ++i) {
        int T = Tb + i;
        const float* bp = (T < 8) ? bs : bd;
        float4 bv = *(const float4*)(bp + (T & 7) * 16 + kg * 4);
        uint2 pk;
        pk.x = f2h2(acc[i][0] + bv.x, acc[i][1] + bv.y);
        pk.y = f2h2(acc[i][2] + bv.z, acc[i][3] + bv.w);
        int colh = (T & 7) * 16 + (T >> 3) * 128 + kg * 4;
        *(uint2*)(eb + (ng * 16 + l15) * 264 + colh) = pk;
    }
    __syncthreads();

#pragma unroll
    for (int j = 0; j < 2; ++j) {
        int f = tid + j * 512;
        int r = f >> 5, c = f & 31;
        i32x4 v = *(const i32x4*)(eb + r * 264 + c * 8);
        *(i32x4*)(fsd + (size_t)(nb + r) * 256 + c * 8) = v;
    }
}

// ---------------- GATv2 edge aggregation + head maxpool ----------------
// 4 nodes per wave via degree-sorted quads, balanced quad->block map, packed int2
// descriptors, 4 edge-chains/quarter, 2-level pipeline, unconditional col loads.
// NEW: packed v_pk_fma_f16 numerator accumulation (4 instrs/edge instead of 8).
__global__ __launch_bounds__(256) void k_edge(const u16* __restrict__ fsd,
                                              const int* __restrict__ colb,
                                              const int2* __restrict__ ndpack,
                                              const float* __restrict__ attn, float* __restrict__ hout) {
    int w = threadIdx.x >> 6, lane = threadIdx.x & 63;
    int bid = blockIdx.x;
    int nb = (bid & 7) * 512 + (bid >> 3);   // XCD-aware swizzle (8 graphs = 4MB fsd per XCD L2)
    int g2 = nb >> 6, bb = nb & 63;
    int q = lane >> 4, s = lane & 15;
    int wgl = bb * 4 + w;
    int quad = (wgl & 3) * 64 + (wgl >> 2);  // balanced bijection over sorted quads
    int2 nd = ndpack[g2 * NPG + quad * 4 + q];
    int start = nd.x;
    int n = nd.y & 0xFFFF;
    int deg = nd.y >> 16;
    const char* fsdb = (const char*)fsd;

    const float* ap = attn + (s >> 2) * 32 + (s & 3) * 8;
    float4 a0 = *(const float4*)ap;
    float4 a1 = *(const float4*)(ap + 4);
    const float L2E = 1.44269504089f;
    h2v av0, av1, av2, av3;
    { H2U t; t.u = f2h2(a0.x * L2E, a0.y * L2E); av0 = t.h;
      t.u = f2h2(a0.z * L2E, a0.w * L2E); av1 = t.h;
      t.u = f2h2(a1.x * L2E, a1.y * L2E); av2 = t.h;
      t.u = f2h2(a1.z * L2E, a1.w * L2E); av3 = t.h; }
    h2v neg2; neg2[0] = (_Float16)NEG; neg2[1] = (_Float16)NEG;

    i32x4 fdq = *(const i32x4*)(fsdb + ((size_t)n << 9) + 256 + (s << 4));
    H2U fd0, fd1, fd2, fd3;
    fd0.u = (uint32)fdq[0]; fd1.u = (uint32)fdq[1]; fd2.u = (uint32)fdq[2]; fd3.u = (uint32)fdq[3];

    int m = deg;
    { int t16 = __shfl_xor(m, 16); m = (t16 > m) ? t16 : m;
      int t32 = __shfl_xor(m, 32); m = (t32 > m) ? t32 : m; }
    int niter = (__builtin_amdgcn_readfirstlane(m) + 3) >> 2;

    const char* fb = fsdb + (s << 4);
    const int* cb = colb + start;

    float z = 0.f;
    uint32 c0 = 0, c1 = 0, c2 = 0, c3 = 0;    // packed f16 accumulators (dims 2d,2d+1)

    auto gather = [&](uint32 cval) -> i32x4 {
        return *(const i32x4*)(fb + (cval & 0x01FFFE00u));
    };

    auto proc = [&](i32x4 f, int e) {
        uint32 w0 = (uint32)f[0], w1 = (uint32)f[1], w2 = (uint32)f[2], w3 = (uint32)f[3];
        float sp = dot_term(w0, fd0.h, neg2, av0, 0.f);
        sp = dot_term(w1, fd1.h, neg2, av1, sp);
        sp = dot_term(w2, fd2.h, neg2, av2, sp);
        sp = dot_term(w3, fd3.h, neg2, av3, sp);
        sp += __shfl_xor(sp, 1);
        sp += __shfl_xor(sp, 2);
        float pe = fast_exp2(sp);
        pe = (e < deg) ? pe : 0.f;
        z += pe;
        uint32 pe2 = f2h2(pe, pe);            // v_cvt_pkrtz
        pk_fma_acc(c0, w0, pe2);
        pk_fma_acc(c1, w1, pe2);
        pk_fma_acc(c2, w2, pe2);
        pk_fma_acc(c3, w3, pe2);
    };

    uint32 cnxt0 = (uint32)cb[4], cnxt1 = (uint32)cb[5], cnxt2 = (uint32)cb[6], cnxt3 = (uint32)cb[7];
    i32x4 fv0 = gather((uint32)cb[0]), fv1 = gather((uint32)cb[1]),
          fv2 = gather((uint32)cb[2]), fv3 = gather((uint32)cb[3]);

    for (int k = 0; k < niter; ++k) {
        int e = k * 4;
        i32x4 a = fv0, b = fv1, c = fv2, d = fv3;
        fv0 = gather(cnxt0); fv1 = gather(cnxt1); fv2 = gather(cnxt2); fv3 = gather(cnxt3);
        cnxt0 = (uint32)cb[e + 8]; cnxt1 = (uint32)cb[e + 9];
        cnxt2 = (uint32)cb[e + 10]; cnxt3 = (uint32)cb[e + 11];
        proc(a, e + 0);
        proc(b, e + 1);
        proc(c, e + 2);
        proc(d, e + 3);
    }

    // unpack packed accumulators to f32
    float2 u0 = h2f(c0), u1 = h2f(c1), u2 = h2f(c2), u3 = h2f(c3);
    float r = (z > 0.f) ? 1.f / z : 0.f;   // deg==0 -> output 0
    float d0 = u0.x * r, d1 = u0.y * r, d2 = u1.x * r, d3 = u1.y * r;
    float d4 = u2.x * r, d5 = u2.y * r, d6 = u3.x * r, d7 = u3.y * r;

    // maxpool over heads: coset {s, s^4, s^8, s^12} within the quarter (bits 2-3)
    d0 = fmaxf(d0, __shfl_xor(d0, 4)); d0 = fmaxf(d0, __shfl_xor(d0, 8));
    d1 = fmaxf(d1, __shfl_xor(d1, 4)); d1 = fmaxf(d1, __shfl_xor(d1, 8));
    d2 = fmaxf(d2, __shfl_xor(d2, 4)); d2 = fmaxf(d2, __shfl_xor(d2, 8));
    d3 = fmaxf(d3, __shfl_xor(d3, 4)); d3 = fmaxf(d3, __shfl_xor(d3, 8));
    d4 = fmaxf(d4, __shfl_xor(d4, 4)); d4 = fmaxf(d4, __shfl_xor(d4, 8));
    d5 = fmaxf(d5, __shfl_xor(d5, 4)); d5 = fmaxf(d5, __shfl_xor(d5, 8));
    d6 = fmaxf(d6, __shfl_xor(d6, 4)); d6 = fmaxf(d6, __shfl_xor(d6, 8));
    d7 = fmaxf(d7, __shfl_xor(d7, 4)); d7 = fmaxf(d7, __shfl_xor(d7, 8));

    if (s < 4) {
        float* op = hout + ((size_t)n << 5) + (s << 3);
        *(float4*)op = make_float4(d0, d1, d2, d3);
        *(float4*)(op + 4) = make_float4(d4, d5, d6, d7);
    }
}

// ---------------- global attention pooling ----------------
__global__ __launch_bounds__(256) void k_pool(const float* __restrict__ h2, const float* __restrict__ gW,
                                              const float* __restrict__ gb, float* __restrict__ out) {
    int b = blockIdx.x, tid = threadIdx.x;
    __shared__ float ga[NPG];
    __shared__ float red[256];
    __shared__ float gws[32];
    const float* hb = h2 + (size_t)b * NPG * 32;
    if (tid < 32) gws[tid] = gW[tid];
    __syncthreads();
    float gbv = gb[0];
    float lmax = -INFINITY;
    float gloc[4];
#pragma unroll
    for (int j = 0; j < 4; ++j) {
        int nl = tid + j * 256;
        const float* row = hb + nl * 32;
        float dot = 0.f;
#pragma unroll
        for (int c = 0; c < 32; c += 4) {
            float4 v = *(const float4*)(row + c);
            dot += v.x * gws[c] + v.y * gws[c + 1] + v.z * gws[c + 2] + v.w * gws[c + 3];
        }
        gloc[j] = dot + gbv;
        lmax = fmaxf(lmax, gloc[j]);
    }
    red[tid] = lmax; __syncthreads();
    for (int s2 = 128; s2 > 0; s2 >>= 1) { if (tid < s2) red[tid] = fmaxf(red[tid], red[tid + s2]); __syncthreads(); }
    float m = red[0];
    __syncthreads();
    float lsum = 0.f;
#pragma unroll
    for (int j = 0; j < 4; ++j) {
        int nl = tid + j * 256;
        float a = __expf(gloc[j] - m);
        ga[nl] = a;
        lsum += a;
    }
    red[tid] = lsum; __syncthreads();
    for (int s2 = 128; s2 > 0; s2 >>= 1) { if (tid < s2) red[tid] += red[tid + s2]; __syncthreads(); }
    float z = red[0];
    __syncthreads();
    int d = tid & 31, ng = tid >> 5;
    float acc = 0.f;
    for (int nl = ng; nl < NPG; nl += 8) acc += ga[nl] * hb[nl * 32 + d];
    red[tid] = acc; __syncthreads();
    if (tid < 32) {
        float s = red[tid];
#pragma unroll
        for (int g2 = 1; g2 < 8; ++g2) s += red[g2 * 32 + tid];
        out[b * 32 + tid] = s / z;
    }
}

extern "C" void kernel_launch(void* const* d_in, const int* in_sizes, int n_in,
                              void* d_out, int out_size, void* d_ws, size_t ws_size,
                              hipStream_t stream) {
    const float* x     = (const float*)d_in[0];
    const int*   src   = (const int*)d_in[1];
    const int*   dst   = (const int*)d_in[2];
    const float* Ws1   = (const float*)d_in[4];
    const float* bs1   = (const float*)d_in[5];
    const float* Wd1   = (const float*)d_in[6];
    const float* bd1   = (const float*)d_in[7];
    const float* attn1 = (const float*)d_in[8];
    const float* Ws2   = (const float*)d_in[9];
    const float* bs2   = (const float*)d_in[10];
    const float* Wd2   = (const float*)d_in[11];
    const float* bd2   = (const float*)d_in[12];
    const float* attn2 = (const float*)d_in[13];
    const float* gW    = (const float*)d_in[14];
    const float* gb    = (const float*)d_in[15];
    float* out = (float*)d_out;

    // workspace layout (~56 MB)
    u16* fsd   = (u16*)d_ws;                               // N*256 halfs (fs|fd interleaved)
    float* h1  = (float*)(fsd + (size_t)N_NODES * 256);    // N*32 f32
    float* h2  = h1 + (size_t)N_NODES * 32;                // N*32 f32
    int* rowptr = (int*)(h2 + (size_t)N_NODES * 32);       // N+1 (padded)
    int* colb   = rowptr + (N_NODES + 4);                  // E (pre-shifted byte offsets)
    __half* Wf1 = (__half*)(colb + E_TOTAL);               // 32768 halfs
    __half* Wf2 = Wf1 + 32768;                             // 8192 halfs
    int2* ndpack = (int2*)(Wf2 + 8192);                    // N int2 (sorted descriptors)

    // CSR build + degree-sort (blocks 0..63) + W fragment conversion (blocks 64..103)
    k_prep<<<B_GRAPHS + 40, 1024, 0, stream>>>(src, dst, rowptr, colb, ndpack,
                                               Ws1, Wd1, Ws2, Wd2, Wf1, Wf2);

    // layer 1
    k_gemm_mfma<128><<<N_NODES / 32, 512, 0, stream>>>(x, Wf1, bs1, bd1, fsd);
    k_edge<<<N_NODES / 16, 256, 0, stream>>>(fsd, colb, ndpack, attn1, h1);

    // layer 2 (overwrites fsd)
    k_gemm_mfma<32><<<N_NODES / 32, 512, 0, stream>>>(h1, Wf2, bs2, bd2, fsd);
    k_edge<<<N_NODES / 16, 256, 0, stream>>>(fsd, colb, ndpack, attn2, h2);

    // global attention pooling
    k_pool<<<B_GRAPHS, 256, 0, stream>>>(h2, gW, gb, out);
}